// Round 2
// baseline (1197.712 us; speedup 1.0000x reference)
//
#include <hip/hip_runtime.h>

#define V_N 49152
#define B_N 16
#define DEG 8

// Batch-grouped ChebNet pipeline. All feature maps are vertex-major:
//   row(v) = [g*F + f] for the G batches in the current group.
// Workspace per group (floats): xTg(GV) x1g(GV) h1g(16GV) x1b(16GV)
//                               h2g(64GV) x1c(64GV); h3g reuses h1g.
// Total = 162*G*V floats; G chosen at launch to fit ws_size.

// ---------- transpose slice: x[B,V] -> xTg[V][G] ----------
template <int G>
__global__ __launch_bounds__(256) void k_transpose_g(const float* __restrict__ x,
                                                     float* __restrict__ xT, int b0) {
    int idx = blockIdx.x * 256 + threadIdx.x;   // idx = g*V + v (coalesced read)
    int g = idx / V_N, v = idx - g * V_N;
    xT[v * G + g] = x[(b0 + g) * V_N + v];
}

// ---------- scalar spmm, row width G ----------
template <int G>
__global__ __launch_bounds__(256) void k_spmm_g(const float* __restrict__ xin,
                                                const int* __restrict__ col,
                                                const float* __restrict__ ew,
                                                float* __restrict__ xout) {
    int idx = blockIdx.x * 256 + threadIdx.x;   // over V*G
    int v = idx / G, b = idx - v * G;
    const int e0 = v * DEG;
    float acc = 0.f;
#pragma unroll
    for (int e = 0; e < DEG; ++e)
        acc = fmaf(ew[e0 + e], xin[col[e0 + e] * G + b], acc);
    xout[idx] = acc;
}

// ---------- vec4 spmm, row width W = 4*W4 ----------
template <int W4>
__global__ __launch_bounds__(256) void k_spmm_v(const float* __restrict__ xin,
                                                const int* __restrict__ col,
                                                const float* __restrict__ ew,
                                                float* __restrict__ xout) {
    int idx = blockIdx.x * 256 + threadIdx.x;   // over V*W4
    int v = idx / W4;
    int c = (idx - v * W4) * 4;
    const int e0 = v * DEG;
    float4 acc = make_float4(0.f, 0.f, 0.f, 0.f);
#pragma unroll
    for (int e = 0; e < DEG; ++e) {
        float wv = ew[e0 + e];
        const float4 u = *(const float4*)&xin[(size_t)col[e0 + e] * (W4 * 4) + c];
        acc.x = fmaf(wv, u.x, acc.x);
        acc.y = fmaf(wv, u.y, acc.y);
        acc.z = fmaf(wv, u.z, acc.z);
        acc.w = fmaf(wv, u.w, acc.w);
    }
    *(float4*)&xout[(size_t)v * (W4 * 4) + c] = acc;
}

// ---------- layer 1 fused: gather x2, einsum Fin=1 -> Fout=16, relu ----------
template <int G>
__global__ __launch_bounds__(256) void k_fused1_g(const float* __restrict__ x0,
                                                  const float* __restrict__ x1,
                                                  const int* __restrict__ col,
                                                  const float* __restrict__ ew,
                                                  const float* __restrict__ W,   // [3][1][16]
                                                  const float* __restrict__ bias,// [16]
                                                  float* __restrict__ out) {     // h1g [V][G*16]
    int idx = blockIdx.x * 256 + threadIdx.x;   // (v, g)
    int v = idx / G, b = idx - v * G;
    float a0 = x0[idx], a1 = x1[idx];
    const int e0 = v * DEG;
    float acc = 0.f;
#pragma unroll
    for (int e = 0; e < DEG; ++e)
        acc = fmaf(ew[e0 + e], x1[col[e0 + e] * G + b], acc);
    float a2 = 2.f * acc - a0;
    float4* dst = (float4*)&out[idx * 16];
#pragma unroll
    for (int oq = 0; oq < 4; ++oq) {
        float4 r;
        float* rp = (float*)&r;
#pragma unroll
        for (int j = 0; j < 4; ++j) {
            int o = oq * 4 + j;
            rp[j] = fmaxf(fmaf(a0, W[o], fmaf(a1, W[16 + o], fmaf(a2, W[32 + o], bias[o]))), 0.f);
        }
        dst[oq] = r;
    }
}

// ---------- layer 2 fused: Fin=16 -> Fout=64 ----------
// Block = 64*GB threads covers GB batches of one vertex.
template <int G, int GB>
__global__ __launch_bounds__(256) void k_fused2_g(const float* __restrict__ x0,  // h1g [V][16G]
                                                  const float* __restrict__ x1,  // x1b [V][16G]
                                                  const int* __restrict__ col,
                                                  const float* __restrict__ ew,
                                                  const float* __restrict__ W,   // [3][16][64]
                                                  const float* __restrict__ bias,// [64]
                                                  float* __restrict__ out) {     // h2g [V][64G]
    constexpr int BPV = G / GB;
    __shared__ float s[3][16 * GB];
    __shared__ float sW[3072];
    __shared__ float sB[64];
    __shared__ int sc[DEG];
    __shared__ float sw[DEG];
    int v = blockIdx.x / BPV;
    int g0 = (blockIdx.x - v * BPV) * GB;
    int t = threadIdx.x;                         // [0, 64*GB)
    if (t < DEG) { sc[t] = col[v * DEG + t]; sw[t] = ew[v * DEG + t]; }
    for (int j = t; j < 3072; j += 64 * GB) sW[j] = W[j];
    if (t < 64) sB[t] = bias[t];
    float a0 = 0.f;
    if (t < 16 * GB) {
        a0 = x0[v * 16 * G + g0 * 16 + t];
        s[0][t] = a0;
        s[1][t] = x1[v * 16 * G + g0 * 16 + t];
    }
    __syncthreads();
    if (t < 16 * GB) {
        float acc = 0.f;
#pragma unroll
        for (int e = 0; e < DEG; ++e)
            acc = fmaf(sw[e], x1[sc[e] * 16 * G + g0 * 16 + t], acc);
        s[2][t] = 2.f * acc - a0;
    }
    __syncthreads();
    int g = t >> 6, o = t & 63;
    float r = sB[o];
#pragma unroll
    for (int k = 0; k < 3; ++k)
#pragma unroll
        for (int i = 0; i < 16; ++i)
            r = fmaf(s[k][g * 16 + i], sW[k * 1024 + i * 64 + o], r);
    out[(size_t)v * 64 * G + g0 * 64 + t] = fmaxf(r, 0.f);
}

// ---------- layer 3 fused: Fin=64 -> Fout=16 ----------
template <int G>
__global__ __launch_bounds__(256) void k_fused3_g(const float* __restrict__ x0,  // h2g [V][64G]
                                                  const float* __restrict__ x1,  // x1c [V][64G]
                                                  const int* __restrict__ col,
                                                  const float* __restrict__ ew,
                                                  const float* __restrict__ W,   // [3][64][16]
                                                  const float* __restrict__ bias,// [16]
                                                  float* __restrict__ out) {     // h3g [V][16G]
    __shared__ float s[3][G][65];   // 65: g-rows land in different banks
    __shared__ float sW[3072];
    __shared__ float sB[16];
    __shared__ int sc[DEG];
    __shared__ float sw[DEG];
    int v = blockIdx.x, t = threadIdx.x;
    if (t < DEG) { sc[t] = col[v * DEG + t]; sw[t] = ew[v * DEG + t]; }
    for (int j = t; j < 3072; j += 256) sW[j] = W[j];
    if (t < 16) sB[t] = bias[t];
    for (int u = t; u < 64 * G; u += 256) {
        int g = u >> 6, i = u & 63;
        s[0][g][i] = x0[(size_t)v * 64 * G + u];
        s[1][g][i] = x1[(size_t)v * 64 * G + u];
    }
    __syncthreads();
    for (int u = t; u < 64 * G; u += 256) {
        int g = u >> 6, i = u & 63;
        float acc = 0.f;
#pragma unroll
        for (int e = 0; e < DEG; ++e)
            acc = fmaf(sw[e], x1[(size_t)sc[e] * 64 * G + u], acc);
        s[2][g][i] = 2.f * acc - s[0][g][i];
    }
    __syncthreads();
    if (t < 16 * G) {
        int g = t >> 4, o = t & 15;
        float r = sB[o];
#pragma unroll
        for (int k = 0; k < 3; ++k)
#pragma unroll
            for (int i = 0; i < 64; ++i)
                r = fmaf(s[k][g][i], sW[k * 1024 + i * 16 + o], r);
        out[v * 16 * G + t] = fmaxf(r, 0.f);
    }
}

// ---------- layer 4: pointwise 16 -> 1, write out[B,V] slice ----------
template <int G>
__global__ __launch_bounds__(256) void k_layer4_g(const float* __restrict__ h,   // h3g [V][16G]
                                                  const float* __restrict__ w4,  // [16]
                                                  const float* __restrict__ b4,  // [1]
                                                  float* __restrict__ out, int b0) {
    int idx = blockIdx.x * 256 + threadIdx.x;   // idx = g*V + v (coalesced write)
    int g = idx / V_N, v = idx - g * V_N;
    const float4* hp = (const float4*)&h[v * 16 * G + g * 16];
    float acc = b4[0];
#pragma unroll
    for (int q = 0; q < 4; ++q) {
        float4 u = hp[q];
        acc = fmaf(u.x, w4[q * 4 + 0], acc);
        acc = fmaf(u.y, w4[q * 4 + 1], acc);
        acc = fmaf(u.z, w4[q * 4 + 2], acc);
        acc = fmaf(u.w, w4[q * 4 + 3], acc);
    }
    out[(b0 + g) * V_N + v] = acc;
}

// ---------- pipeline driver ----------
template <int G>
static void run_pipeline(const float* x, const int* ecol, const float* ew,
                         const float* w1, const float* b1, const float* w2, const float* b2,
                         const float* w3, const float* b3, const float* w4, const float* b4,
                         float* out, float* ws, hipStream_t stream) {
    const size_t GV = (size_t)G * V_N;
    float* xTg = ws;
    float* x1g = xTg + GV;
    float* h1g = x1g + GV;
    float* x1b = h1g + 16 * GV;
    float* h2g = x1b + 16 * GV;
    float* x1c = h2g + 64 * GV;
    float* h3g = h1g;                 // reuse after fused2 consumed h1g/x1b
    constexpr int GB = (G < 4) ? G : 4;
    dim3 blk(256);
    for (int b0 = 0; b0 < B_N; b0 += G) {
        k_transpose_g<G><<<V_N * G / 256, blk, 0, stream>>>(x, xTg, b0);
        k_spmm_g<G><<<V_N * G / 256, blk, 0, stream>>>(xTg, ecol, ew, x1g);
        k_fused1_g<G><<<V_N * G / 256, blk, 0, stream>>>(xTg, x1g, ecol, ew, w1, b1, h1g);
        k_spmm_v<4 * G><<<V_N * 4 * G / 256, blk, 0, stream>>>(h1g, ecol, ew, x1b);
        k_fused2_g<G, GB><<<V_N * (G / GB), dim3(64 * GB), 0, stream>>>(h1g, x1b, ecol, ew, w2, b2, h2g);
        k_spmm_v<16 * G><<<V_N * 16 * G / 256, blk, 0, stream>>>(h2g, ecol, ew, x1c);
        k_fused3_g<G><<<V_N, blk, 0, stream>>>(h2g, x1c, ecol, ew, w3, b3, h3g);
        k_layer4_g<G><<<V_N * G / 256, blk, 0, stream>>>(h3g, w4, b4, out, b0);
    }
}

extern "C" void kernel_launch(void* const* d_in, const int* in_sizes, int n_in,
                              void* d_out, int out_size, void* d_ws, size_t ws_size,
                              hipStream_t stream) {
    const float* x = (const float*)d_in[0];
    // d_in[1] = edge_row = repeat(arange(V), 8) -> implicit, unused
    const int* ecol = (const int*)d_in[2];
    const float* ew = (const float*)d_in[3];
    const float* w1 = (const float*)d_in[4];
    const float* b1 = (const float*)d_in[5];
    const float* w2 = (const float*)d_in[6];
    const float* b2 = (const float*)d_in[7];
    const float* w3 = (const float*)d_in[8];
    const float* b3 = (const float*)d_in[9];
    const float* w4 = (const float*)d_in[10];
    const float* b4 = (const float*)d_in[11];
    float* out = (float*)d_out;
    float* ws = (float*)d_ws;

    auto need = [](int G) { return (size_t)162 * G * V_N * 4; };
    if (ws_size >= need(8))
        run_pipeline<8>(x, ecol, ew, w1, b1, w2, b2, w3, b3, w4, b4, out, ws, stream);
    else if (ws_size >= need(4))
        run_pipeline<4>(x, ecol, ew, w1, b1, w2, b2, w3, b3, w4, b4, out, ws, stream);
    else if (ws_size >= need(2))
        run_pipeline<2>(x, ecol, ew, w1, b1, w2, b2, w3, b3, w4, b4, out, ws, stream);
    else
        run_pipeline<1>(x, ecol, ew, w1, b1, w2, b2, w3, b3, w4, b4, out, ws, stream);
}

// Round 5
// 571.428 us; speedup vs baseline: 2.0960x; 2.0960x over previous
//
#include <hip/hip_runtime.h>

#define V_N 49152
#define B_N 16
#define DEG 8

// ChebNet, batch-grouped (G batches per pass), all maps vertex-major.
// Layer 3 uses the commuting trick (L x)W = L(xW):
//   h3 = relu(y0 - y2 + L y1 + 2 L(L y2) + b3),  yk = relu_h2 . W3_k (width 16)
// so h2 (width 64) is never materialized; only width-16/32 rows are gathered.
// Buffers (floats): xT(GV) x1(GV) h1(16GV) x1b(16GV) y012(48GV); z12 reuses h1+x1b.

// ---------- transpose slice: x[B,V] -> xT[V][G] ----------
template <int G>
__global__ __launch_bounds__(256) void k_transpose_g(const float* __restrict__ x,
                                                     float* __restrict__ xT, int b0) {
    int idx = blockIdx.x * 256 + threadIdx.x;   // idx = g*V + v (coalesced read)
    int g = idx / V_N, v = idx - g * V_N;
    xT[v * G + g] = x[(b0 + g) * V_N + v];
}

// ---------- scalar spmm, row width G ----------
template <int G>
__global__ __launch_bounds__(256) void k_spmm_g(const float* __restrict__ xin,
                                                const int* __restrict__ col,
                                                const float* __restrict__ ew,
                                                float* __restrict__ xout) {
    int idx = blockIdx.x * 256 + threadIdx.x;   // over V*G
    int v = idx / G, b = idx - v * G;
    const int e0 = v * DEG;
    float acc = 0.f;
#pragma unroll
    for (int e = 0; e < DEG; ++e)
        acc = fmaf(ew[e0 + e], xin[col[e0 + e] * G + b], acc);
    xout[idx] = acc;
}

// ---------- vec4 spmm, contiguous rows, width = 4*W4 floats ----------
template <int W4>
__global__ __launch_bounds__(256) void k_spmm_v(const float* __restrict__ xin,
                                                const int* __restrict__ col,
                                                const float* __restrict__ ew,
                                                float* __restrict__ xout) {
    int idx = blockIdx.x * 256 + threadIdx.x;   // over V*W4
    int v = idx / W4;
    int c = (idx - v * W4) * 4;
    const int e0 = v * DEG;
    float4 acc = make_float4(0.f, 0.f, 0.f, 0.f);
#pragma unroll
    for (int e = 0; e < DEG; ++e) {
        float wv = ew[e0 + e];
        const float4 u = *(const float4*)&xin[(size_t)col[e0 + e] * (W4 * 4) + c];
        acc.x = fmaf(wv, u.x, acc.x);
        acc.y = fmaf(wv, u.y, acc.y);
        acc.z = fmaf(wv, u.z, acc.z);
        acc.w = fmaf(wv, u.w, acc.w);
    }
    *(float4*)&xout[(size_t)v * (W4 * 4) + c] = acc;
}

// ---------- vec4 spmm, strided rows: out width 4*W4, separate strides ----------
template <int W4>
__global__ __launch_bounds__(256) void k_spmm_vs(const float* __restrict__ xin,
                                                 int in_stride,      // floats
                                                 const int* __restrict__ col,
                                                 const float* __restrict__ ew,
                                                 float* __restrict__ xout,
                                                 int out_stride) {   // floats
    int idx = blockIdx.x * 256 + threadIdx.x;   // over V*W4
    int v = idx / W4;
    int c = (idx - v * W4) * 4;
    const int e0 = v * DEG;
    float4 acc = make_float4(0.f, 0.f, 0.f, 0.f);
#pragma unroll
    for (int e = 0; e < DEG; ++e) {
        float wv = ew[e0 + e];
        const float4 u = *(const float4*)&xin[(size_t)col[e0 + e] * in_stride + c];
        acc.x = fmaf(wv, u.x, acc.x);
        acc.y = fmaf(wv, u.y, acc.y);
        acc.z = fmaf(wv, u.z, acc.z);
        acc.w = fmaf(wv, u.w, acc.w);
    }
    *(float4*)&xout[(size_t)v * out_stride + c] = acc;
}

// ---------- layer 1 fused: gather x2, einsum Fin=1 -> Fout=16, relu ----------
template <int G>
__global__ __launch_bounds__(256) void k_fused1_g(const float* __restrict__ x0,
                                                  const float* __restrict__ x1,
                                                  const int* __restrict__ col,
                                                  const float* __restrict__ ew,
                                                  const float* __restrict__ W,   // [3][1][16]
                                                  const float* __restrict__ bias,// [16]
                                                  float* __restrict__ out) {     // h1 [V][16G]
    int idx = blockIdx.x * 256 + threadIdx.x;   // (v, g)
    int v = idx / G;
    float a0 = x0[idx], a1 = x1[idx];
    const int e0 = v * DEG;
    float acc = 0.f;
#pragma unroll
    for (int e = 0; e < DEG; ++e)
        acc = fmaf(ew[e0 + e], x1[col[e0 + e] * G + (idx - v * G)], acc);
    float a2 = 2.f * acc - a0;
    float4* dst = (float4*)&out[(size_t)idx * 16];
#pragma unroll
    for (int oq = 0; oq < 4; ++oq) {
        float4 r;
        float* rp = (float*)&r;
#pragma unroll
        for (int j = 0; j < 4; ++j) {
            int o = oq * 4 + j;
            rp[j] = fmaxf(fmaf(a0, W[o], fmaf(a1, W[16 + o], fmaf(a2, W[32 + o], bias[o]))), 0.f);
        }
        dst[oq] = r;
    }
}

// ---------- layer 2 fused + y-projection ----------
// Per vertex: x2 = 2 L x1b - h1 (gather); h2 = relu(cheb einsum 16->64 + b2)
// kept in LDS; then y_k = h2 . W3_k  (64->16, k=0..2) written as y012 [V][48G]
// row layout: [y0: g*16 | y1: g*16 | y2: g*16].
// Block = 256 threads = 4 vertices x 64 lanes; W columns cached in VGPRs,
// x read as broadcast b128 from LDS (4 FMA per LDS instr).
template <int G>
__global__ __launch_bounds__(256) void k_fused2y(const float* __restrict__ x0,  // h1 [V][16G]
                                                 const float* __restrict__ x1,  // x1b [V][16G]
                                                 const int* __restrict__ col,
                                                 const float* __restrict__ ew,
                                                 const float* __restrict__ W2,  // [3][16][64]
                                                 const float* __restrict__ b2,  // [64]
                                                 const float* __restrict__ W3,  // [3][64][16]
                                                 float* __restrict__ y) {       // y012 [V][48G]
    constexpr int R = 16 * G;
    __shared__ float s[4][3 * R];        // [vl][k*R + el]
    __shared__ float sh2[4][G][64];
    __shared__ float sW2[3072];
    __shared__ float sW3[3072];
    __shared__ float sB[64];
    __shared__ int   sc[4][DEG];
    __shared__ float sw[4][DEG];
    const int t = threadIdx.x;
    const int v0 = blockIdx.x * 4;
    for (int j = t; j < 3072; j += 256) { sW2[j] = W2[j]; sW3[j] = W3[j]; }
    if (t < 64) sB[t] = b2[t];
    if (t < 32) {
        int vl = t >> 3, e = t & 7;
        sc[vl][e] = col[(v0 + vl) * DEG + e];
        sw[vl][e] = ew[(v0 + vl) * DEG + e];
    }
    __syncthreads();
    // stage x0, x1; gather x2
    for (int u = t; u < 4 * R; u += 256) {
        int vl = u / R, el = u - vl * R;
        size_t row = (size_t)(v0 + vl) * R;
        float a0 = x0[row + el];
        float a1 = x1[row + el];
        s[vl][0 * R + el] = a0;
        s[vl][1 * R + el] = a1;
        float acc = 0.f;
#pragma unroll
        for (int e = 0; e < DEG; ++e)
            acc = fmaf(sw[vl][e], x1[(size_t)sc[vl][e] * R + el], acc);
        s[vl][2 * R + el] = 2.f * acc - a0;
    }
    __syncthreads();
    const int vl = t >> 6, o = t & 63;
    // W2 column o -> regs
    float wc[48];
#pragma unroll
    for (int k = 0; k < 3; ++k)
#pragma unroll
        for (int i = 0; i < 16; ++i)
            wc[k * 16 + i] = sW2[k * 1024 + i * 64 + o];
    // phase A: h2[g][o] for all g
    float bias = sB[o];
#pragma unroll
    for (int g = 0; g < G; ++g) {
        float r = bias;
#pragma unroll
        for (int k = 0; k < 3; ++k) {
            const float4* ap = (const float4*)&s[vl][k * R + g * 16];
#pragma unroll
            for (int iq = 0; iq < 4; ++iq) {
                float4 a = ap[iq];
                r = fmaf(a.x, wc[k * 16 + iq * 4 + 0], r);
                r = fmaf(a.y, wc[k * 16 + iq * 4 + 1], r);
                r = fmaf(a.z, wc[k * 16 + iq * 4 + 2], r);
                r = fmaf(a.w, wc[k * 16 + iq * 4 + 3], r);
            }
        }
        sh2[vl][g][o] = fmaxf(r, 0.f);
    }
    __syncthreads();
    // phase B: y_j(g) = h2(g) . W3col(j), j = o in [0,48)
    if (o < 48) {
        const int k3 = o >> 4, o3 = o & 15;
        float wy[64];
#pragma unroll
        for (int i = 0; i < 64; ++i)
            wy[i] = sW3[k3 * 1024 + i * 16 + o3];
        size_t yrow = (size_t)(v0 + vl) * (48 * G) + (size_t)k3 * (16 * G) + o3;
#pragma unroll
        for (int g = 0; g < G; ++g) {
            float r = 0.f;
            const float4* hp = (const float4*)&sh2[vl][g][0];
#pragma unroll
            for (int iq = 0; iq < 16; ++iq) {
                float4 h = hp[iq];
                r = fmaf(h.x, wy[iq * 4 + 0], r);
                r = fmaf(h.y, wy[iq * 4 + 1], r);
                r = fmaf(h.z, wy[iq * 4 + 2], r);
                r = fmaf(h.w, wy[iq * 4 + 3], r);
            }
            y[yrow + (size_t)g * 16] = r;
        }
    }
}

// ---------- final: gather L z2, combine layer-3, fuse layer-4 dot ----------
template <int G>
__global__ __launch_bounds__(256) void k_final_g(const float* __restrict__ y,  // y012 [V][48G]
                                                 const float* __restrict__ z,  // z12 [V][32G]
                                                 const int* __restrict__ col,
                                                 const float* __restrict__ ew,
                                                 const float* __restrict__ b3, // [16]
                                                 const float* __restrict__ w4, // [16]
                                                 const float* __restrict__ b4, // [1]
                                                 float* __restrict__ out, int b0) {
    int idx = blockIdx.x * 256 + threadIdx.x;   // over V*G
    int v = idx / G, g = idx - v * G;
    const size_t yr = (size_t)v * (48 * G) + g * 16;
    const size_t zr = (size_t)v * (32 * G) + g * 16;
    const int e0 = v * DEG;
    float4 acc[4];
#pragma unroll
    for (int q = 0; q < 4; ++q) acc[q] = make_float4(0.f, 0.f, 0.f, 0.f);
#pragma unroll
    for (int e = 0; e < DEG; ++e) {
        float wv = ew[e0 + e];
        const float* src = z + (size_t)col[e0 + e] * (32 * G) + 16 * G + g * 16;
#pragma unroll
        for (int q = 0; q < 4; ++q) {
            float4 u = *(const float4*)(src + q * 4);
            acc[q].x = fmaf(wv, u.x, acc[q].x);
            acc[q].y = fmaf(wv, u.y, acc[q].y);
            acc[q].z = fmaf(wv, u.z, acc[q].z);
            acc[q].w = fmaf(wv, u.w, acc[q].w);
        }
    }
    float r = b4[0];
#pragma unroll
    for (int q = 0; q < 4; ++q) {
        float4 y0v = *(const float4*)(y + yr + q * 4);
        float4 y2v = *(const float4*)(y + yr + (size_t)32 * G + q * 4);
        float4 z1v = *(const float4*)(z + zr + q * 4);
        const float* a = (const float*)&acc[q];
        const float* p0 = (const float*)&y0v;
        const float* p2 = (const float*)&y2v;
        const float* p1 = (const float*)&z1v;
#pragma unroll
        for (int j = 0; j < 4; ++j) {
            float h = p0[j] - p2[j] + p1[j] + 2.f * a[j] + b3[q * 4 + j];
            h = fmaxf(h, 0.f);
            r = fmaf(h, w4[q * 4 + j], r);
        }
    }
    out[(b0 + g) * V_N + v] = r;
}

// ---------- pipeline driver ----------
template <int G>
static void run_pipeline(const float* x, const int* ecol, const float* ew,
                         const float* w1, const float* b1, const float* w2, const float* b2,
                         const float* w3, const float* b3, const float* w4, const float* b4,
                         float* out, float* ws, hipStream_t stream) {
    const size_t GV = (size_t)G * V_N;
    float* xT   = ws;
    float* x1   = xT + GV;
    float* h1   = x1 + GV;
    float* x1b  = h1 + 16 * GV;
    float* y012 = x1b + 16 * GV;
    float* z12  = h1;              // reuse h1+x1b (32GV) after fused2y consumed them
    dim3 blk(256);
    for (int b0 = 0; b0 < B_N; b0 += G) {
        k_transpose_g<G><<<(V_N * G) / 256, blk, 0, stream>>>(x, xT, b0);
        k_spmm_g<G><<<(V_N * G) / 256, blk, 0, stream>>>(xT, ecol, ew, x1);
        k_fused1_g<G><<<(V_N * G) / 256, blk, 0, stream>>>(xT, x1, ecol, ew, w1, b1, h1);
        k_spmm_v<4 * G><<<(V_N * 4 * G) / 256, blk, 0, stream>>>(h1, ecol, ew, x1b);
        k_fused2y<G><<<V_N / 4, blk, 0, stream>>>(h1, x1b, ecol, ew, w2, b2, w3, y012);
        // z12 = L [y1|y2]  (strided source: columns [16G,48G) of y012)
        k_spmm_vs<8 * G><<<(V_N * 8 * G) / 256, blk, 0, stream>>>(
            y012 + 16 * G, 48 * G, ecol, ew, z12, 32 * G);
        k_final_g<G><<<(V_N * G) / 256, blk, 0, stream>>>(y012, z12, ecol, ew, b3, w4, b4, out, b0);
    }
}

extern "C" void kernel_launch(void* const* d_in, const int* in_sizes, int n_in,
                              void* d_out, int out_size, void* d_ws, size_t ws_size,
                              hipStream_t stream) {
    const float* x = (const float*)d_in[0];
    // d_in[1] = edge_row = repeat(arange(V), 8) -> implicit, unused
    const int* ecol = (const int*)d_in[2];
    const float* ew = (const float*)d_in[3];
    const float* w1 = (const float*)d_in[4];
    const float* b1 = (const float*)d_in[5];
    const float* w2 = (const float*)d_in[6];
    const float* b2 = (const float*)d_in[7];
    const float* w3 = (const float*)d_in[8];
    const float* b3 = (const float*)d_in[9];
    const float* w4 = (const float*)d_in[10];
    const float* b4 = (const float*)d_in[11];
    float* out = (float*)d_out;
    float* ws = (float*)d_ws;

    auto need = [](int G) { return (size_t)82 * G * V_N * 4; };
    if (ws_size >= need(8))
        run_pipeline<8>(x, ecol, ew, w1, b1, w2, b2, w3, b3, w4, b4, out, ws, stream);
    else if (ws_size >= need(4))
        run_pipeline<4>(x, ecol, ew, w1, b1, w2, b2, w3, b3, w4, b4, out, ws, stream);
    else if (ws_size >= need(2))
        run_pipeline<2>(x, ecol, ew, w1, b1, w2, b2, w3, b3, w4, b4, out, ws, stream);
    else
        run_pipeline<1>(x, ecol, ew, w1, b1, w2, b2, w3, b3, w4, b4, out, ws, stream);
}

// Round 7
// 455.188 us; speedup vs baseline: 2.6312x; 1.2554x over previous
//
#include <hip/hip_runtime.h>

#define V_N 49152
#define B_N 16
#define DEG 8

typedef __bf16 bf16x8 __attribute__((ext_vector_type(8)));
typedef float f32x4 __attribute__((ext_vector_type(4)));

// ChebNet, batch-grouped (G batches per pass), all maps vertex-major.
// Layer 3 commuting trick: h3 = relu(y0 - y2 + L y1 + 2 L(L y2) + b3),
// yk = relu(h2).W3_k, so h2 (width 64/batch) is never materialized.
// G=8 path: layer-2+y einsums via split-bf16 MFMA (hi+lo, fp32-accurate).

// ---------- transpose slice: x[B,V] -> xT[V][G] ----------
template <int G>
__global__ __launch_bounds__(256) void k_transpose_g(const float* __restrict__ x,
                                                     float* __restrict__ xT, int b0) {
    int idx = blockIdx.x * 256 + threadIdx.x;   // idx = g*V + v (coalesced read)
    int g = idx / V_N, v = idx - g * V_N;
    xT[v * G + g] = x[(b0 + g) * V_N + v];
}

// ---------- scalar spmm, row width G ----------
template <int G>
__global__ __launch_bounds__(256) void k_spmm_g(const float* __restrict__ xin,
                                                const int* __restrict__ col,
                                                const float* __restrict__ ew,
                                                float* __restrict__ xout) {
    int idx = blockIdx.x * 256 + threadIdx.x;   // over V*G
    int v = idx / G, b = idx - v * G;
    const int e0 = v * DEG;
    float acc = 0.f;
#pragma unroll
    for (int e = 0; e < DEG; ++e)
        acc = fmaf(ew[e0 + e], xin[col[e0 + e] * G + b], acc);
    xout[idx] = acc;
}

// ---------- vec4 spmm, contiguous rows, width = 4*W4 floats ----------
template <int W4>
__global__ __launch_bounds__(256) void k_spmm_v(const float* __restrict__ xin,
                                                const int* __restrict__ col,
                                                const float* __restrict__ ew,
                                                float* __restrict__ xout) {
    int idx = blockIdx.x * 256 + threadIdx.x;   // over V*W4
    int v = idx / W4;
    int c = (idx - v * W4) * 4;
    const int e0 = v * DEG;
    float4 acc = make_float4(0.f, 0.f, 0.f, 0.f);
#pragma unroll
    for (int e = 0; e < DEG; ++e) {
        float wv = ew[e0 + e];
        const float4 u = *(const float4*)&xin[(size_t)col[e0 + e] * (W4 * 4) + c];
        acc.x = fmaf(wv, u.x, acc.x);
        acc.y = fmaf(wv, u.y, acc.y);
        acc.z = fmaf(wv, u.z, acc.z);
        acc.w = fmaf(wv, u.w, acc.w);
    }
    *(float4*)&xout[(size_t)v * (W4 * 4) + c] = acc;
}

// ---------- vec4 spmm, strided rows ----------
template <int W4>
__global__ __launch_bounds__(256) void k_spmm_vs(const float* __restrict__ xin,
                                                 int in_stride,
                                                 const int* __restrict__ col,
                                                 const float* __restrict__ ew,
                                                 float* __restrict__ xout,
                                                 int out_stride) {
    int idx = blockIdx.x * 256 + threadIdx.x;   // over V*W4
    int v = idx / W4;
    int c = (idx - v * W4) * 4;
    const int e0 = v * DEG;
    float4 acc = make_float4(0.f, 0.f, 0.f, 0.f);
#pragma unroll
    for (int e = 0; e < DEG; ++e) {
        float wv = ew[e0 + e];
        const float4 u = *(const float4*)&xin[(size_t)col[e0 + e] * in_stride + c];
        acc.x = fmaf(wv, u.x, acc.x);
        acc.y = fmaf(wv, u.y, acc.y);
        acc.z = fmaf(wv, u.z, acc.z);
        acc.w = fmaf(wv, u.w, acc.w);
    }
    *(float4*)&xout[(size_t)v * out_stride + c] = acc;
}

// ---------- layer 1 fused: gather x2, einsum Fin=1 -> Fout=16, relu ----------
template <int G>
__global__ __launch_bounds__(256) void k_fused1_g(const float* __restrict__ x0,
                                                  const float* __restrict__ x1,
                                                  const int* __restrict__ col,
                                                  const float* __restrict__ ew,
                                                  const float* __restrict__ W,   // [3][1][16]
                                                  const float* __restrict__ bias,// [16]
                                                  float* __restrict__ out) {     // h1 [V][16G]
    int idx = blockIdx.x * 256 + threadIdx.x;   // (v, g)
    int v = idx / G;
    float a0 = x0[idx], a1 = x1[idx];
    const int e0 = v * DEG;
    float acc = 0.f;
#pragma unroll
    for (int e = 0; e < DEG; ++e)
        acc = fmaf(ew[e0 + e], x1[col[e0 + e] * G + (idx - v * G)], acc);
    float a2 = 2.f * acc - a0;
    float4* dst = (float4*)&out[(size_t)idx * 16];
#pragma unroll
    for (int oq = 0; oq < 4; ++oq) {
        float4 r;
        float* rp = (float*)&r;
#pragma unroll
        for (int j = 0; j < 4; ++j) {
            int o = oq * 4 + j;
            rp[j] = fmaxf(fmaf(a0, W[o], fmaf(a1, W[16 + o], fmaf(a2, W[32 + o], bias[o]))), 0.f);
        }
        dst[oq] = r;
    }
}

// ---------- weight prepack into MFMA B-fragment layout (hi/lo split) ----------
// pk: [0,4096)=W2hi  [4096,8192)=W2lo  [8192,11264)=W3hi  [11264,14336)=W3lo
// W2 frag: kt(2) x nt(4) x lane(64) x e(8), k = kt*32+(lane>>4)*8+e (>=48 -> 0),
//          col = nt*16+(lane&15).  W3 frag: kt(2) x nt(3), k=feature, col=(k3,o3).
__global__ __launch_bounds__(512) void k_prepack(const float* __restrict__ w2,
                                                 const float* __restrict__ w3,
                                                 __bf16* __restrict__ pk) {
    int t = threadIdx.x;
    {
        int kt = t >> 8, nt = (t >> 6) & 3, lane = t & 63;
#pragma unroll
        for (int e = 0; e < 8; ++e) {
            int k = kt * 32 + ((lane >> 4) * 8) + e;
            float val = (k < 48) ? w2[(k >> 4) * 1024 + (k & 15) * 64 + nt * 16 + (lane & 15)] : 0.f;
            __bf16 hi = (__bf16)val;
            pk[t * 8 + e] = hi;
            pk[4096 + t * 8 + e] = (__bf16)(val - (float)hi);
        }
    }
    if (t < 384) {
        int kt = t / 192, nt = (t / 64) % 3, lane = t & 63;
#pragma unroll
        for (int e = 0; e < 8; ++e) {
            int k = kt * 32 + ((lane >> 4) * 8) + e;
            float val = w3[nt * 1024 + k * 16 + (lane & 15)];
            __bf16 hi = (__bf16)val;
            pk[8192 + t * 8 + e] = hi;
            pk[11264 + t * 8 + e] = (__bf16)(val - (float)hi);
        }
    }
}

// ---------- layer 2 + y projection via split-bf16 MFMA (G=8 only) ----------
// Block = 8 vertices = 4 waves; wave w owns M-tile of 16 rows = 2 vertices x 8 g.
// A row = (v&1)*8+g; K = (kcheb,i) padded 48->64.  Phase A: h2 = relu(x.W2+b2)
// -> fp32 in wave-private LDS; phase B: y = h2.W3 -> y012 [V][384].
__global__ __launch_bounds__(256) void k_fused2y_mfma(const float* __restrict__ x0, // h1 [V][128]
                                                      const float* __restrict__ x1, // x1b [V][128]
                                                      const int* __restrict__ col,
                                                      const float* __restrict__ ew,
                                                      const __bf16* __restrict__ pk,
                                                      const float* __restrict__ b2, // [64]
                                                      float* __restrict__ y) {      // [V][384]
    __shared__ __attribute__((aligned(16))) __bf16 s_hi[4][16 * 72]; // stride 72: 16B-aligned, 2-way banks
    __shared__ __attribute__((aligned(16))) __bf16 s_lo[4][16 * 72];
    __shared__ __attribute__((aligned(16))) float  sh2[4][16 * 68];  // stride 68: 16B-aligned, 2-way banks
    __shared__ int   sc[8][8];
    __shared__ float sw[8][8];
    const int t = threadIdx.x;
    const int v0 = blockIdx.x * 8;
    if (t < 64) {
        int vl = t >> 3, e = t & 7;
        sc[vl][e] = col[(v0 + vl) * DEG + e];
        sw[vl][e] = ew[(v0 + vl) * DEG + e];
    }
    __syncthreads();
    // zero K-pad (kcol 48..63) so pad contributes exact 0 (B rows there are 0 too)
    for (int u = t; u < 4 * 16 * 16; u += 256) {
        int tile = u >> 8, row = (u >> 4) & 15, i = u & 15;
        s_hi[tile][row * 72 + 48 + i] = (__bf16)0.f;
        s_lo[tile][row * 72 + 48 + i] = (__bf16)0.f;
    }
    // stage x0,x1 and gathered x2 = 2 L x1 - x0 as bf16 hi/lo A-fragments
#pragma unroll
    for (int j = 0; j < 12; ++j) {
        int u = j * 256 + t;
        int slice = u >> 7;                 // 0..23 = (vl, kcheb); wave-uniform
        int vl = slice / 3, kch = slice - vl * 3;
        int el = u & 127;                   // g*16 + i
        size_t rowg = (size_t)(v0 + vl) * 128;
        float val;
        if (kch == 0) val = x0[rowg + el];
        else if (kch == 1) val = x1[rowg + el];
        else {
            float acc = 0.f;
#pragma unroll
            for (int e = 0; e < DEG; ++e)
                acc = fmaf(sw[vl][e], x1[(size_t)sc[vl][e] * 128 + el], acc);
            val = 2.f * acc - x0[rowg + el];
        }
        __bf16 hi = (__bf16)val;
        __bf16 lo = (__bf16)(val - (float)hi);
        int tile = vl >> 1;
        int row = (vl & 1) * 8 + (el >> 4);
        int kcol = kch * 16 + (el & 15);
        s_hi[tile][row * 72 + kcol] = hi;
        s_lo[tile][row * 72 + kcol] = lo;
    }
    __syncthreads();
    const int wv = t >> 6, lane = t & 63;
    const int lrow = lane & 15, lkg = lane >> 4;
    // ---- phase A ----
    f32x4 acc[4] = {{0.f,0.f,0.f,0.f},{0.f,0.f,0.f,0.f},{0.f,0.f,0.f,0.f},{0.f,0.f,0.f,0.f}};
#pragma unroll
    for (int kt = 0; kt < 2; ++kt) {
        bf16x8 Ah = *(const bf16x8*)&s_hi[wv][lrow * 72 + kt * 32 + lkg * 8];
        bf16x8 Al = *(const bf16x8*)&s_lo[wv][lrow * 72 + kt * 32 + lkg * 8];
#pragma unroll
        for (int nt = 0; nt < 4; ++nt) {
            bf16x8 Wh = *(const bf16x8*)&pk[((kt * 4 + nt) * 64 + lane) * 8];
            bf16x8 Wl = *(const bf16x8*)&pk[4096 + ((kt * 4 + nt) * 64 + lane) * 8];
            acc[nt] = __builtin_amdgcn_mfma_f32_16x16x32_bf16(Ah, Wh, acc[nt], 0, 0, 0);
            acc[nt] = __builtin_amdgcn_mfma_f32_16x16x32_bf16(Al, Wh, acc[nt], 0, 0, 0);
            acc[nt] = __builtin_amdgcn_mfma_f32_16x16x32_bf16(Ah, Wl, acc[nt], 0, 0, 0);
        }
    }
    // bias + relu -> wave-private fp32 LDS (C layout: row=(lane>>4)*4+r, col=lane&15)
#pragma unroll
    for (int nt = 0; nt < 4; ++nt) {
        float bias = b2[nt * 16 + lrow];
#pragma unroll
        for (int r = 0; r < 4; ++r) {
            int row = lkg * 4 + r;
            sh2[wv][row * 68 + nt * 16 + lrow] = fmaxf(acc[nt][r] + bias, 0.f);
        }
    }
    // no barrier: tile is wave-private; compiler inserts lgkmcnt waits
    // ---- phase B ----
    f32x4 accy[3] = {{0.f,0.f,0.f,0.f},{0.f,0.f,0.f,0.f},{0.f,0.f,0.f,0.f}};
#pragma unroll
    for (int kt = 0; kt < 2; ++kt) {
        f32x4 f0 = *(const f32x4*)&sh2[wv][lrow * 68 + kt * 32 + lkg * 8];
        f32x4 f1 = *(const f32x4*)&sh2[wv][lrow * 68 + kt * 32 + lkg * 8 + 4];
        bf16x8 Ah, Al;
#pragma unroll
        for (int q = 0; q < 4; ++q) {
            float f = f0[q];
            __bf16 h = (__bf16)f;
            Ah[q] = h;
            Al[q] = (__bf16)(f - (float)h);
            f = f1[q];
            h = (__bf16)f;
            Ah[q + 4] = h;
            Al[q + 4] = (__bf16)(f - (float)h);
        }
#pragma unroll
        for (int nt = 0; nt < 3; ++nt) {
            bf16x8 Wh = *(const bf16x8*)&pk[8192 + ((kt * 3 + nt) * 64 + lane) * 8];
            bf16x8 Wl = *(const bf16x8*)&pk[11264 + ((kt * 3 + nt) * 64 + lane) * 8];
            accy[nt] = __builtin_amdgcn_mfma_f32_16x16x32_bf16(Ah, Wh, accy[nt], 0, 0, 0);
            accy[nt] = __builtin_amdgcn_mfma_f32_16x16x32_bf16(Al, Wh, accy[nt], 0, 0, 0);
            accy[nt] = __builtin_amdgcn_mfma_f32_16x16x32_bf16(Ah, Wl, accy[nt], 0, 0, 0);
        }
    }
    // store y: [V][k3*128 + g*16 + o3]
    const int vbase = v0 + wv * 2;
#pragma unroll
    for (int nt = 0; nt < 3; ++nt)
#pragma unroll
        for (int r = 0; r < 4; ++r) {
            int row = lkg * 4 + r;
            int v = vbase + (row >> 3), g = row & 7;
            y[(size_t)v * 384 + nt * 128 + g * 16 + lrow] = accy[nt][r];
        }
}

// ---------- legacy fp32 layer-2+y (used for G<8 fallback) ----------
template <int G>
__global__ __launch_bounds__(256) void k_fused2y(const float* __restrict__ x0,
                                                 const float* __restrict__ x1,
                                                 const int* __restrict__ col,
                                                 const float* __restrict__ ew,
                                                 const float* __restrict__ W2,
                                                 const float* __restrict__ b2,
                                                 const float* __restrict__ W3,
                                                 float* __restrict__ y) {
    constexpr int R = 16 * G;
    __shared__ float s[4][3 * R];
    __shared__ float sh2[4][G][64];
    __shared__ float sW2[3072];
    __shared__ float sW3[3072];
    __shared__ float sB[64];
    __shared__ int   sc[4][DEG];
    __shared__ float sw[4][DEG];
    const int t = threadIdx.x;
    const int v0 = blockIdx.x * 4;
    for (int j = t; j < 3072; j += 256) { sW2[j] = W2[j]; sW3[j] = W3[j]; }
    if (t < 64) sB[t] = b2[t];
    if (t < 32) {
        int vl = t >> 3, e = t & 7;
        sc[vl][e] = col[(v0 + vl) * DEG + e];
        sw[vl][e] = ew[(v0 + vl) * DEG + e];
    }
    __syncthreads();
    for (int u = t; u < 4 * R; u += 256) {
        int vl = u / R, el = u - vl * R;
        size_t row = (size_t)(v0 + vl) * R;
        float a0 = x0[row + el];
        float a1 = x1[row + el];
        s[vl][0 * R + el] = a0;
        s[vl][1 * R + el] = a1;
        float acc = 0.f;
#pragma unroll
        for (int e = 0; e < DEG; ++e)
            acc = fmaf(sw[vl][e], x1[(size_t)sc[vl][e] * R + el], acc);
        s[vl][2 * R + el] = 2.f * acc - a0;
    }
    __syncthreads();
    const int vl = t >> 6, o = t & 63;
    float wc[48];
#pragma unroll
    for (int k = 0; k < 3; ++k)
#pragma unroll
        for (int i = 0; i < 16; ++i)
            wc[k * 16 + i] = sW2[k * 1024 + i * 64 + o];
    float bias = sB[o];
#pragma unroll
    for (int g = 0; g < G; ++g) {
        float r = bias;
#pragma unroll
        for (int k = 0; k < 3; ++k) {
            const float4* ap = (const float4*)&s[vl][k * R + g * 16];
#pragma unroll
            for (int iq = 0; iq < 4; ++iq) {
                float4 a = ap[iq];
                r = fmaf(a.x, wc[k * 16 + iq * 4 + 0], r);
                r = fmaf(a.y, wc[k * 16 + iq * 4 + 1], r);
                r = fmaf(a.z, wc[k * 16 + iq * 4 + 2], r);
                r = fmaf(a.w, wc[k * 16 + iq * 4 + 3], r);
            }
        }
        sh2[vl][g][o] = fmaxf(r, 0.f);
    }
    __syncthreads();
    if (o < 48) {
        const int k3 = o >> 4, o3 = o & 15;
        float wy[64];
#pragma unroll
        for (int i = 0; i < 64; ++i)
            wy[i] = sW3[k3 * 1024 + i * 16 + o3];
        size_t yrow = (size_t)(v0 + vl) * (48 * G) + (size_t)k3 * (16 * G) + o3;
#pragma unroll
        for (int g = 0; g < G; ++g) {
            float r = 0.f;
            const float4* hp = (const float4*)&sh2[vl][g][0];
#pragma unroll
            for (int iq = 0; iq < 16; ++iq) {
                float4 h = hp[iq];
                r = fmaf(h.x, wy[iq * 4 + 0], r);
                r = fmaf(h.y, wy[iq * 4 + 1], r);
                r = fmaf(h.z, wy[iq * 4 + 2], r);
                r = fmaf(h.w, wy[iq * 4 + 3], r);
            }
            y[yrow + (size_t)g * 16] = r;
        }
    }
}

// ---------- final: gather L z2, combine layer-3, fuse layer-4 dot ----------
template <int G>
__global__ __launch_bounds__(256) void k_final_g(const float* __restrict__ y,
                                                 const float* __restrict__ z,
                                                 const int* __restrict__ col,
                                                 const float* __restrict__ ew,
                                                 const float* __restrict__ b3,
                                                 const float* __restrict__ w4,
                                                 const float* __restrict__ b4,
                                                 float* __restrict__ out, int b0) {
    int idx = blockIdx.x * 256 + threadIdx.x;   // over V*G
    int v = idx / G, g = idx - v * G;
    const size_t yr = (size_t)v * (48 * G) + g * 16;
    const size_t zr = (size_t)v * (32 * G) + g * 16;
    const int e0 = v * DEG;
    float4 acc[4];
#pragma unroll
    for (int q = 0; q < 4; ++q) acc[q] = make_float4(0.f, 0.f, 0.f, 0.f);
#pragma unroll
    for (int e = 0; e < DEG; ++e) {
        float wv = ew[e0 + e];
        const float* src = z + (size_t)col[e0 + e] * (32 * G) + 16 * G + g * 16;
#pragma unroll
        for (int q = 0; q < 4; ++q) {
            float4 u = *(const float4*)(src + q * 4);
            acc[q].x = fmaf(wv, u.x, acc[q].x);
            acc[q].y = fmaf(wv, u.y, acc[q].y);
            acc[q].z = fmaf(wv, u.z, acc[q].z);
            acc[q].w = fmaf(wv, u.w, acc[q].w);
        }
    }
    float r = b4[0];
#pragma unroll
    for (int q = 0; q < 4; ++q) {
        float4 y0v = *(const float4*)(y + yr + q * 4);
        float4 y2v = *(const float4*)(y + yr + (size_t)32 * G + q * 4);
        float4 z1v = *(const float4*)(z + zr + q * 4);
        const float* a = (const float*)&acc[q];
        const float* p0 = (const float*)&y0v;
        const float* p2 = (const float*)&y2v;
        const float* p1 = (const float*)&z1v;
#pragma unroll
        for (int j = 0; j < 4; ++j) {
            float h = p0[j] - p2[j] + p1[j] + 2.f * a[j] + b3[q * 4 + j];
            h = fmaxf(h, 0.f);
            r = fmaf(h, w4[q * 4 + j], r);
        }
    }
    out[(b0 + g) * V_N + v] = r;
}

// ---------- pipeline driver ----------
template <int G>
static void run_pipeline(const float* x, const int* ecol, const float* ew,
                         const float* w1, const float* b1, const float* w2, const float* b2,
                         const float* w3, const float* b3, const float* w4, const float* b4,
                         float* out, float* ws, hipStream_t stream) {
    const size_t GV = (size_t)G * V_N;
    float* xT   = ws;
    float* x1   = xT + GV;
    float* h1   = x1 + GV;
    float* x1b  = h1 + 16 * GV;
    float* y012 = x1b + 16 * GV;
    float* z12  = h1;              // reuse h1+x1b (32GV) after fused2y consumed them
    __bf16* pk  = (__bf16*)xT;     // xT dead after k_fused1; 28KB fits in GV floats
    dim3 blk(256);
    for (int b0 = 0; b0 < B_N; b0 += G) {
        k_transpose_g<G><<<(V_N * G) / 256, blk, 0, stream>>>(x, xT, b0);
        k_spmm_g<G><<<(V_N * G) / 256, blk, 0, stream>>>(xT, ecol, ew, x1);
        k_fused1_g<G><<<(V_N * G) / 256, blk, 0, stream>>>(xT, x1, ecol, ew, w1, b1, h1);
        if constexpr (G == 8) {
            k_prepack<<<1, 512, 0, stream>>>(w2, w3, pk);
            k_spmm_v<4 * G><<<(V_N * 4 * G) / 256, blk, 0, stream>>>(h1, ecol, ew, x1b);
            k_fused2y_mfma<<<V_N / 8, blk, 0, stream>>>(h1, x1b, ecol, ew, pk, b2, y012);
        } else {
            k_spmm_v<4 * G><<<(V_N * 4 * G) / 256, blk, 0, stream>>>(h1, ecol, ew, x1b);
            k_fused2y<G><<<V_N / 4, blk, 0, stream>>>(h1, x1b, ecol, ew, w2, b2, w3, y012);
        }
        // z12 = L [y1|y2]  (strided source: columns [16G,48G) of y012)
        k_spmm_vs<8 * G><<<(V_N * 8 * G) / 256, blk, 0, stream>>>(
            y012 + 16 * G, 48 * G, ecol, ew, z12, 32 * G);
        k_final_g<G><<<(V_N * G) / 256, blk, 0, stream>>>(y012, z12, ecol, ew, b3, w4, b4, out, b0);
    }
}

extern "C" void kernel_launch(void* const* d_in, const int* in_sizes, int n_in,
                              void* d_out, int out_size, void* d_ws, size_t ws_size,
                              hipStream_t stream) {
    const float* x = (const float*)d_in[0];
    // d_in[1] = edge_row = repeat(arange(V), 8) -> implicit, unused
    const int* ecol = (const int*)d_in[2];
    const float* ew = (const float*)d_in[3];
    const float* w1 = (const float*)d_in[4];
    const float* b1 = (const float*)d_in[5];
    const float* w2 = (const float*)d_in[6];
    const float* b2 = (const float*)d_in[7];
    const float* w3 = (const float*)d_in[8];
    const float* b3 = (const float*)d_in[9];
    const float* w4 = (const float*)d_in[10];
    const float* b4 = (const float*)d_in[11];
    float* out = (float*)d_out;
    float* ws = (float*)d_ws;

    auto need = [](int G) { return (size_t)82 * G * V_N * 4; };
    if (ws_size >= need(8))
        run_pipeline<8>(x, ecol, ew, w1, b1, w2, b2, w3, b3, w4, b4, out, ws, stream);
    else if (ws_size >= need(4))
        run_pipeline<4>(x, ecol, ew, w1, b1, w2, b2, w3, b3, w4, b4, out, ws, stream);
    else if (ws_size >= need(2))
        run_pipeline<2>(x, ecol, ew, w1, b1, w2, b2, w3, b3, w4, b4, out, ws, stream);
    else
        run_pipeline<1>(x, ecol, ew, w1, b1, w2, b2, w3, b3, w4, b4, out, ws, stream);
}

// Round 8
// 336.991 us; speedup vs baseline: 3.5541x; 1.3507x over previous
//
#include <hip/hip_runtime.h>

#define V_N 49152
#define B_N 16
#define DEG 8

typedef __bf16 bf16x8 __attribute__((ext_vector_type(8)));
typedef __bf16 bf16x4 __attribute__((ext_vector_type(4)));
typedef float f32x4 __attribute__((ext_vector_type(4)));

// ChebNet, batch-grouped (G=8 main path), all maps vertex-major.
// Layer 3 commuting trick: h3 = relu(y0 - y2 + L y1 + 2 L(L y2) + b3),
// yk = relu(h2).W3_k -> h2 never materialized.
// Gather-heavy buffers (x1b, y12, z2) stored bf16 (halves gather bytes);
// precision-critical paths (h1, y0-y2 combined, z1) stay fp32.

// ---------- transpose slice: x[B,V] -> xT[V][G] ----------
template <int G>
__global__ __launch_bounds__(256) void k_transpose_g(const float* __restrict__ x,
                                                     float* __restrict__ xT, int b0) {
    int idx = blockIdx.x * 256 + threadIdx.x;   // idx = g*V + v (coalesced read)
    int g = idx / V_N, v = idx - g * V_N;
    xT[v * G + g] = x[(b0 + g) * V_N + v];
}

// ---------- scalar spmm, row width G ----------
template <int G>
__global__ __launch_bounds__(256) void k_spmm_g(const float* __restrict__ xin,
                                                const int* __restrict__ col,
                                                const float* __restrict__ ew,
                                                float* __restrict__ xout) {
    int idx = blockIdx.x * 256 + threadIdx.x;   // over V*G
    int v = idx / G, b = idx - v * G;
    const int e0 = v * DEG;
    float acc = 0.f;
#pragma unroll
    for (int e = 0; e < DEG; ++e)
        acc = fmaf(ew[e0 + e], xin[col[e0 + e] * G + b], acc);
    xout[idx] = acc;
}

// ---------- vec4 spmm fp32 (fallback path) ----------
template <int W4>
__global__ __launch_bounds__(256) void k_spmm_v(const float* __restrict__ xin,
                                                const int* __restrict__ col,
                                                const float* __restrict__ ew,
                                                float* __restrict__ xout) {
    int idx = blockIdx.x * 256 + threadIdx.x;
    int v = idx / W4;
    int c = (idx - v * W4) * 4;
    const int e0 = v * DEG;
    float4 acc = make_float4(0.f, 0.f, 0.f, 0.f);
#pragma unroll
    for (int e = 0; e < DEG; ++e) {
        float wv = ew[e0 + e];
        const float4 u = *(const float4*)&xin[(size_t)col[e0 + e] * (W4 * 4) + c];
        acc.x = fmaf(wv, u.x, acc.x);
        acc.y = fmaf(wv, u.y, acc.y);
        acc.z = fmaf(wv, u.z, acc.z);
        acc.w = fmaf(wv, u.w, acc.w);
    }
    *(float4*)&xout[(size_t)v * (W4 * 4) + c] = acc;
}

// ---------- vec4 spmm, strided rows (fallback path) ----------
template <int W4>
__global__ __launch_bounds__(256) void k_spmm_vs(const float* __restrict__ xin,
                                                 int in_stride,
                                                 const int* __restrict__ col,
                                                 const float* __restrict__ ew,
                                                 float* __restrict__ xout,
                                                 int out_stride) {
    int idx = blockIdx.x * 256 + threadIdx.x;
    int v = idx / W4;
    int c = (idx - v * W4) * 4;
    const int e0 = v * DEG;
    float4 acc = make_float4(0.f, 0.f, 0.f, 0.f);
#pragma unroll
    for (int e = 0; e < DEG; ++e) {
        float wv = ew[e0 + e];
        const float4 u = *(const float4*)&xin[(size_t)col[e0 + e] * in_stride + c];
        acc.x = fmaf(wv, u.x, acc.x);
        acc.y = fmaf(wv, u.y, acc.y);
        acc.z = fmaf(wv, u.z, acc.z);
        acc.w = fmaf(wv, u.w, acc.w);
    }
    *(float4*)&xout[(size_t)v * out_stride + c] = acc;
}

// ---------- layer 1 fused: gather x2, einsum Fin=1 -> Fout=16, relu ----------
template <int G>
__global__ __launch_bounds__(256) void k_fused1_g(const float* __restrict__ x0,
                                                  const float* __restrict__ x1,
                                                  const int* __restrict__ col,
                                                  const float* __restrict__ ew,
                                                  const float* __restrict__ W,   // [3][1][16]
                                                  const float* __restrict__ bias,// [16]
                                                  float* __restrict__ out) {     // h1 [V][16G]
    int idx = blockIdx.x * 256 + threadIdx.x;   // (v, g)
    int v = idx / G;
    float a0 = x0[idx], a1 = x1[idx];
    const int e0 = v * DEG;
    float acc = 0.f;
#pragma unroll
    for (int e = 0; e < DEG; ++e)
        acc = fmaf(ew[e0 + e], x1[col[e0 + e] * G + (idx - v * G)], acc);
    float a2 = 2.f * acc - a0;
    float4* dst = (float4*)&out[(size_t)idx * 16];
#pragma unroll
    for (int oq = 0; oq < 4; ++oq) {
        float4 r;
        float* rp = (float*)&r;
#pragma unroll
        for (int j = 0; j < 4; ++j) {
            int o = oq * 4 + j;
            rp[j] = fmaxf(fmaf(a0, W[o], fmaf(a1, W[16 + o], fmaf(a2, W[32 + o], bias[o]))), 0.f);
        }
        dst[oq] = r;
    }
}

// ---------- x1b = L h1, fp32 in -> bf16 out (width 128) ----------
__global__ __launch_bounds__(256) void k_spmm_f2b(const float* __restrict__ xin,  // h1 [V][128]
                                                  const int* __restrict__ col,
                                                  const float* __restrict__ ew,
                                                  __bf16* __restrict__ xout) {    // [V][128] bf16
    int idx = blockIdx.x * 256 + threadIdx.x;   // over V*32
    int v = idx >> 5;
    int c = (idx & 31) * 4;
    const int e0 = v * DEG;
    float4 acc = make_float4(0.f, 0.f, 0.f, 0.f);
#pragma unroll
    for (int e = 0; e < DEG; ++e) {
        float wv = ew[e0 + e];
        const float4 u = *(const float4*)&xin[(size_t)col[e0 + e] * 128 + c];
        acc.x = fmaf(wv, u.x, acc.x);
        acc.y = fmaf(wv, u.y, acc.y);
        acc.z = fmaf(wv, u.z, acc.z);
        acc.w = fmaf(wv, u.w, acc.w);
    }
    bf16x4 o;
    o[0] = (__bf16)acc.x; o[1] = (__bf16)acc.y; o[2] = (__bf16)acc.z; o[3] = (__bf16)acc.w;
    *(bf16x4*)&xout[(size_t)v * 128 + c] = o;
}

// ---------- z = L [y1|y2]: bf16 in, z1 fp32 + z2 bf16 out ----------
__global__ __launch_bounds__(256) void k_spmm_z(const __bf16* __restrict__ y12,  // [V][256] bf16
                                                const int* __restrict__ col,
                                                const float* __restrict__ ew,
                                                float* __restrict__ z1,          // [V][128] f32
                                                __bf16* __restrict__ z2) {       // [V][128] bf16
    int idx = blockIdx.x * 256 + threadIdx.x;   // over V*64
    int v = idx >> 6;
    int c = (idx & 63) * 4;                     // [0,256)
    const int e0 = v * DEG;
    float4 acc = make_float4(0.f, 0.f, 0.f, 0.f);
#pragma unroll
    for (int e = 0; e < DEG; ++e) {
        float wv = ew[e0 + e];
        bf16x4 u = *(const bf16x4*)&y12[(size_t)col[e0 + e] * 256 + c];
        acc.x = fmaf(wv, (float)u[0], acc.x);
        acc.y = fmaf(wv, (float)u[1], acc.y);
        acc.z = fmaf(wv, (float)u[2], acc.z);
        acc.w = fmaf(wv, (float)u[3], acc.w);
    }
    if (c < 128) {
        *(float4*)&z1[(size_t)v * 128 + c] = acc;
    } else {
        bf16x4 o;
        o[0] = (__bf16)acc.x; o[1] = (__bf16)acc.y; o[2] = (__bf16)acc.z; o[3] = (__bf16)acc.w;
        *(bf16x4*)&z2[(size_t)v * 128 + (c - 128)] = o;
    }
}

// ---------- weight prepack into MFMA B-fragment layout (hi/lo split) ----------
// pk: [0,4096)=W2hi  [4096,8192)=W2lo  [8192,11264)=W3hi  [11264,14336)=W3lo
__global__ __launch_bounds__(512) void k_prepack(const float* __restrict__ w2,
                                                 const float* __restrict__ w3,
                                                 __bf16* __restrict__ pk) {
    int t = threadIdx.x;
    {
        int kt = t >> 8, nt = (t >> 6) & 3, lane = t & 63;
#pragma unroll
        for (int e = 0; e < 8; ++e) {
            int k = kt * 32 + ((lane >> 4) * 8) + e;
            float val = (k < 48) ? w2[(k >> 4) * 1024 + (k & 15) * 64 + nt * 16 + (lane & 15)] : 0.f;
            __bf16 hi = (__bf16)val;
            pk[t * 8 + e] = hi;
            pk[4096 + t * 8 + e] = (__bf16)(val - (float)hi);
        }
    }
    if (t < 384) {
        int kt = t / 192, nt = (t / 64) % 3, lane = t & 63;
#pragma unroll
        for (int e = 0; e < 8; ++e) {
            int k = kt * 32 + ((lane >> 4) * 8) + e;
            float val = w3[nt * 1024 + k * 16 + (lane & 15)];
            __bf16 hi = (__bf16)val;
            pk[8192 + t * 8 + e] = hi;
            pk[11264 + t * 8 + e] = (__bf16)(val - (float)hi);
        }
    }
}

// ---------- layer 2 + y projection via split-bf16 MFMA (G=8 only) ----------
// Outputs: y02 = y0 - y2 (fp32, direct-use term) and y12 = [y1|y2] (bf16, gathered).
__global__ __launch_bounds__(256) void k_fused2y_mfma(const float* __restrict__ x0,  // h1 [V][128] f32
                                                      const __bf16* __restrict__ x1, // x1b [V][128] bf16
                                                      const int* __restrict__ col,
                                                      const float* __restrict__ ew,
                                                      const __bf16* __restrict__ pk,
                                                      const float* __restrict__ b2,  // [64]
                                                      float* __restrict__ y02,       // [V][128] f32
                                                      __bf16* __restrict__ y12) {    // [V][256] bf16
    __shared__ __attribute__((aligned(16))) __bf16 s_hi[4][16 * 72];
    __shared__ __attribute__((aligned(16))) __bf16 s_lo[4][16 * 72];
    __shared__ __attribute__((aligned(16))) float  sh2[4][16 * 68];
    __shared__ int   sc[8][8];
    __shared__ float sw[8][8];
    const int t = threadIdx.x;
    const int v0 = blockIdx.x * 8;
    if (t < 64) {
        int vl = t >> 3, e = t & 7;
        sc[vl][e] = col[(v0 + vl) * DEG + e];
        sw[vl][e] = ew[(v0 + vl) * DEG + e];
    }
    __syncthreads();
    // zero K-pad (kcol 48..63)
    for (int u = t; u < 4 * 16 * 16; u += 256) {
        int tile = u >> 8, row = (u >> 4) & 15, i = u & 15;
        s_hi[tile][row * 72 + 48 + i] = (__bf16)0.f;
        s_lo[tile][row * 72 + 48 + i] = (__bf16)0.f;
    }
    // stage x0, x1 (bf16), gathered x2 = 2 L x1 - x0 as hi/lo A-fragments
#pragma unroll
    for (int j = 0; j < 12; ++j) {
        int u = j * 256 + t;
        int slice = u >> 7;                 // 0..23 = (vl, kcheb); wave-uniform
        int vl = slice / 3, kch = slice - vl * 3;
        int el = u & 127;
        size_t rowg = (size_t)(v0 + vl) * 128;
        __bf16 hi, lo;
        if (kch == 0) {
            float val = x0[rowg + el];
            hi = (__bf16)val;
            lo = (__bf16)(val - (float)hi);
        } else if (kch == 1) {
            hi = x1[rowg + el];
            lo = (__bf16)0.f;
        } else {
            float acc = 0.f;
#pragma unroll
            for (int e = 0; e < DEG; ++e)
                acc = fmaf(sw[vl][e], (float)x1[(size_t)sc[vl][e] * 128 + el], acc);
            float val = 2.f * acc - x0[rowg + el];
            hi = (__bf16)val;
            lo = (__bf16)(val - (float)hi);
        }
        int tile = vl >> 1;
        int row = (vl & 1) * 8 + (el >> 4);
        int kcol = kch * 16 + (el & 15);
        s_hi[tile][row * 72 + kcol] = hi;
        s_lo[tile][row * 72 + kcol] = lo;
    }
    __syncthreads();
    const int wv = t >> 6, lane = t & 63;
    const int lrow = lane & 15, lkg = lane >> 4;
    // ---- phase A: h2 = relu(x.W2 + b2) ----
    f32x4 acc[4] = {{0.f,0.f,0.f,0.f},{0.f,0.f,0.f,0.f},{0.f,0.f,0.f,0.f},{0.f,0.f,0.f,0.f}};
#pragma unroll
    for (int kt = 0; kt < 2; ++kt) {
        bf16x8 Ah = *(const bf16x8*)&s_hi[wv][lrow * 72 + kt * 32 + lkg * 8];
        bf16x8 Al = *(const bf16x8*)&s_lo[wv][lrow * 72 + kt * 32 + lkg * 8];
#pragma unroll
        for (int nt = 0; nt < 4; ++nt) {
            bf16x8 Wh = *(const bf16x8*)&pk[((kt * 4 + nt) * 64 + lane) * 8];
            bf16x8 Wl = *(const bf16x8*)&pk[4096 + ((kt * 4 + nt) * 64 + lane) * 8];
            acc[nt] = __builtin_amdgcn_mfma_f32_16x16x32_bf16(Ah, Wh, acc[nt], 0, 0, 0);
            acc[nt] = __builtin_amdgcn_mfma_f32_16x16x32_bf16(Al, Wh, acc[nt], 0, 0, 0);
            acc[nt] = __builtin_amdgcn_mfma_f32_16x16x32_bf16(Ah, Wl, acc[nt], 0, 0, 0);
        }
    }
#pragma unroll
    for (int nt = 0; nt < 4; ++nt) {
        float bias = b2[nt * 16 + lrow];
#pragma unroll
        for (int r = 0; r < 4; ++r) {
            int row = lkg * 4 + r;
            sh2[wv][row * 68 + nt * 16 + lrow] = fmaxf(acc[nt][r] + bias, 0.f);
        }
    }
    // wave-private tile: no barrier needed
    // ---- phase B: y = h2 . W3 ----
    f32x4 accy[3] = {{0.f,0.f,0.f,0.f},{0.f,0.f,0.f,0.f},{0.f,0.f,0.f,0.f}};
#pragma unroll
    for (int kt = 0; kt < 2; ++kt) {
        f32x4 f0 = *(const f32x4*)&sh2[wv][lrow * 68 + kt * 32 + lkg * 8];
        f32x4 f1 = *(const f32x4*)&sh2[wv][lrow * 68 + kt * 32 + lkg * 8 + 4];
        bf16x8 Ah, Al;
#pragma unroll
        for (int q = 0; q < 4; ++q) {
            float f = f0[q];
            __bf16 h = (__bf16)f;
            Ah[q] = h;
            Al[q] = (__bf16)(f - (float)h);
            f = f1[q];
            h = (__bf16)f;
            Ah[q + 4] = h;
            Al[q + 4] = (__bf16)(f - (float)h);
        }
#pragma unroll
        for (int nt = 0; nt < 3; ++nt) {
            bf16x8 Wh = *(const bf16x8*)&pk[8192 + ((kt * 3 + nt) * 64 + lane) * 8];
            bf16x8 Wl = *(const bf16x8*)&pk[11264 + ((kt * 3 + nt) * 64 + lane) * 8];
            accy[nt] = __builtin_amdgcn_mfma_f32_16x16x32_bf16(Ah, Wh, accy[nt], 0, 0, 0);
            accy[nt] = __builtin_amdgcn_mfma_f32_16x16x32_bf16(Al, Wh, accy[nt], 0, 0, 0);
            accy[nt] = __builtin_amdgcn_mfma_f32_16x16x32_bf16(Ah, Wl, accy[nt], 0, 0, 0);
        }
    }
    // store: y02 = y0 - y2 (fp32); y12 = [y1 | y2] (bf16)
    const int vbase = v0 + wv * 2;
#pragma unroll
    for (int r = 0; r < 4; ++r) {
        int row = lkg * 4 + r;
        int v = vbase + (row >> 3), g = row & 7;
        y02[(size_t)v * 128 + g * 16 + lrow] = accy[0][r] - accy[2][r];
        y12[(size_t)v * 256 + g * 16 + lrow] = (__bf16)accy[1][r];
        y12[(size_t)v * 256 + 128 + g * 16 + lrow] = (__bf16)accy[2][r];
    }
}

// ---------- final (G=8): gather L z2 (bf16), combine layer-3, layer-4 dot ----------
__global__ __launch_bounds__(256) void k_final_gb(const float* __restrict__ y02, // [V][128] f32
                                                  const float* __restrict__ z1,  // [V][128] f32
                                                  const __bf16* __restrict__ z2, // [V][128] bf16
                                                  const int* __restrict__ col,
                                                  const float* __restrict__ ew,
                                                  const float* __restrict__ b3,  // [16]
                                                  const float* __restrict__ w4,  // [16]
                                                  const float* __restrict__ b4,  // [1]
                                                  float* __restrict__ out, int b0) {
    int idx = blockIdx.x * 256 + threadIdx.x;   // over V*8
    int v = idx >> 3, g = idx & 7;
    const int e0 = v * DEG;
    float acc[16];
#pragma unroll
    for (int j = 0; j < 16; ++j) acc[j] = 0.f;
#pragma unroll
    for (int e = 0; e < DEG; ++e) {
        float wv = ew[e0 + e];
        const __bf16* src = z2 + (size_t)col[e0 + e] * 128 + g * 16;
        bf16x8 u0 = *(const bf16x8*)src;
        bf16x8 u1 = *(const bf16x8*)(src + 8);
#pragma unroll
        for (int j = 0; j < 8; ++j) {
            acc[j] = fmaf(wv, (float)u0[j], acc[j]);
            acc[8 + j] = fmaf(wv, (float)u1[j], acc[8 + j]);
        }
    }
    const float4* yp = (const float4*)&y02[(size_t)v * 128 + g * 16];
    const float4* zp = (const float4*)&z1[(size_t)v * 128 + g * 16];
    float r = b4[0];
#pragma unroll
    for (int q = 0; q < 4; ++q) {
        float4 yv = yp[q], zv = zp[q];
        const float* py = (const float*)&yv;
        const float* pz = (const float*)&zv;
#pragma unroll
        for (int j = 0; j < 4; ++j) {
            float h = py[j] + pz[j] + 2.f * acc[q * 4 + j] + b3[q * 4 + j];
            h = fmaxf(h, 0.f);
            r = fmaf(h, w4[q * 4 + j], r);
        }
    }
    out[(b0 + g) * V_N + v] = r;
}

// ---------- legacy fp32 layer-2+y (G<8 fallback) ----------
template <int G>
__global__ __launch_bounds__(256) void k_fused2y(const float* __restrict__ x0,
                                                 const float* __restrict__ x1,
                                                 const int* __restrict__ col,
                                                 const float* __restrict__ ew,
                                                 const float* __restrict__ W2,
                                                 const float* __restrict__ b2,
                                                 const float* __restrict__ W3,
                                                 float* __restrict__ y) {
    constexpr int R = 16 * G;
    __shared__ float s[4][3 * R];
    __shared__ float sh2[4][G][64];
    __shared__ float sW2[3072];
    __shared__ float sW3[3072];
    __shared__ float sB[64];
    __shared__ int   sc[4][DEG];
    __shared__ float sw[4][DEG];
    const int t = threadIdx.x;
    const int v0 = blockIdx.x * 4;
    for (int j = t; j < 3072; j += 256) { sW2[j] = W2[j]; sW3[j] = W3[j]; }
    if (t < 64) sB[t] = b2[t];
    if (t < 32) {
        int vl = t >> 3, e = t & 7;
        sc[vl][e] = col[(v0 + vl) * DEG + e];
        sw[vl][e] = ew[(v0 + vl) * DEG + e];
    }
    __syncthreads();
    for (int u = t; u < 4 * R; u += 256) {
        int vl = u / R, el = u - vl * R;
        size_t row = (size_t)(v0 + vl) * R;
        float a0 = x0[row + el];
        float a1 = x1[row + el];
        s[vl][0 * R + el] = a0;
        s[vl][1 * R + el] = a1;
        float acc = 0.f;
#pragma unroll
        for (int e = 0; e < DEG; ++e)
            acc = fmaf(sw[vl][e], x1[(size_t)sc[vl][e] * R + el], acc);
        s[vl][2 * R + el] = 2.f * acc - a0;
    }
    __syncthreads();
    const int vl = t >> 6, o = t & 63;
    float wc[48];
#pragma unroll
    for (int k = 0; k < 3; ++k)
#pragma unroll
        for (int i = 0; i < 16; ++i)
            wc[k * 16 + i] = sW2[k * 1024 + i * 64 + o];
    float bias = sB[o];
#pragma unroll
    for (int g = 0; g < G; ++g) {
        float r = bias;
#pragma unroll
        for (int k = 0; k < 3; ++k) {
            const float4* ap = (const float4*)&s[vl][k * R + g * 16];
#pragma unroll
            for (int iq = 0; iq < 4; ++iq) {
                float4 a = ap[iq];
                r = fmaf(a.x, wc[k * 16 + iq * 4 + 0], r);
                r = fmaf(a.y, wc[k * 16 + iq * 4 + 1], r);
                r = fmaf(a.z, wc[k * 16 + iq * 4 + 2], r);
                r = fmaf(a.w, wc[k * 16 + iq * 4 + 3], r);
            }
        }
        sh2[vl][g][o] = fmaxf(r, 0.f);
    }
    __syncthreads();
    if (o < 48) {
        const int k3 = o >> 4, o3 = o & 15;
        float wy[64];
#pragma unroll
        for (int i = 0; i < 64; ++i)
            wy[i] = sW3[k3 * 1024 + i * 16 + o3];
        size_t yrow = (size_t)(v0 + vl) * (48 * G) + (size_t)k3 * (16 * G) + o3;
#pragma unroll
        for (int g = 0; g < G; ++g) {
            float r = 0.f;
            const float4* hp = (const float4*)&sh2[vl][g][0];
#pragma unroll
            for (int iq = 0; iq < 16; ++iq) {
                float4 h = hp[iq];
                r = fmaf(h.x, wy[iq * 4 + 0], r);
                r = fmaf(h.y, wy[iq * 4 + 1], r);
                r = fmaf(h.z, wy[iq * 4 + 2], r);
                r = fmaf(h.w, wy[iq * 4 + 3], r);
            }
            y[yrow + (size_t)g * 16] = r;
        }
    }
}

// ---------- legacy final (G<8 fallback) ----------
template <int G>
__global__ __launch_bounds__(256) void k_final_g(const float* __restrict__ y,
                                                 const float* __restrict__ z,
                                                 const int* __restrict__ col,
                                                 const float* __restrict__ ew,
                                                 const float* __restrict__ b3,
                                                 const float* __restrict__ w4,
                                                 const float* __restrict__ b4,
                                                 float* __restrict__ out, int b0) {
    int idx = blockIdx.x * 256 + threadIdx.x;   // over V*G
    int v = idx / G, g = idx - v * G;
    const size_t yr = (size_t)v * (48 * G) + g * 16;
    const size_t zr = (size_t)v * (32 * G) + g * 16;
    const int e0 = v * DEG;
    float4 acc[4];
#pragma unroll
    for (int q = 0; q < 4; ++q) acc[q] = make_float4(0.f, 0.f, 0.f, 0.f);
#pragma unroll
    for (int e = 0; e < DEG; ++e) {
        float wv = ew[e0 + e];
        const float* src = z + (size_t)col[e0 + e] * (32 * G) + 16 * G + g * 16;
#pragma unroll
        for (int q = 0; q < 4; ++q) {
            float4 u = *(const float4*)(src + q * 4);
            acc[q].x = fmaf(wv, u.x, acc[q].x);
            acc[q].y = fmaf(wv, u.y, acc[q].y);
            acc[q].z = fmaf(wv, u.z, acc[q].z);
            acc[q].w = fmaf(wv, u.w, acc[q].w);
        }
    }
    float r = b4[0];
#pragma unroll
    for (int q = 0; q < 4; ++q) {
        float4 y0v = *(const float4*)(y + yr + q * 4);
        float4 y2v = *(const float4*)(y + yr + (size_t)32 * G + q * 4);
        float4 z1v = *(const float4*)(z + zr + q * 4);
        const float* a = (const float*)&acc[q];
        const float* p0 = (const float*)&y0v;
        const float* p2 = (const float*)&y2v;
        const float* p1 = (const float*)&z1v;
#pragma unroll
        for (int j = 0; j < 4; ++j) {
            float h = p0[j] - p2[j] + p1[j] + 2.f * a[j] + b3[q * 4 + j];
            h = fmaxf(h, 0.f);
            r = fmaf(h, w4[q * 4 + j], r);
        }
    }
    out[(b0 + g) * V_N + v] = r;
}

// ---------- pipeline driver ----------
template <int G>
static void run_pipeline(const float* x, const int* ecol, const float* ew,
                         const float* w1, const float* b1, const float* w2, const float* b2,
                         const float* w3, const float* b3, const float* w4, const float* b4,
                         float* out, float* ws, hipStream_t stream) {
    const size_t V = V_N;
    dim3 blk(256);
    if constexpr (G == 8) {
        // layout (floats): xT 8V | x1 8V | h1 128V | x1b 64V(bf16 128V) |
        //                  y02 128V | y12 128V(bf16 256V)   total 464V = 91MB
        float*  xT  = ws;
        float*  x1  = xT + 8 * V;
        float*  h1  = x1 + 8 * V;
        __bf16* x1b = (__bf16*)(h1 + 128 * V);
        float*  y02 = h1 + 192 * V;
        __bf16* y12 = (__bf16*)(y02 + 128 * V);
        float*  z1  = h1;            // reuse h1 region after fused2y
        __bf16* z2  = x1b;           // reuse x1b region after fused2y
        __bf16* pk  = (__bf16*)xT;   // xT dead after k_fused1 (28KB)
        for (int b0 = 0; b0 < B_N; b0 += 8) {
            k_transpose_g<8><<<(V * 8) / 256, blk, 0, stream>>>(x, xT, b0);
            k_spmm_g<8><<<(V * 8) / 256, blk, 0, stream>>>(xT, ecol, ew, x1);
            k_fused1_g<8><<<(V * 8) / 256, blk, 0, stream>>>(xT, x1, ecol, ew, w1, b1, h1);
            k_prepack<<<1, 512, 0, stream>>>(w2, w3, pk);
            k_spmm_f2b<<<(V * 32) / 256, blk, 0, stream>>>(h1, ecol, ew, x1b);
            k_fused2y_mfma<<<V / 8, blk, 0, stream>>>(h1, x1b, ecol, ew, pk, b2, y02, y12);
            k_spmm_z<<<(V * 64) / 256, blk, 0, stream>>>(y12, ecol, ew, z1, z2);
            k_final_gb<<<(V * 8) / 256, blk, 0, stream>>>(y02, z1, z2, ecol, ew, b3, w4, b4, out, b0);
        }
    } else {
        const size_t GV = (size_t)G * V;
        float* xT   = ws;
        float* x1   = xT + GV;
        float* h1   = x1 + GV;
        float* x1b  = h1 + 16 * GV;
        float* y012 = x1b + 16 * GV;
        float* z12  = h1;
        for (int b0 = 0; b0 < B_N; b0 += G) {
            k_transpose_g<G><<<(V * G) / 256, blk, 0, stream>>>(x, xT, b0);
            k_spmm_g<G><<<(V * G) / 256, blk, 0, stream>>>(xT, ecol, ew, x1);
            k_fused1_g<G><<<(V * G) / 256, blk, 0, stream>>>(xT, x1, ecol, ew, w1, b1, h1);
            k_spmm_v<4 * G><<<(V * 4 * G) / 256, blk, 0, stream>>>(h1, ecol, ew, x1b);
            k_fused2y<G><<<V / 4, blk, 0, stream>>>(h1, x1b, ecol, ew, w2, b2, w3, y012);
            k_spmm_vs<8 * G><<<(V * 8 * G) / 256, blk, 0, stream>>>(
                y012 + 16 * G, 48 * G, ecol, ew, z12, 32 * G);
            k_final_g<G><<<(V * G) / 256, blk, 0, stream>>>(y012, z12, ecol, ew, b3, w4, b4, out, b0);
        }
    }
}

extern "C" void kernel_launch(void* const* d_in, const int* in_sizes, int n_in,
                              void* d_out, int out_size, void* d_ws, size_t ws_size,
                              hipStream_t stream) {
    const float* x = (const float*)d_in[0];
    // d_in[1] = edge_row = repeat(arange(V), 8) -> implicit, unused
    const int* ecol = (const int*)d_in[2];
    const float* ew = (const float*)d_in[3];
    const float* w1 = (const float*)d_in[4];
    const float* b1 = (const float*)d_in[5];
    const float* w2 = (const float*)d_in[6];
    const float* b2 = (const float*)d_in[7];
    const float* w3 = (const float*)d_in[8];
    const float* b3 = (const float*)d_in[9];
    const float* w4 = (const float*)d_in[10];
    const float* b4 = (const float*)d_in[11];
    float* out = (float*)d_out;
    float* ws = (float*)d_ws;

    auto need = [](int G) { return (size_t)82 * G * V_N * 4; };
    if (ws_size >= need(8))
        run_pipeline<8>(x, ecol, ew, w1, b1, w2, b2, w3, b3, w4, b4, out, ws, stream);
    else if (ws_size >= need(4))
        run_pipeline<4>(x, ecol, ew, w1, b1, w2, b2, w3, b3, w4, b4, out, ws, stream);
    else if (ws_size >= need(2))
        run_pipeline<2>(x, ecol, ew, w1, b1, w2, b2, w3, b3, w4, b4, out, ws, stream);
    else
        run_pipeline<1>(x, ecol, ew, w1, b1, w2, b2, w3, b3, w4, b4, out, ws, stream);
}

// Round 10
// 267.371 us; speedup vs baseline: 4.4796x; 1.2604x over previous
//
#include <hip/hip_runtime.h>

#define V_N 49152
#define B_N 16
#define DEG 8

typedef __bf16 bf16x8 __attribute__((ext_vector_type(8)));
typedef __bf16 bf16x4 __attribute__((ext_vector_type(4)));
typedef __bf16 bf16x2 __attribute__((ext_vector_type(2)));
typedef float f32x4 __attribute__((ext_vector_type(4)));

// ChebNet, batch-grouped (G=8 main path), all maps vertex-major.
// Layer 3 commuting trick + linearity fold:
//   h3 = relu(y0 - y2 + L(y1 + 2 L y2) + b3),  yk = relu(h2).W3_k
// so h2 is never materialized and only ONE width-16 buffer (u) is gathered
// after fused2y. Gathered buffers (x1b, y2, u) are bf16; direct-use terms
// (h1, y02 = y0-y2) stay fp32.

// ---------- transpose slice: x[B,V] -> xT[V][G] ----------
template <int G>
__global__ __launch_bounds__(256) void k_transpose_g(const float* __restrict__ x,
                                                     float* __restrict__ xT, int b0) {
    int idx = blockIdx.x * 256 + threadIdx.x;   // idx = g*V + v (coalesced read)
    int g = idx / V_N, v = idx - g * V_N;
    xT[v * G + g] = x[(b0 + g) * V_N + v];
}

// ---------- scalar spmm, row width G ----------
template <int G>
__global__ __launch_bounds__(256) void k_spmm_g(const float* __restrict__ xin,
                                                const int* __restrict__ col,
                                                const float* __restrict__ ew,
                                                float* __restrict__ xout) {
    int idx = blockIdx.x * 256 + threadIdx.x;   // over V*G
    int v = idx / G, b = idx - v * G;
    const int e0 = v * DEG;
    float acc = 0.f;
#pragma unroll
    for (int e = 0; e < DEG; ++e)
        acc = fmaf(ew[e0 + e], xin[col[e0 + e] * G + b], acc);
    xout[idx] = acc;
}

// ---------- vec4 spmm fp32 (fallback path) ----------
template <int W4>
__global__ __launch_bounds__(256) void k_spmm_v(const float* __restrict__ xin,
                                                const int* __restrict__ col,
                                                const float* __restrict__ ew,
                                                float* __restrict__ xout) {
    int idx = blockIdx.x * 256 + threadIdx.x;
    int v = idx / W4;
    int c = (idx - v * W4) * 4;
    const int e0 = v * DEG;
    float4 acc = make_float4(0.f, 0.f, 0.f, 0.f);
#pragma unroll
    for (int e = 0; e < DEG; ++e) {
        float wv = ew[e0 + e];
        const float4 u = *(const float4*)&xin[(size_t)col[e0 + e] * (W4 * 4) + c];
        acc.x = fmaf(wv, u.x, acc.x);
        acc.y = fmaf(wv, u.y, acc.y);
        acc.z = fmaf(wv, u.z, acc.z);
        acc.w = fmaf(wv, u.w, acc.w);
    }
    *(float4*)&xout[(size_t)v * (W4 * 4) + c] = acc;
}

// ---------- vec4 spmm, strided rows (fallback path) ----------
template <int W4>
__global__ __launch_bounds__(256) void k_spmm_vs(const float* __restrict__ xin,
                                                 int in_stride,
                                                 const int* __restrict__ col,
                                                 const float* __restrict__ ew,
                                                 float* __restrict__ xout,
                                                 int out_stride) {
    int idx = blockIdx.x * 256 + threadIdx.x;
    int v = idx / W4;
    int c = (idx - v * W4) * 4;
    const int e0 = v * DEG;
    float4 acc = make_float4(0.f, 0.f, 0.f, 0.f);
#pragma unroll
    for (int e = 0; e < DEG; ++e) {
        float wv = ew[e0 + e];
        const float4 u = *(const float4*)&xin[(size_t)col[e0 + e] * in_stride + c];
        acc.x = fmaf(wv, u.x, acc.x);
        acc.y = fmaf(wv, u.y, acc.y);
        acc.z = fmaf(wv, u.z, acc.z);
        acc.w = fmaf(wv, u.w, acc.w);
    }
    *(float4*)&xout[(size_t)v * out_stride + c] = acc;
}

// ---------- layer 1 fused: gather x2, einsum Fin=1 -> Fout=16, relu ----------
template <int G>
__global__ __launch_bounds__(256) void k_fused1_g(const float* __restrict__ x0,
                                                  const float* __restrict__ x1,
                                                  const int* __restrict__ col,
                                                  const float* __restrict__ ew,
                                                  const float* __restrict__ W,   // [3][1][16]
                                                  const float* __restrict__ bias,// [16]
                                                  float* __restrict__ out) {     // h1 [V][16G]
    int idx = blockIdx.x * 256 + threadIdx.x;   // (v, g)
    int v = idx / G;
    float a0 = x0[idx], a1 = x1[idx];
    const int e0 = v * DEG;
    float acc = 0.f;
#pragma unroll
    for (int e = 0; e < DEG; ++e)
        acc = fmaf(ew[e0 + e], x1[col[e0 + e] * G + (idx - v * G)], acc);
    float a2 = 2.f * acc - a0;
    float4* dst = (float4*)&out[(size_t)idx * 16];
#pragma unroll
    for (int oq = 0; oq < 4; ++oq) {
        float4 r;
        float* rp = (float*)&r;
#pragma unroll
        for (int j = 0; j < 4; ++j) {
            int o = oq * 4 + j;
            rp[j] = fmaxf(fmaf(a0, W[o], fmaf(a1, W[16 + o], fmaf(a2, W[32 + o], bias[o]))), 0.f);
        }
        dst[oq] = r;
    }
}

// ---------- x1b = L h1, fp32 in -> bf16 out (width 128) ----------
__global__ __launch_bounds__(256) void k_spmm_f2b(const float* __restrict__ xin,  // h1 [V][128]
                                                  const int* __restrict__ col,
                                                  const float* __restrict__ ew,
                                                  __bf16* __restrict__ xout) {    // [V][128] bf16
    int idx = blockIdx.x * 256 + threadIdx.x;   // over V*32
    int v = idx >> 5;
    int c = (idx & 31) * 4;
    const int e0 = v * DEG;
    float4 acc = make_float4(0.f, 0.f, 0.f, 0.f);
#pragma unroll
    for (int e = 0; e < DEG; ++e) {
        float wv = ew[e0 + e];
        const float4 u = *(const float4*)&xin[(size_t)col[e0 + e] * 128 + c];
        acc.x = fmaf(wv, u.x, acc.x);
        acc.y = fmaf(wv, u.y, acc.y);
        acc.z = fmaf(wv, u.z, acc.z);
        acc.w = fmaf(wv, u.w, acc.w);
    }
    bf16x4 o;
    o[0] = (__bf16)acc.x; o[1] = (__bf16)acc.y; o[2] = (__bf16)acc.z; o[3] = (__bf16)acc.w;
    *(bf16x4*)&xout[(size_t)v * 128 + c] = o;
}

// ---------- u = y1 + 2 * (L y2): bf16 in/out, width 128 ----------
__global__ __launch_bounds__(256) void k_spmm_u(const __bf16* __restrict__ y1,
                                                const __bf16* __restrict__ y2,
                                                const int* __restrict__ col,
                                                const float* __restrict__ ew,
                                                __bf16* __restrict__ u) {
    int idx = blockIdx.x * 256 + threadIdx.x;   // over V*32
    int v = idx >> 5;
    int c = (idx & 31) * 4;
    const int e0 = v * DEG;
    float4 acc = make_float4(0.f, 0.f, 0.f, 0.f);
#pragma unroll
    for (int e = 0; e < DEG; ++e) {
        float wv = ew[e0 + e];
        bf16x4 p = *(const bf16x4*)&y2[(size_t)col[e0 + e] * 128 + c];
        acc.x = fmaf(wv, (float)p[0], acc.x);
        acc.y = fmaf(wv, (float)p[1], acc.y);
        acc.z = fmaf(wv, (float)p[2], acc.z);
        acc.w = fmaf(wv, (float)p[3], acc.w);
    }
    bf16x4 a = *(const bf16x4*)&y1[(size_t)v * 128 + c];
    bf16x4 o;
    o[0] = (__bf16)fmaf(2.f, acc.x, (float)a[0]);
    o[1] = (__bf16)fmaf(2.f, acc.y, (float)a[1]);
    o[2] = (__bf16)fmaf(2.f, acc.z, (float)a[2]);
    o[3] = (__bf16)fmaf(2.f, acc.w, (float)a[3]);
    *(bf16x4*)&u[(size_t)v * 128 + c] = o;
}

// ---------- weight prepack into MFMA B-fragment layout (hi/lo split) ----------
// pk: [0,4096)=W2hi  [4096,8192)=W2lo  [8192,11264)=W3hi  [11264,14336)=W3lo
__global__ __launch_bounds__(512) void k_prepack(const float* __restrict__ w2,
                                                 const float* __restrict__ w3,
                                                 __bf16* __restrict__ pk) {
    int t = threadIdx.x;
    {
        int kt = t >> 8, nt = (t >> 6) & 3, lane = t & 63;
#pragma unroll
        for (int e = 0; e < 8; ++e) {
            int k = kt * 32 + ((lane >> 4) * 8) + e;
            float val = (k < 48) ? w2[(k >> 4) * 1024 + (k & 15) * 64 + nt * 16 + (lane & 15)] : 0.f;
            __bf16 hi = (__bf16)val;
            pk[t * 8 + e] = hi;
            pk[4096 + t * 8 + e] = (__bf16)(val - (float)hi);
        }
    }
    if (t < 384) {
        int kt = t / 192, nt = (t / 64) % 3, lane = t & 63;
#pragma unroll
        for (int e = 0; e < 8; ++e) {
            int k = kt * 32 + ((lane >> 4) * 8) + e;
            float val = w3[nt * 1024 + k * 16 + (lane & 15)];
            __bf16 hi = (__bf16)val;
            pk[8192 + t * 8 + e] = hi;
            pk[11264 + t * 8 + e] = (__bf16)(val - (float)hi);
        }
    }
}

// ---------- layer 2 + y projection via split-bf16 MFMA (G=8 only) ----------
// Block = 8 vertices = 4 waves; wave owns a 16-row M-tile (2 vertices x 8 g).
// LDS: only s_hi/s_lo (19KB -> 8 blocks/CU). After phase A, h2 is re-stored
// (bias+relu, bf16 hi/lo) into the SAME wave-private tile in A-frag layout,
// so phase B reads it directly. Outputs: y02 = y0-y2 (f32), y1, y2 (bf16).
__global__ __launch_bounds__(256) void k_fused2y_mfma(const float* __restrict__ x0,  // h1 [V][128] f32
                                                      const __bf16* __restrict__ x1, // x1b [V][128] bf16
                                                      const int* __restrict__ col,
                                                      const float* __restrict__ ew,
                                                      const __bf16* __restrict__ pk,
                                                      const float* __restrict__ b2,  // [64]
                                                      float* __restrict__ y02,       // [V][128] f32
                                                      __bf16* __restrict__ y1o,      // [V][128] bf16
                                                      __bf16* __restrict__ y2o) {    // [V][128] bf16
    __shared__ __attribute__((aligned(16))) __bf16 s_hi[4][16 * 72];
    __shared__ __attribute__((aligned(16))) __bf16 s_lo[4][16 * 72];
    __shared__ int   sc[8][8];
    __shared__ float sw[8][8];
    const int t = threadIdx.x;
    const int v0 = blockIdx.x * 8;
    if (t < 64) {
        int vl = t >> 3, e = t & 7;
        sc[vl][e] = col[(v0 + vl) * DEG + e];
        sw[vl][e] = ew[(v0 + vl) * DEG + e];
    }
    __syncthreads();
    // zero K-pad (kcol 48..63), pairs
    for (int u = t; u < 512; u += 256) {
        int tile = u >> 7, row = (u >> 3) & 15, i = (u & 7) * 2;
        bf16x2 z; z[0] = (__bf16)0.f; z[1] = (__bf16)0.f;
        *(bf16x2*)&s_hi[tile][row * 72 + 48 + i] = z;
        *(bf16x2*)&s_lo[tile][row * 72 + 48 + i] = z;
    }
    // stage x0, x1 (bf16), gathered x2 = 2 L x1 - x0; 2 elements per thread
#pragma unroll
    for (int j = 0; j < 6; ++j) {
        int u = j * 512 + t * 2;
        int slice = u >> 7;                 // (vl, kcheb); wave-uniform
        int vl = slice / 3, kch = slice - vl * 3;
        int el = u & 127;                   // even
        size_t rowg = (size_t)(v0 + vl) * 128;
        bf16x2 hi2, lo2;
        if (kch == 0) {
            float2 val = *(const float2*)&x0[rowg + el];
            __bf16 h0 = (__bf16)val.x, h1v = (__bf16)val.y;
            hi2[0] = h0; hi2[1] = h1v;
            lo2[0] = (__bf16)(val.x - (float)h0);
            lo2[1] = (__bf16)(val.y - (float)h1v);
        } else if (kch == 1) {
            hi2 = *(const bf16x2*)&x1[rowg + el];
            lo2[0] = (__bf16)0.f; lo2[1] = (__bf16)0.f;
        } else {
            float ax = 0.f, ay = 0.f;
#pragma unroll
            for (int e = 0; e < DEG; ++e) {
                bf16x2 p = *(const bf16x2*)&x1[(size_t)sc[vl][e] * 128 + el];
                ax = fmaf(sw[vl][e], (float)p[0], ax);
                ay = fmaf(sw[vl][e], (float)p[1], ay);
            }
            float2 val = *(const float2*)&x0[rowg + el];
            float vx = 2.f * ax - val.x;
            float vy = 2.f * ay - val.y;
            __bf16 h0 = (__bf16)vx, h1v = (__bf16)vy;
            hi2[0] = h0; hi2[1] = h1v;
            lo2[0] = (__bf16)(vx - (float)h0);
            lo2[1] = (__bf16)(vy - (float)h1v);
        }
        int tile = vl >> 1;
        int row = (vl & 1) * 8 + (el >> 4);
        int kcol = kch * 16 + (el & 15);
        *(bf16x2*)&s_hi[tile][row * 72 + kcol] = hi2;
        *(bf16x2*)&s_lo[tile][row * 72 + kcol] = lo2;
    }
    __syncthreads();
    const int wv = t >> 6, lane = t & 63;
    const int lrow = lane & 15, lkg = lane >> 4;
    // ---- phase A: h2 = relu(x.W2 + b2) ----
    f32x4 acc[4] = {{0.f,0.f,0.f,0.f},{0.f,0.f,0.f,0.f},{0.f,0.f,0.f,0.f},{0.f,0.f,0.f,0.f}};
#pragma unroll
    for (int kt = 0; kt < 2; ++kt) {
        bf16x8 Ah = *(const bf16x8*)&s_hi[wv][lrow * 72 + kt * 32 + lkg * 8];
        bf16x8 Al = *(const bf16x8*)&s_lo[wv][lrow * 72 + kt * 32 + lkg * 8];
#pragma unroll
        for (int nt = 0; nt < 4; ++nt) {
            bf16x8 Wh = *(const bf16x8*)&pk[((kt * 4 + nt) * 64 + lane) * 8];
            bf16x8 Wl = *(const bf16x8*)&pk[4096 + ((kt * 4 + nt) * 64 + lane) * 8];
            acc[nt] = __builtin_amdgcn_mfma_f32_16x16x32_bf16(Ah, Wh, acc[nt], 0, 0, 0);
            acc[nt] = __builtin_amdgcn_mfma_f32_16x16x32_bf16(Al, Wh, acc[nt], 0, 0, 0);
            acc[nt] = __builtin_amdgcn_mfma_f32_16x16x32_bf16(Ah, Wl, acc[nt], 0, 0, 0);
        }
    }
    // bias + relu -> overwrite OWN tile with h2 as bf16 hi/lo, A-frag layout.
    // (A-frag reads above precede these aliasing writes in program order.)
    __builtin_amdgcn_sched_barrier(0);
#pragma unroll
    for (int nt = 0; nt < 4; ++nt) {
        float bias = b2[nt * 16 + lrow];
#pragma unroll
        for (int r = 0; r < 4; ++r) {
            int row = lkg * 4 + r;
            float h = fmaxf(acc[nt][r] + bias, 0.f);
            __bf16 hh = (__bf16)h;
            s_hi[wv][row * 72 + nt * 16 + lrow] = hh;
            s_lo[wv][row * 72 + nt * 16 + lrow] = (__bf16)(h - (float)hh);
        }
    }
    // wave-private tile: intra-wave lgkmcnt ordering suffices, no barrier
    // ---- phase B: y = h2 . W3 ----
    f32x4 accy[3] = {{0.f,0.f,0.f,0.f},{0.f,0.f,0.f,0.f},{0.f,0.f,0.f,0.f}};
#pragma unroll
    for (int kt = 0; kt < 2; ++kt) {
        bf16x8 Ah = *(const bf16x8*)&s_hi[wv][lrow * 72 + kt * 32 + lkg * 8];
        bf16x8 Al = *(const bf16x8*)&s_lo[wv][lrow * 72 + kt * 32 + lkg * 8];
#pragma unroll
        for (int nt = 0; nt < 3; ++nt) {
            bf16x8 Wh = *(const bf16x8*)&pk[8192 + ((kt * 3 + nt) * 64 + lane) * 8];
            bf16x8 Wl = *(const bf16x8*)&pk[11264 + ((kt * 3 + nt) * 64 + lane) * 8];
            accy[nt] = __builtin_amdgcn_mfma_f32_16x16x32_bf16(Ah, Wh, accy[nt], 0, 0, 0);
            accy[nt] = __builtin_amdgcn_mfma_f32_16x16x32_bf16(Al, Wh, accy[nt], 0, 0, 0);
            accy[nt] = __builtin_amdgcn_mfma_f32_16x16x32_bf16(Ah, Wl, accy[nt], 0, 0, 0);
        }
    }
    // store: y02 = y0 - y2 (fp32); y1, y2 bf16
    const int vbase = v0 + wv * 2;
#pragma unroll
    for (int r = 0; r < 4; ++r) {
        int row = lkg * 4 + r;
        int v = vbase + (row >> 3), g = row & 7;
        size_t off = (size_t)v * 128 + g * 16 + lrow;
        y02[off] = accy[0][r] - accy[2][r];
        y1o[off] = (__bf16)accy[1][r];
        y2o[off] = (__bf16)accy[2][r];
    }
}

// ---------- final (G=8): h3 = relu(y02 + L u + b3); out = h3 . w4 + b4 ----------
__global__ __launch_bounds__(256) void k_final_gb(const float* __restrict__ y02, // [V][128] f32
                                                  const __bf16* __restrict__ u,  // [V][128] bf16
                                                  const int* __restrict__ col,
                                                  const float* __restrict__ ew,
                                                  const float* __restrict__ b3,  // [16]
                                                  const float* __restrict__ w4,  // [16]
                                                  const float* __restrict__ b4,  // [1]
                                                  float* __restrict__ out, int b0) {
    int idx = blockIdx.x * 256 + threadIdx.x;   // over V*8
    int v = idx >> 3, g = idx & 7;
    const int e0 = v * DEG;
    float acc[16];
#pragma unroll
    for (int j = 0; j < 16; ++j) acc[j] = 0.f;
#pragma unroll
    for (int e = 0; e < DEG; ++e) {
        float wv = ew[e0 + e];
        const __bf16* src = u + (size_t)col[e0 + e] * 128 + g * 16;
        bf16x8 u0 = *(const bf16x8*)src;
        bf16x8 u1 = *(const bf16x8*)(src + 8);
#pragma unroll
        for (int j = 0; j < 8; ++j) {
            acc[j] = fmaf(wv, (float)u0[j], acc[j]);
            acc[8 + j] = fmaf(wv, (float)u1[j], acc[8 + j]);
        }
    }
    const float4* yp = (const float4*)&y02[(size_t)v * 128 + g * 16];
    float r = b4[0];
#pragma unroll
    for (int q = 0; q < 4; ++q) {
        float4 yv = yp[q];
        const float* py = (const float*)&yv;
#pragma unroll
        for (int j = 0; j < 4; ++j) {
            float h = py[j] + acc[q * 4 + j] + b3[q * 4 + j];
            h = fmaxf(h, 0.f);
            r = fmaf(h, w4[q * 4 + j], r);
        }
    }
    out[(b0 + g) * V_N + v] = r;
}

// ---------- legacy fp32 layer-2+y (G<8 fallback) ----------
template <int G>
__global__ __launch_bounds__(256) void k_fused2y(const float* __restrict__ x0,
                                                 const float* __restrict__ x1,
                                                 const int* __restrict__ col,
                                                 const float* __restrict__ ew,
                                                 const float* __restrict__ W2,
                                                 const float* __restrict__ b2,
                                                 const float* __restrict__ W3,
                                                 float* __restrict__ y) {
    constexpr int R = 16 * G;
    __shared__ float s[4][3 * R];
    __shared__ float sh2[4][G][64];
    __shared__ float sW2[3072];
    __shared__ float sW3[3072];
    __shared__ float sB[64];
    __shared__ int   sc[4][DEG];
    __shared__ float sw[4][DEG];
    const int t = threadIdx.x;
    const int v0 = blockIdx.x * 4;
    for (int j = t; j < 3072; j += 256) { sW2[j] = W2[j]; sW3[j] = W3[j]; }
    if (t < 64) sB[t] = b2[t];
    if (t < 32) {
        int vl = t >> 3, e = t & 7;
        sc[vl][e] = col[(v0 + vl) * DEG + e];
        sw[vl][e] = ew[(v0 + vl) * DEG + e];
    }
    __syncthreads();
    for (int u = t; u < 4 * R; u += 256) {
        int vl = u / R, el = u - vl * R;
        size_t row = (size_t)(v0 + vl) * R;
        float a0 = x0[row + el];
        float a1 = x1[row + el];
        s[vl][0 * R + el] = a0;
        s[vl][1 * R + el] = a1;
        float acc = 0.f;
#pragma unroll
        for (int e = 0; e < DEG; ++e)
            acc = fmaf(sw[vl][e], x1[(size_t)sc[vl][e] * R + el], acc);
        s[vl][2 * R + el] = 2.f * acc - a0;
    }
    __syncthreads();
    const int vl = t >> 6, o = t & 63;
    float wc[48];
#pragma unroll
    for (int k = 0; k < 3; ++k)
#pragma unroll
        for (int i = 0; i < 16; ++i)
            wc[k * 16 + i] = sW2[k * 1024 + i * 64 + o];
    float bias = sB[o];
#pragma unroll
    for (int g = 0; g < G; ++g) {
        float r = bias;
#pragma unroll
        for (int k = 0; k < 3; ++k) {
            const float4* ap = (const float4*)&s[vl][k * R + g * 16];
#pragma unroll
            for (int iq = 0; iq < 4; ++iq) {
                float4 a = ap[iq];
                r = fmaf(a.x, wc[k * 16 + iq * 4 + 0], r);
                r = fmaf(a.y, wc[k * 16 + iq * 4 + 1], r);
                r = fmaf(a.z, wc[k * 16 + iq * 4 + 2], r);
                r = fmaf(a.w, wc[k * 16 + iq * 4 + 3], r);
            }
        }
        sh2[vl][g][o] = fmaxf(r, 0.f);
    }
    __syncthreads();
    if (o < 48) {
        const int k3 = o >> 4, o3 = o & 15;
        float wy[64];
#pragma unroll
        for (int i = 0; i < 64; ++i)
            wy[i] = sW3[k3 * 1024 + i * 16 + o3];
        size_t yrow = (size_t)(v0 + vl) * (48 * G) + (size_t)k3 * (16 * G) + o3;
#pragma unroll
        for (int g = 0; g < G; ++g) {
            float r = 0.f;
            const float4* hp = (const float4*)&sh2[vl][g][0];
#pragma unroll
            for (int iq = 0; iq < 16; ++iq) {
                float4 h = hp[iq];
                r = fmaf(h.x, wy[iq * 4 + 0], r);
                r = fmaf(h.y, wy[iq * 4 + 1], r);
                r = fmaf(h.z, wy[iq * 4 + 2], r);
                r = fmaf(h.w, wy[iq * 4 + 3], r);
            }
            y[yrow + (size_t)g * 16] = r;
        }
    }
}

// ---------- legacy final (G<8 fallback) ----------
template <int G>
__global__ __launch_bounds__(256) void k_final_g(const float* __restrict__ y,
                                                 const float* __restrict__ z,
                                                 const int* __restrict__ col,
                                                 const float* __restrict__ ew,
                                                 const float* __restrict__ b3,
                                                 const float* __restrict__ w4,
                                                 const float* __restrict__ b4,
                                                 float* __restrict__ out, int b0) {
    int idx = blockIdx.x * 256 + threadIdx.x;   // over V*G
    int v = idx / G, g = idx - v * G;
    const size_t yr = (size_t)v * (48 * G) + g * 16;
    const size_t zr = (size_t)v * (32 * G) + g * 16;
    const int e0 = v * DEG;
    float4 acc[4];
#pragma unroll
    for (int q = 0; q < 4; ++q) acc[q] = make_float4(0.f, 0.f, 0.f, 0.f);
#pragma unroll
    for (int e = 0; e < DEG; ++e) {
        float wv = ew[e0 + e];
        const float* src = z + (size_t)col[e0 + e] * (32 * G) + 16 * G + g * 16;
#pragma unroll
        for (int q = 0; q < 4; ++q) {
            float4 u = *(const float4*)(src + q * 4);
            acc[q].x = fmaf(wv, u.x, acc[q].x);
            acc[q].y = fmaf(wv, u.y, acc[q].y);
            acc[q].z = fmaf(wv, u.z, acc[q].z);
            acc[q].w = fmaf(wv, u.w, acc[q].w);
        }
    }
    float r = b4[0];
#pragma unroll
    for (int q = 0; q < 4; ++q) {
        float4 y0v = *(const float4*)(y + yr + q * 4);
        float4 y2v = *(const float4*)(y + yr + (size_t)32 * G + q * 4);
        float4 z1v = *(const float4*)(z + zr + q * 4);
        const float* a = (const float*)&acc[q];
        const float* p0 = (const float*)&y0v;
        const float* p2 = (const float*)&y2v;
        const float* p1 = (const float*)&z1v;
#pragma unroll
        for (int j = 0; j < 4; ++j) {
            float h = p0[j] - p2[j] + p1[j] + 2.f * a[j] + b3[q * 4 + j];
            h = fmaxf(h, 0.f);
            r = fmaf(h, w4[q * 4 + j], r);
        }
    }
    out[(b0 + g) * V_N + v] = r;
}

// ---------- pipeline driver ----------
template <int G>
static void run_pipeline(const float* x, const int* ecol, const float* ew,
                         const float* w1, const float* b1, const float* w2, const float* b2,
                         const float* w3, const float* b3, const float* w4, const float* b4,
                         float* out, float* ws, hipStream_t stream) {
    const size_t V = V_N;
    dim3 blk(256);
    if constexpr (G == 8) {
        // layout (floats): xT 8V | x1 8V | h1 128V | x1b 64V(bf16) |
        //                  y02 128V | y1 64V(bf16) | y2 64V(bf16)  total 464V = 91MB
        float*  xT  = ws;
        float*  x1  = xT + 8 * V;
        float*  h1  = x1 + 8 * V;
        __bf16* x1b = (__bf16*)(h1 + 128 * V);
        float*  y02 = h1 + 192 * V;
        __bf16* y1b = (__bf16*)(y02 + 128 * V);
        __bf16* y2b = y1b + 128 * V;          // bf16 elements
        __bf16* ub  = x1b;                    // reuse x1b after fused2y
        __bf16* pk  = (__bf16*)xT;            // xT dead after k_fused1 (28KB)
        for (int b0 = 0; b0 < B_N; b0 += 8) {
            k_transpose_g<8><<<(V * 8) / 256, blk, 0, stream>>>(x, xT, b0);
            k_spmm_g<8><<<(V * 8) / 256, blk, 0, stream>>>(xT, ecol, ew, x1);
            k_fused1_g<8><<<(V * 8) / 256, blk, 0, stream>>>(xT, x1, ecol, ew, w1, b1, h1);
            k_prepack<<<1, 512, 0, stream>>>(w2, w3, pk);
            k_spmm_f2b<<<(V * 32) / 256, blk, 0, stream>>>(h1, ecol, ew, x1b);
            k_fused2y_mfma<<<V / 8, blk, 0, stream>>>(h1, x1b, ecol, ew, pk, b2, y02, y1b, y2b);
            k_spmm_u<<<(V * 32) / 256, blk, 0, stream>>>(y1b, y2b, ecol, ew, ub);
            k_final_gb<<<(V * 8) / 256, blk, 0, stream>>>(y02, ub, ecol, ew, b3, w4, b4, out, b0);
        }
    } else {
        const size_t GV = (size_t)G * V;
        float* xT   = ws;
        float* x1   = xT + GV;
        float* h1   = x1 + GV;
        float* x1b  = h1 + 16 * GV;
        float* y012 = x1b + 16 * GV;
        float* z12  = h1;
        for (int b0 = 0; b0 < B_N; b0 += G) {
            k_transpose_g<G><<<(V * G) / 256, blk, 0, stream>>>(x, xT, b0);
            k_spmm_g<G><<<(V * G) / 256, blk, 0, stream>>>(xT, ecol, ew, x1);
            k_fused1_g<G><<<(V * G) / 256, blk, 0, stream>>>(xT, x1, ecol, ew, w1, b1, h1);
            k_spmm_v<4 * G><<<(V * 4 * G) / 256, blk, 0, stream>>>(h1, ecol, ew, x1b);
            k_fused2y<G><<<V / 4, blk, 0, stream>>>(h1, x1b, ecol, ew, w2, b2, w3, y012);
            k_spmm_vs<8 * G><<<(V * 8 * G) / 256, blk, 0, stream>>>(
                y012 + 16 * G, 48 * G, ecol, ew, z12, 32 * G);
            k_final_g<G><<<(V * G) / 256, blk, 0, stream>>>(y012, z12, ecol, ew, b3, w4, b4, out, b0);
        }
    }
}

extern "C" void kernel_launch(void* const* d_in, const int* in_sizes, int n_in,
                              void* d_out, int out_size, void* d_ws, size_t ws_size,
                              hipStream_t stream) {
    const float* x = (const float*)d_in[0];
    // d_in[1] = edge_row = repeat(arange(V), 8) -> implicit, unused
    const int* ecol = (const int*)d_in[2];
    const float* ew = (const float*)d_in[3];
    const float* w1 = (const float*)d_in[4];
    const float* b1 = (const float*)d_in[5];
    const float* w2 = (const float*)d_in[6];
    const float* b2 = (const float*)d_in[7];
    const float* w3 = (const float*)d_in[8];
    const float* b3 = (const float*)d_in[9];
    const float* w4 = (const float*)d_in[10];
    const float* b4 = (const float*)d_in[11];
    float* out = (float*)d_out;
    float* ws = (float*)d_ws;

    auto need = [](int G) { return (size_t)82 * G * V_N * 4; };
    if (ws_size >= need(8))
        run_pipeline<8>(x, ecol, ew, w1, b1, w2, b2, w3, b3, w4, b4, out, ws, stream);
    else if (ws_size >= need(4))
        run_pipeline<4>(x, ecol, ew, w1, b1, w2, b2, w3, b3, w4, b4, out, ws, stream);
    else if (ws_size >= need(2))
        run_pipeline<2>(x, ecol, ew, w1, b1, w2, b2, w3, b3, w4, b4, out, ws, stream);
    else
        run_pipeline<1>(x, ecol, ew, w1, b1, w2, b2, w3, b3, w4, b4, out, ws, stream);
}

// Round 12
// 237.682 us; speedup vs baseline: 5.0391x; 1.1249x over previous
//
#include <hip/hip_runtime.h>

#define V_N 49152
#define B_N 16
#define DEG 8

typedef __bf16 bf16x8 __attribute__((ext_vector_type(8)));
typedef __bf16 bf16x4 __attribute__((ext_vector_type(4)));
typedef __bf16 bf16x2 __attribute__((ext_vector_type(2)));
typedef float f32x4 __attribute__((ext_vector_type(4)));

// ChebNet, batch-grouped (G=8 main path), all maps vertex-major.
// Layer 3 commuting trick + linearity fold:
//   h3 = relu(y0 - y2 + L(y1 + 2 L y2) + b3),  yk = relu(h2).W3_k
// h2 never materialized; ALL gather sources are bf16 (h1 dual-stored:
// fp32 for the direct x0 operand, bf16 for the L-gather).

// ---------- transpose slice: x[B,V] -> xT[V][G] ----------
template <int G>
__global__ __launch_bounds__(256) void k_transpose_g(const float* __restrict__ x,
                                                     float* __restrict__ xT, int b0) {
    int idx = blockIdx.x * 256 + threadIdx.x;   // idx = g*V + v (coalesced read)
    int g = idx / V_N, v = idx - g * V_N;
    xT[v * G + g] = x[(b0 + g) * V_N + v];
}

// ---------- scalar spmm, row width G ----------
template <int G>
__global__ __launch_bounds__(256) void k_spmm_g(const float* __restrict__ xin,
                                                const int* __restrict__ col,
                                                const float* __restrict__ ew,
                                                float* __restrict__ xout) {
    int idx = blockIdx.x * 256 + threadIdx.x;   // over V*G
    int v = idx / G, b = idx - v * G;
    const int e0 = v * DEG;
    float acc = 0.f;
#pragma unroll
    for (int e = 0; e < DEG; ++e)
        acc = fmaf(ew[e0 + e], xin[col[e0 + e] * G + b], acc);
    xout[idx] = acc;
}

// ---------- vec4 spmm fp32 (fallback path) ----------
template <int W4>
__global__ __launch_bounds__(256) void k_spmm_v(const float* __restrict__ xin,
                                                const int* __restrict__ col,
                                                const float* __restrict__ ew,
                                                float* __restrict__ xout) {
    int idx = blockIdx.x * 256 + threadIdx.x;
    int v = idx / W4;
    int c = (idx - v * W4) * 4;
    const int e0 = v * DEG;
    float4 acc = make_float4(0.f, 0.f, 0.f, 0.f);
#pragma unroll
    for (int e = 0; e < DEG; ++e) {
        float wv = ew[e0 + e];
        const float4 u = *(const float4*)&xin[(size_t)col[e0 + e] * (W4 * 4) + c];
        acc.x = fmaf(wv, u.x, acc.x);
        acc.y = fmaf(wv, u.y, acc.y);
        acc.z = fmaf(wv, u.z, acc.z);
        acc.w = fmaf(wv, u.w, acc.w);
    }
    *(float4*)&xout[(size_t)v * (W4 * 4) + c] = acc;
}

// ---------- vec4 spmm, strided rows (fallback path) ----------
template <int W4>
__global__ __launch_bounds__(256) void k_spmm_vs(const float* __restrict__ xin,
                                                 int in_stride,
                                                 const int* __restrict__ col,
                                                 const float* __restrict__ ew,
                                                 float* __restrict__ xout,
                                                 int out_stride) {
    int idx = blockIdx.x * 256 + threadIdx.x;
    int v = idx / W4;
    int c = (idx - v * W4) * 4;
    const int e0 = v * DEG;
    float4 acc = make_float4(0.f, 0.f, 0.f, 0.f);
#pragma unroll
    for (int e = 0; e < DEG; ++e) {
        float wv = ew[e0 + e];
        const float4 u = *(const float4*)&xin[(size_t)col[e0 + e] * in_stride + c];
        acc.x = fmaf(wv, u.x, acc.x);
        acc.y = fmaf(wv, u.y, acc.y);
        acc.z = fmaf(wv, u.z, acc.z);
        acc.w = fmaf(wv, u.w, acc.w);
    }
    *(float4*)&xout[(size_t)v * out_stride + c] = acc;
}

// ---------- layer 1 fused (fallback, f32 out only) ----------
template <int G>
__global__ __launch_bounds__(256) void k_fused1_g(const float* __restrict__ x0,
                                                  const float* __restrict__ x1,
                                                  const int* __restrict__ col,
                                                  const float* __restrict__ ew,
                                                  const float* __restrict__ W,   // [3][1][16]
                                                  const float* __restrict__ bias,// [16]
                                                  float* __restrict__ out) {     // h1 [V][16G]
    int idx = blockIdx.x * 256 + threadIdx.x;   // (v, g)
    int v = idx / G;
    float a0 = x0[idx], a1 = x1[idx];
    const int e0 = v * DEG;
    float acc = 0.f;
#pragma unroll
    for (int e = 0; e < DEG; ++e)
        acc = fmaf(ew[e0 + e], x1[col[e0 + e] * G + (idx - v * G)], acc);
    float a2 = 2.f * acc - a0;
    float4* dst = (float4*)&out[(size_t)idx * 16];
#pragma unroll
    for (int oq = 0; oq < 4; ++oq) {
        float4 r;
        float* rp = (float*)&r;
#pragma unroll
        for (int j = 0; j < 4; ++j) {
            int o = oq * 4 + j;
            rp[j] = fmaxf(fmaf(a0, W[o], fmaf(a1, W[16 + o], fmaf(a2, W[32 + o], bias[o]))), 0.f);
        }
        dst[oq] = r;
    }
}

// ---------- layer 1 fused, G=8: dual-store h1 (f32 + bf16 gather copy) ----------
__global__ __launch_bounds__(256) void k_fused1_gb(const float* __restrict__ x0,
                                                   const float* __restrict__ x1,
                                                   const int* __restrict__ col,
                                                   const float* __restrict__ ew,
                                                   const float* __restrict__ W,   // [3][1][16]
                                                   const float* __restrict__ bias,// [16]
                                                   float* __restrict__ out,       // h1 [V][128] f32
                                                   __bf16* __restrict__ outb) {   // h1b [V][128] bf16
    int idx = blockIdx.x * 256 + threadIdx.x;   // (v, g)
    int v = idx >> 3;
    float a0 = x0[idx], a1 = x1[idx];
    const int e0 = v * DEG;
    float acc = 0.f;
#pragma unroll
    for (int e = 0; e < DEG; ++e)
        acc = fmaf(ew[e0 + e], x1[col[e0 + e] * 8 + (idx & 7)], acc);
    float a2 = 2.f * acc - a0;
    float4* dst = (float4*)&out[(size_t)idx * 16];
    bf16x4* dstb = (bf16x4*)&outb[(size_t)idx * 16];
#pragma unroll
    for (int oq = 0; oq < 4; ++oq) {
        float4 r;
        float* rp = (float*)&r;
        bf16x4 rb;
#pragma unroll
        for (int j = 0; j < 4; ++j) {
            int o = oq * 4 + j;
            float h = fmaxf(fmaf(a0, W[o], fmaf(a1, W[16 + o], fmaf(a2, W[32 + o], bias[o]))), 0.f);
            rp[j] = h;
            rb[j] = (__bf16)h;
        }
        dst[oq] = r;
        dstb[oq] = rb;
    }
}

// ---------- x1b = L h1b, bf16 in -> bf16 out (width 128) ----------
__global__ __launch_bounds__(256) void k_spmm_f2b(const __bf16* __restrict__ xin, // h1b [V][128]
                                                  const int* __restrict__ col,
                                                  const float* __restrict__ ew,
                                                  __bf16* __restrict__ xout) {    // [V][128] bf16
    int idx = blockIdx.x * 256 + threadIdx.x;   // over V*32
    int v = idx >> 5;
    int c = (idx & 31) * 4;
    const int e0 = v * DEG;
    float4 acc = make_float4(0.f, 0.f, 0.f, 0.f);
#pragma unroll
    for (int e = 0; e < DEG; ++e) {
        float wv = ew[e0 + e];
        bf16x4 p = *(const bf16x4*)&xin[(size_t)col[e0 + e] * 128 + c];
        acc.x = fmaf(wv, (float)p[0], acc.x);
        acc.y = fmaf(wv, (float)p[1], acc.y);
        acc.z = fmaf(wv, (float)p[2], acc.z);
        acc.w = fmaf(wv, (float)p[3], acc.w);
    }
    bf16x4 o;
    o[0] = (__bf16)acc.x; o[1] = (__bf16)acc.y; o[2] = (__bf16)acc.z; o[3] = (__bf16)acc.w;
    *(bf16x4*)&xout[(size_t)v * 128 + c] = o;
}

// ---------- u = y1 + 2 * (L y2): bf16 in/out, width 128 ----------
__global__ __launch_bounds__(256) void k_spmm_u(const __bf16* __restrict__ y1,
                                                const __bf16* __restrict__ y2,
                                                const int* __restrict__ col,
                                                const float* __restrict__ ew,
                                                __bf16* __restrict__ u) {
    int idx = blockIdx.x * 256 + threadIdx.x;   // over V*32
    int v = idx >> 5;
    int c = (idx & 31) * 4;
    const int e0 = v * DEG;
    float4 acc = make_float4(0.f, 0.f, 0.f, 0.f);
#pragma unroll
    for (int e = 0; e < DEG; ++e) {
        float wv = ew[e0 + e];
        bf16x4 p = *(const bf16x4*)&y2[(size_t)col[e0 + e] * 128 + c];
        acc.x = fmaf(wv, (float)p[0], acc.x);
        acc.y = fmaf(wv, (float)p[1], acc.y);
        acc.z = fmaf(wv, (float)p[2], acc.z);
        acc.w = fmaf(wv, (float)p[3], acc.w);
    }
    bf16x4 a = *(const bf16x4*)&y1[(size_t)v * 128 + c];
    bf16x4 o;
    o[0] = (__bf16)fmaf(2.f, acc.x, (float)a[0]);
    o[1] = (__bf16)fmaf(2.f, acc.y, (float)a[1]);
    o[2] = (__bf16)fmaf(2.f, acc.z, (float)a[2]);
    o[3] = (__bf16)fmaf(2.f, acc.w, (float)a[3]);
    *(bf16x4*)&u[(size_t)v * 128 + c] = o;
}

// ---------- weight prepack into MFMA B-fragment layout (hi/lo split) ----------
// pk: [0,4096)=W2hi  [4096,8192)=W2lo  [8192,11264)=W3hi  [11264,14336)=W3lo
__global__ __launch_bounds__(512) void k_prepack(const float* __restrict__ w2,
                                                 const float* __restrict__ w3,
                                                 __bf16* __restrict__ pk) {
    int t = threadIdx.x;
    {
        int kt = t >> 8, nt = (t >> 6) & 3, lane = t & 63;
#pragma unroll
        for (int e = 0; e < 8; ++e) {
            int k = kt * 32 + ((lane >> 4) * 8) + e;
            float val = (k < 48) ? w2[(k >> 4) * 1024 + (k & 15) * 64 + nt * 16 + (lane & 15)] : 0.f;
            __bf16 hi = (__bf16)val;
            pk[t * 8 + e] = hi;
            pk[4096 + t * 8 + e] = (__bf16)(val - (float)hi);
        }
    }
    if (t < 384) {
        int kt = t / 192, nt = (t / 64) % 3, lane = t & 63;
#pragma unroll
        for (int e = 0; e < 8; ++e) {
            int k = kt * 32 + ((lane >> 4) * 8) + e;
            float val = w3[nt * 1024 + k * 16 + (lane & 15)];
            __bf16 hi = (__bf16)val;
            pk[8192 + t * 8 + e] = hi;
            pk[11264 + t * 8 + e] = (__bf16)(val - (float)hi);
        }
    }
}

// ---------- layer 2 + y projection via split-bf16 MFMA (G=8 only) ----------
// Block = 8 vertices = 4 waves; wave owns a 16-row M-tile (2 vertices x 8 g).
// LDS: only s_hi/s_lo (19KB -> 8 blocks/CU). After phase A, h2 is re-stored
// (bias+relu, bf16 hi/lo) into the SAME wave-private tile in A-frag layout,
// so phase B reads it directly. Outputs: y02 = y0-y2 (f32), y1, y2 (bf16).
__global__ __launch_bounds__(256) void k_fused2y_mfma(const float* __restrict__ x0,  // h1 [V][128] f32
                                                      const __bf16* __restrict__ x1, // x1b [V][128] bf16
                                                      const int* __restrict__ col,
                                                      const float* __restrict__ ew,
                                                      const __bf16* __restrict__ pk,
                                                      const float* __restrict__ b2,  // [64]
                                                      float* __restrict__ y02,       // [V][128] f32
                                                      __bf16* __restrict__ y1o,      // [V][128] bf16
                                                      __bf16* __restrict__ y2o) {    // [V][128] bf16
    __shared__ __attribute__((aligned(16))) __bf16 s_hi[4][16 * 72];
    __shared__ __attribute__((aligned(16))) __bf16 s_lo[4][16 * 72];
    __shared__ int   sc[8][8];
    __shared__ float sw[8][8];
    const int t = threadIdx.x;
    const int v0 = blockIdx.x * 8;
    if (t < 64) {
        int vl = t >> 3, e = t & 7;
        sc[vl][e] = col[(v0 + vl) * DEG + e];
        sw[vl][e] = ew[(v0 + vl) * DEG + e];
    }
    __syncthreads();
    // zero K-pad (kcol 48..63), pairs
    for (int u = t; u < 512; u += 256) {
        int tile = u >> 7, row = (u >> 3) & 15, i = (u & 7) * 2;
        bf16x2 z; z[0] = (__bf16)0.f; z[1] = (__bf16)0.f;
        *(bf16x2*)&s_hi[tile][row * 72 + 48 + i] = z;
        *(bf16x2*)&s_lo[tile][row * 72 + 48 + i] = z;
    }
    // stage x0, x1 (bf16), gathered x2 = 2 L x1 - x0; 2 elements per thread
#pragma unroll
    for (int j = 0; j < 6; ++j) {
        int u = j * 512 + t * 2;
        int slice = u >> 7;                 // (vl, kcheb); wave-uniform
        int vl = slice / 3, kch = slice - vl * 3;
        int el = u & 127;                   // even
        size_t rowg = (size_t)(v0 + vl) * 128;
        bf16x2 hi2, lo2;
        if (kch == 0) {
            float2 val = *(const float2*)&x0[rowg + el];
            __bf16 h0 = (__bf16)val.x, h1v = (__bf16)val.y;
            hi2[0] = h0; hi2[1] = h1v;
            lo2[0] = (__bf16)(val.x - (float)h0);
            lo2[1] = (__bf16)(val.y - (float)h1v);
        } else if (kch == 1) {
            hi2 = *(const bf16x2*)&x1[rowg + el];
            lo2[0] = (__bf16)0.f; lo2[1] = (__bf16)0.f;
        } else {
            float ax = 0.f, ay = 0.f;
#pragma unroll
            for (int e = 0; e < DEG; ++e) {
                bf16x2 p = *(const bf16x2*)&x1[(size_t)sc[vl][e] * 128 + el];
                ax = fmaf(sw[vl][e], (float)p[0], ax);
                ay = fmaf(sw[vl][e], (float)p[1], ay);
            }
            float2 val = *(const float2*)&x0[rowg + el];
            float vx = 2.f * ax - val.x;
            float vy = 2.f * ay - val.y;
            __bf16 h0 = (__bf16)vx, h1v = (__bf16)vy;
            hi2[0] = h0; hi2[1] = h1v;
            lo2[0] = (__bf16)(vx - (float)h0);
            lo2[1] = (__bf16)(vy - (float)h1v);
        }
        int tile = vl >> 1;
        int row = (vl & 1) * 8 + (el >> 4);
        int kcol = kch * 16 + (el & 15);
        *(bf16x2*)&s_hi[tile][row * 72 + kcol] = hi2;
        *(bf16x2*)&s_lo[tile][row * 72 + kcol] = lo2;
    }
    __syncthreads();
    const int wv = t >> 6, lane = t & 63;
    const int lrow = lane & 15, lkg = lane >> 4;
    // ---- phase A: h2 = relu(x.W2 + b2) ----
    f32x4 acc[4] = {{0.f,0.f,0.f,0.f},{0.f,0.f,0.f,0.f},{0.f,0.f,0.f,0.f},{0.f,0.f,0.f,0.f}};
#pragma unroll
    for (int kt = 0; kt < 2; ++kt) {
        bf16x8 Ah = *(const bf16x8*)&s_hi[wv][lrow * 72 + kt * 32 + lkg * 8];
        bf16x8 Al = *(const bf16x8*)&s_lo[wv][lrow * 72 + kt * 32 + lkg * 8];
#pragma unroll
        for (int nt = 0; nt < 4; ++nt) {
            bf16x8 Wh = *(const bf16x8*)&pk[((kt * 4 + nt) * 64 + lane) * 8];
            bf16x8 Wl = *(const bf16x8*)&pk[4096 + ((kt * 4 + nt) * 64 + lane) * 8];
            acc[nt] = __builtin_amdgcn_mfma_f32_16x16x32_bf16(Ah, Wh, acc[nt], 0, 0, 0);
            acc[nt] = __builtin_amdgcn_mfma_f32_16x16x32_bf16(Al, Wh, acc[nt], 0, 0, 0);
            acc[nt] = __builtin_amdgcn_mfma_f32_16x16x32_bf16(Ah, Wl, acc[nt], 0, 0, 0);
        }
    }
    // bias + relu -> overwrite OWN tile with h2 as bf16 hi/lo, A-frag layout.
    // (A-frag reads above precede these aliasing writes in program order.)
    __builtin_amdgcn_sched_barrier(0);
#pragma unroll
    for (int nt = 0; nt < 4; ++nt) {
        float bias = b2[nt * 16 + lrow];
#pragma unroll
        for (int r = 0; r < 4; ++r) {
            int row = lkg * 4 + r;
            float h = fmaxf(acc[nt][r] + bias, 0.f);
            __bf16 hh = (__bf16)h;
            s_hi[wv][row * 72 + nt * 16 + lrow] = hh;
            s_lo[wv][row * 72 + nt * 16 + lrow] = (__bf16)(h - (float)hh);
        }
    }
    // wave-private tile: intra-wave lgkmcnt ordering suffices, no barrier
    // ---- phase B: y = h2 . W3 ----
    f32x4 accy[3] = {{0.f,0.f,0.f,0.f},{0.f,0.f,0.f,0.f},{0.f,0.f,0.f,0.f}};
#pragma unroll
    for (int kt = 0; kt < 2; ++kt) {
        bf16x8 Ah = *(const bf16x8*)&s_hi[wv][lrow * 72 + kt * 32 + lkg * 8];
        bf16x8 Al = *(const bf16x8*)&s_lo[wv][lrow * 72 + kt * 32 + lkg * 8];
#pragma unroll
        for (int nt = 0; nt < 3; ++nt) {
            bf16x8 Wh = *(const bf16x8*)&pk[8192 + ((kt * 3 + nt) * 64 + lane) * 8];
            bf16x8 Wl = *(const bf16x8*)&pk[11264 + ((kt * 3 + nt) * 64 + lane) * 8];
            accy[nt] = __builtin_amdgcn_mfma_f32_16x16x32_bf16(Ah, Wh, accy[nt], 0, 0, 0);
            accy[nt] = __builtin_amdgcn_mfma_f32_16x16x32_bf16(Al, Wh, accy[nt], 0, 0, 0);
            accy[nt] = __builtin_amdgcn_mfma_f32_16x16x32_bf16(Ah, Wl, accy[nt], 0, 0, 0);
        }
    }
    // store: y02 = y0 - y2 (fp32); y1, y2 bf16
    const int vbase = v0 + wv * 2;
#pragma unroll
    for (int r = 0; r < 4; ++r) {
        int row = lkg * 4 + r;
        int v = vbase + (row >> 3), g = row & 7;
        size_t off = (size_t)v * 128 + g * 16 + lrow;
        y02[off] = accy[0][r] - accy[2][r];
        y1o[off] = (__bf16)accy[1][r];
        y2o[off] = (__bf16)accy[2][r];
    }
}

// ---------- final (G=8): h3 = relu(y02 + L u + b3); out = h3 . w4 + b4 ----------
__global__ __launch_bounds__(256) void k_final_gb(const float* __restrict__ y02, // [V][128] f32
                                                  const __bf16* __restrict__ u,  // [V][128] bf16
                                                  const int* __restrict__ col,
                                                  const float* __restrict__ ew,
                                                  const float* __restrict__ b3,  // [16]
                                                  const float* __restrict__ w4,  // [16]
                                                  const float* __restrict__ b4,  // [1]
                                                  float* __restrict__ out, int b0) {
    int idx = blockIdx.x * 256 + threadIdx.x;   // over V*8
    int v = idx >> 3, g = idx & 7;
    const int e0 = v * DEG;
    float acc[16];
#pragma unroll
    for (int j = 0; j < 16; ++j) acc[j] = 0.f;
#pragma unroll
    for (int e = 0; e < DEG; ++e) {
        float wv = ew[e0 + e];
        const __bf16* src = u + (size_t)col[e0 + e] * 128 + g * 16;
        bf16x8 u0 = *(const bf16x8*)src;
        bf16x8 u1 = *(const bf16x8*)(src + 8);
#pragma unroll
        for (int j = 0; j < 8; ++j) {
            acc[j] = fmaf(wv, (float)u0[j], acc[j]);
            acc[8 + j] = fmaf(wv, (float)u1[j], acc[8 + j]);
        }
    }
    const float4* yp = (const float4*)&y02[(size_t)v * 128 + g * 16];
    float r = b4[0];
#pragma unroll
    for (int q = 0; q < 4; ++q) {
        float4 yv = yp[q];
        const float* py = (const float*)&yv;
#pragma unroll
        for (int j = 0; j < 4; ++j) {
            float h = py[j] + acc[q * 4 + j] + b3[q * 4 + j];
            h = fmaxf(h, 0.f);
            r = fmaf(h, w4[q * 4 + j], r);
        }
    }
    out[(b0 + g) * V_N + v] = r;
}

// ---------- legacy fp32 layer-2+y (G<8 fallback) ----------
template <int G>
__global__ __launch_bounds__(256) void k_fused2y(const float* __restrict__ x0,
                                                 const float* __restrict__ x1,
                                                 const int* __restrict__ col,
                                                 const float* __restrict__ ew,
                                                 const float* __restrict__ W2,
                                                 const float* __restrict__ b2,
                                                 const float* __restrict__ W3,
                                                 float* __restrict__ y) {
    constexpr int R = 16 * G;
    __shared__ float s[4][3 * R];
    __shared__ float sh2[4][G][64];
    __shared__ float sW2[3072];
    __shared__ float sW3[3072];
    __shared__ float sB[64];
    __shared__ int   sc[4][DEG];
    __shared__ float sw[4][DEG];
    const int t = threadIdx.x;
    const int v0 = blockIdx.x * 4;
    for (int j = t; j < 3072; j += 256) { sW2[j] = W2[j]; sW3[j] = W3[j]; }
    if (t < 64) sB[t] = b2[t];
    if (t < 32) {
        int vl = t >> 3, e = t & 7;
        sc[vl][e] = col[(v0 + vl) * DEG + e];
        sw[vl][e] = ew[(v0 + vl) * DEG + e];
    }
    __syncthreads();
    for (int u = t; u < 4 * R; u += 256) {
        int vl = u / R, el = u - vl * R;
        size_t row = (size_t)(v0 + vl) * R;
        float a0 = x0[row + el];
        float a1 = x1[row + el];
        s[vl][0 * R + el] = a0;
        s[vl][1 * R + el] = a1;
        float acc = 0.f;
#pragma unroll
        for (int e = 0; e < DEG; ++e)
            acc = fmaf(sw[vl][e], x1[(size_t)sc[vl][e] * R + el], acc);
        s[vl][2 * R + el] = 2.f * acc - a0;
    }
    __syncthreads();
    const int vl = t >> 6, o = t & 63;
    float wc[48];
#pragma unroll
    for (int k = 0; k < 3; ++k)
#pragma unroll
        for (int i = 0; i < 16; ++i)
            wc[k * 16 + i] = sW2[k * 1024 + i * 64 + o];
    float bias = sB[o];
#pragma unroll
    for (int g = 0; g < G; ++g) {
        float r = bias;
#pragma unroll
        for (int k = 0; k < 3; ++k) {
            const float4* ap = (const float4*)&s[vl][k * R + g * 16];
#pragma unroll
            for (int iq = 0; iq < 4; ++iq) {
                float4 a = ap[iq];
                r = fmaf(a.x, wc[k * 16 + iq * 4 + 0], r);
                r = fmaf(a.y, wc[k * 16 + iq * 4 + 1], r);
                r = fmaf(a.z, wc[k * 16 + iq * 4 + 2], r);
                r = fmaf(a.w, wc[k * 16 + iq * 4 + 3], r);
            }
        }
        sh2[vl][g][o] = fmaxf(r, 0.f);
    }
    __syncthreads();
    if (o < 48) {
        const int k3 = o >> 4, o3 = o & 15;
        float wy[64];
#pragma unroll
        for (int i = 0; i < 64; ++i)
            wy[i] = sW3[k3 * 1024 + i * 16 + o3];
        size_t yrow = (size_t)(v0 + vl) * (48 * G) + (size_t)k3 * (16 * G) + o3;
#pragma unroll
        for (int g = 0; g < G; ++g) {
            float r = 0.f;
            const float4* hp = (const float4*)&sh2[vl][g][0];
#pragma unroll
            for (int iq = 0; iq < 16; ++iq) {
                float4 h = hp[iq];
                r = fmaf(h.x, wy[iq * 4 + 0], r);
                r = fmaf(h.y, wy[iq * 4 + 1], r);
                r = fmaf(h.z, wy[iq * 4 + 2], r);
                r = fmaf(h.w, wy[iq * 4 + 3], r);
            }
            y[yrow + (size_t)g * 16] = r;
        }
    }
}

// ---------- legacy final (G<8 fallback) ----------
template <int G>
__global__ __launch_bounds__(256) void k_final_g(const float* __restrict__ y,
                                                 const float* __restrict__ z,
                                                 const int* __restrict__ col,
                                                 const float* __restrict__ ew,
                                                 const float* __restrict__ b3,
                                                 const float* __restrict__ w4,
                                                 const float* __restrict__ b4,
                                                 float* __restrict__ out, int b0) {
    int idx = blockIdx.x * 256 + threadIdx.x;   // over V*G
    int v = idx / G, g = idx - v * G;
    const size_t yr = (size_t)v * (48 * G) + g * 16;
    const size_t zr = (size_t)v * (32 * G) + g * 16;
    const int e0 = v * DEG;
    float4 acc[4];
#pragma unroll
    for (int q = 0; q < 4; ++q) acc[q] = make_float4(0.f, 0.f, 0.f, 0.f);
#pragma unroll
    for (int e = 0; e < DEG; ++e) {
        float wv = ew[e0 + e];
        const float* src = z + (size_t)col[e0 + e] * (32 * G) + 16 * G + g * 16;
#pragma unroll
        for (int q = 0; q < 4; ++q) {
            float4 u = *(const float4*)(src + q * 4);
            acc[q].x = fmaf(wv, u.x, acc[q].x);
            acc[q].y = fmaf(wv, u.y, acc[q].y);
            acc[q].z = fmaf(wv, u.z, acc[q].z);
            acc[q].w = fmaf(wv, u.w, acc[q].w);
        }
    }
    float r = b4[0];
#pragma unroll
    for (int q = 0; q < 4; ++q) {
        float4 y0v = *(const float4*)(y + yr + q * 4);
        float4 y2v = *(const float4*)(y + yr + (size_t)32 * G + q * 4);
        float4 z1v = *(const float4*)(z + zr + q * 4);
        const float* a = (const float*)&acc[q];
        const float* p0 = (const float*)&y0v;
        const float* p2 = (const float*)&y2v;
        const float* p1 = (const float*)&z1v;
#pragma unroll
        for (int j = 0; j < 4; ++j) {
            float h = p0[j] - p2[j] + p1[j] + 2.f * a[j] + b3[q * 4 + j];
            h = fmaxf(h, 0.f);
            r = fmaf(h, w4[q * 4 + j], r);
        }
    }
    out[(b0 + g) * V_N + v] = r;
}

// ---------- pipeline driver ----------
template <int G>
static void run_pipeline(const float* x, const int* ecol, const float* ew,
                         const float* w1, const float* b1, const float* w2, const float* b2,
                         const float* w3, const float* b3, const float* w4, const float* b4,
                         float* out, float* ws, hipStream_t stream) {
    const size_t V = V_N;
    dim3 blk(256);
    if constexpr (G == 8) {
        // layout (floats): xT 8V | x1 8V | h1 128V | h1b 64V(bf16) | x1b 64V(bf16) |
        //                  y02 128V | y1 64V(bf16) | y2 64V(bf16) | pk  -> 528V+pk <= 656V
        float*  xT  = ws;
        float*  x1  = xT + 8 * V;
        float*  h1  = x1 + 8 * V;
        __bf16* h1b = (__bf16*)(h1 + 128 * V);
        __bf16* x1b = (__bf16*)(h1 + 192 * V);
        float*  y02 = h1 + 256 * V;
        __bf16* y1b = (__bf16*)(y02 + 128 * V);
        __bf16* y2b = y1b + 128 * V;          // bf16 elements
        __bf16* ub  = x1b;                    // reuse x1b after fused2y
        __bf16* pk  = (__bf16*)(h1 + 512 * V); // dedicated spare (no aliasing)
        k_prepack<<<1, 512, 0, stream>>>(w2, w3, pk);   // once: weights pass-invariant
        for (int b0 = 0; b0 < B_N; b0 += 8) {
            k_transpose_g<8><<<(V * 8) / 256, blk, 0, stream>>>(x, xT, b0);
            k_spmm_g<8><<<(V * 8) / 256, blk, 0, stream>>>(xT, ecol, ew, x1);
            k_fused1_gb<<<(V * 8) / 256, blk, 0, stream>>>(xT, x1, ecol, ew, w1, b1, h1, h1b);
            k_spmm_f2b<<<(V * 32) / 256, blk, 0, stream>>>(h1b, ecol, ew, x1b);
            k_fused2y_mfma<<<V / 8, blk, 0, stream>>>(h1, x1b, ecol, ew, pk, b2, y02, y1b, y2b);
            k_spmm_u<<<(V * 32) / 256, blk, 0, stream>>>(y1b, y2b, ecol, ew, ub);
            k_final_gb<<<(V * 8) / 256, blk, 0, stream>>>(y02, ub, ecol, ew, b3, w4, b4, out, b0);
        }
    } else {
        const size_t GV = (size_t)G * V;
        float* xT   = ws;
        float* x1   = xT + GV;
        float* h1   = x1 + GV;
        float* x1b  = h1 + 16 * GV;
        float* y012 = x1b + 16 * GV;
        float* z12  = h1;
        for (int b0 = 0; b0 < B_N; b0 += G) {
            k_transpose_g<G><<<(V * G) / 256, blk, 0, stream>>>(x, xT, b0);
            k_spmm_g<G><<<(V * G) / 256, blk, 0, stream>>>(xT, ecol, ew, x1);
            k_fused1_g<G><<<(V * G) / 256, blk, 0, stream>>>(xT, x1, ecol, ew, w1, b1, h1);
            k_spmm_v<4 * G><<<(V * 4 * G) / 256, blk, 0, stream>>>(h1, ecol, ew, x1b);
            k_fused2y<G><<<V / 4, blk, 0, stream>>>(h1, x1b, ecol, ew, w2, b2, w3, y012);
            k_spmm_vs<8 * G><<<(V * 8 * G) / 256, blk, 0, stream>>>(
                y012 + 16 * G, 48 * G, ecol, ew, z12, 32 * G);
            k_final_g<G><<<(V * G) / 256, blk, 0, stream>>>(y012, z12, ecol, ew, b3, w4, b4, out, b0);
        }
    }
}

extern "C" void kernel_launch(void* const* d_in, const int* in_sizes, int n_in,
                              void* d_out, int out_size, void* d_ws, size_t ws_size,
                              hipStream_t stream) {
    const float* x = (const float*)d_in[0];
    // d_in[1] = edge_row = repeat(arange(V), 8) -> implicit, unused
    const int* ecol = (const int*)d_in[2];
    const float* ew = (const float*)d_in[3];
    const float* w1 = (const float*)d_in[4];
    const float* b1 = (const float*)d_in[5];
    const float* w2 = (const float*)d_in[6];
    const float* b2 = (const float*)d_in[7];
    const float* w3 = (const float*)d_in[8];
    const float* b3 = (const float*)d_in[9];
    const float* w4 = (const float*)d_in[10];
    const float* b4 = (const float*)d_in[11];
    float* out = (float*)d_out;
    float* ws = (float*)d_ws;

    auto need = [](int G) { return (size_t)82 * G * V_N * 4; };
    if (ws_size >= need(8))
        run_pipeline<8>(x, ecol, ew, w1, b1, w2, b2, w3, b3, w4, b4, out, ws, stream);
    else if (ws_size >= need(4))
        run_pipeline<4>(x, ecol, ew, w1, b1, w2, b2, w3, b3, w4, b4, out, ws, stream);
    else if (ws_size >= need(2))
        run_pipeline<2>(x, ecol, ew, w1, b1, w2, b2, w3, b3, w4, b4, out, ws, stream);
    else
        run_pipeline<1>(x, ecol, ew, w1, b1, w2, b2, w3, b3, w4, b4, out, ws, stream);
}

// Round 13
// 233.322 us; speedup vs baseline: 5.1333x; 1.0187x over previous
//
#include <hip/hip_runtime.h>

#define V_N 49152
#define B_N 16
#define DEG 8

typedef __bf16 bf16x8 __attribute__((ext_vector_type(8)));
typedef __bf16 bf16x4 __attribute__((ext_vector_type(4)));
typedef __bf16 bf16x2 __attribute__((ext_vector_type(2)));
typedef float f32x4 __attribute__((ext_vector_type(4)));

// ChebNet, batch-grouped (G=8 main path), all maps vertex-major.
// Layer 3 commuting trick + linearity fold:
//   h3 = relu(y0 - y2 + L(y1 + 2 L y2) + b3),  yk = relu(h2).W3_k
// h2 never materialized; ALL gather sources are bf16 (h1 dual-stored).
// Gather structure is algebraically minimal: 4 width-128 L-applications.

// ---------- transpose slice: x[B,V] -> xT[V][G] ----------
template <int G>
__global__ __launch_bounds__(256) void k_transpose_g(const float* __restrict__ x,
                                                     float* __restrict__ xT, int b0) {
    int idx = blockIdx.x * 256 + threadIdx.x;   // idx = g*V + v (coalesced read)
    int g = idx / V_N, v = idx - g * V_N;
    xT[v * G + g] = x[(b0 + g) * V_N + v];
}

// ---------- scalar spmm, row width G ----------
template <int G>
__global__ __launch_bounds__(256) void k_spmm_g(const float* __restrict__ xin,
                                                const int* __restrict__ col,
                                                const float* __restrict__ ew,
                                                float* __restrict__ xout) {
    int idx = blockIdx.x * 256 + threadIdx.x;   // over V*G
    int v = idx / G, b = idx - v * G;
    const int e0 = v * DEG;
    float acc = 0.f;
#pragma unroll
    for (int e = 0; e < DEG; ++e)
        acc = fmaf(ew[e0 + e], xin[col[e0 + e] * G + b], acc);
    xout[idx] = acc;
}

// ---------- vec4 spmm fp32 (fallback path) ----------
template <int W4>
__global__ __launch_bounds__(256) void k_spmm_v(const float* __restrict__ xin,
                                                const int* __restrict__ col,
                                                const float* __restrict__ ew,
                                                float* __restrict__ xout) {
    int idx = blockIdx.x * 256 + threadIdx.x;
    int v = idx / W4;
    int c = (idx - v * W4) * 4;
    const int e0 = v * DEG;
    float4 acc = make_float4(0.f, 0.f, 0.f, 0.f);
#pragma unroll
    for (int e = 0; e < DEG; ++e) {
        float wv = ew[e0 + e];
        const float4 u = *(const float4*)&xin[(size_t)col[e0 + e] * (W4 * 4) + c];
        acc.x = fmaf(wv, u.x, acc.x);
        acc.y = fmaf(wv, u.y, acc.y);
        acc.z = fmaf(wv, u.z, acc.z);
        acc.w = fmaf(wv, u.w, acc.w);
    }
    *(float4*)&xout[(size_t)v * (W4 * 4) + c] = acc;
}

// ---------- vec4 spmm, strided rows (fallback path) ----------
template <int W4>
__global__ __launch_bounds__(256) void k_spmm_vs(const float* __restrict__ xin,
                                                 int in_stride,
                                                 const int* __restrict__ col,
                                                 const float* __restrict__ ew,
                                                 float* __restrict__ xout,
                                                 int out_stride) {
    int idx = blockIdx.x * 256 + threadIdx.x;
    int v = idx / W4;
    int c = (idx - v * W4) * 4;
    const int e0 = v * DEG;
    float4 acc = make_float4(0.f, 0.f, 0.f, 0.f);
#pragma unroll
    for (int e = 0; e < DEG; ++e) {
        float wv = ew[e0 + e];
        const float4 u = *(const float4*)&xin[(size_t)col[e0 + e] * in_stride + c];
        acc.x = fmaf(wv, u.x, acc.x);
        acc.y = fmaf(wv, u.y, acc.y);
        acc.z = fmaf(wv, u.z, acc.z);
        acc.w = fmaf(wv, u.w, acc.w);
    }
    *(float4*)&xout[(size_t)v * out_stride + c] = acc;
}

// ---------- layer 1 fused (fallback, f32 out only) ----------
template <int G>
__global__ __launch_bounds__(256) void k_fused1_g(const float* __restrict__ x0,
                                                  const float* __restrict__ x1,
                                                  const int* __restrict__ col,
                                                  const float* __restrict__ ew,
                                                  const float* __restrict__ W,   // [3][1][16]
                                                  const float* __restrict__ bias,// [16]
                                                  float* __restrict__ out) {     // h1 [V][16G]
    int idx = blockIdx.x * 256 + threadIdx.x;   // (v, g)
    int v = idx / G;
    float a0 = x0[idx], a1 = x1[idx];
    const int e0 = v * DEG;
    float acc = 0.f;
#pragma unroll
    for (int e = 0; e < DEG; ++e)
        acc = fmaf(ew[e0 + e], x1[col[e0 + e] * G + (idx - v * G)], acc);
    float a2 = 2.f * acc - a0;
    float4* dst = (float4*)&out[(size_t)idx * 16];
#pragma unroll
    for (int oq = 0; oq < 4; ++oq) {
        float4 r;
        float* rp = (float*)&r;
#pragma unroll
        for (int j = 0; j < 4; ++j) {
            int o = oq * 4 + j;
            rp[j] = fmaxf(fmaf(a0, W[o], fmaf(a1, W[16 + o], fmaf(a2, W[32 + o], bias[o]))), 0.f);
        }
        dst[oq] = r;
    }
}

// ---------- layer 1 fused, G=8: dual-store h1 (f32 + bf16 gather copy) ----------
__global__ __launch_bounds__(256) void k_fused1_gb(const float* __restrict__ x0,
                                                   const float* __restrict__ x1,
                                                   const int* __restrict__ col,
                                                   const float* __restrict__ ew,
                                                   const float* __restrict__ W,   // [3][1][16]
                                                   const float* __restrict__ bias,// [16]
                                                   float* __restrict__ out,       // h1 [V][128] f32
                                                   __bf16* __restrict__ outb) {   // h1b [V][128] bf16
    int idx = blockIdx.x * 256 + threadIdx.x;   // (v, g)
    int v = idx >> 3;
    float a0 = x0[idx], a1 = x1[idx];
    const int e0 = v * DEG;
    float acc = 0.f;
#pragma unroll
    for (int e = 0; e < DEG; ++e)
        acc = fmaf(ew[e0 + e], x1[col[e0 + e] * 8 + (idx & 7)], acc);
    float a2 = 2.f * acc - a0;
    float4* dst = (float4*)&out[(size_t)idx * 16];
    bf16x4* dstb = (bf16x4*)&outb[(size_t)idx * 16];
#pragma unroll
    for (int oq = 0; oq < 4; ++oq) {
        float4 r;
        float* rp = (float*)&r;
        bf16x4 rb;
#pragma unroll
        for (int j = 0; j < 4; ++j) {
            int o = oq * 4 + j;
            float h = fmaxf(fmaf(a0, W[o], fmaf(a1, W[16 + o], fmaf(a2, W[32 + o], bias[o]))), 0.f);
            rp[j] = h;
            rb[j] = (__bf16)h;
        }
        dst[oq] = r;
        dstb[oq] = rb;
    }
}

// ---------- x1b = L h1b, bf16 in -> bf16 out (width 128), 16B/lane ----------
__global__ __launch_bounds__(256) void k_spmm_f2b(const __bf16* __restrict__ xin, // h1b [V][128]
                                                  const int* __restrict__ col,
                                                  const float* __restrict__ ew,
                                                  __bf16* __restrict__ xout) {    // [V][128] bf16
    int idx = blockIdx.x * 256 + threadIdx.x;   // over V*16
    int v = idx >> 4;
    int c = (idx & 15) * 8;
    const int e0 = v * DEG;
    float acc[8];
#pragma unroll
    for (int j = 0; j < 8; ++j) acc[j] = 0.f;
#pragma unroll
    for (int e = 0; e < DEG; ++e) {
        float wv = ew[e0 + e];
        bf16x8 p = *(const bf16x8*)&xin[(size_t)col[e0 + e] * 128 + c];
#pragma unroll
        for (int j = 0; j < 8; ++j) acc[j] = fmaf(wv, (float)p[j], acc[j]);
    }
    bf16x8 o;
#pragma unroll
    for (int j = 0; j < 8; ++j) o[j] = (__bf16)acc[j];
    *(bf16x8*)&xout[(size_t)v * 128 + c] = o;
}

// ---------- u = y1 + 2 * (L y2): bf16 in/out, width 128, 16B/lane ----------
__global__ __launch_bounds__(256) void k_spmm_u(const __bf16* __restrict__ y1,
                                                const __bf16* __restrict__ y2,
                                                const int* __restrict__ col,
                                                const float* __restrict__ ew,
                                                __bf16* __restrict__ u) {
    int idx = blockIdx.x * 256 + threadIdx.x;   // over V*16
    int v = idx >> 4;
    int c = (idx & 15) * 8;
    const int e0 = v * DEG;
    float acc[8];
#pragma unroll
    for (int j = 0; j < 8; ++j) acc[j] = 0.f;
#pragma unroll
    for (int e = 0; e < DEG; ++e) {
        float wv = ew[e0 + e];
        bf16x8 p = *(const bf16x8*)&y2[(size_t)col[e0 + e] * 128 + c];
#pragma unroll
        for (int j = 0; j < 8; ++j) acc[j] = fmaf(wv, (float)p[j], acc[j]);
    }
    bf16x8 a = *(const bf16x8*)&y1[(size_t)v * 128 + c];
    bf16x8 o;
#pragma unroll
    for (int j = 0; j < 8; ++j) o[j] = (__bf16)fmaf(2.f, acc[j], (float)a[j]);
    *(bf16x8*)&u[(size_t)v * 128 + c] = o;
}

// ---------- weight prepack into MFMA B-fragment layout (hi/lo split) ----------
// pk: [0,4096)=W2hi  [4096,8192)=W2lo  [8192,11264)=W3hi  [11264,14336)=W3lo
__global__ __launch_bounds__(512) void k_prepack(const float* __restrict__ w2,
                                                 const float* __restrict__ w3,
                                                 __bf16* __restrict__ pk) {
    int t = threadIdx.x;
    {
        int kt = t >> 8, nt = (t >> 6) & 3, lane = t & 63;
#pragma unroll
        for (int e = 0; e < 8; ++e) {
            int k = kt * 32 + ((lane >> 4) * 8) + e;
            float val = (k < 48) ? w2[(k >> 4) * 1024 + (k & 15) * 64 + nt * 16 + (lane & 15)] : 0.f;
            __bf16 hi = (__bf16)val;
            pk[t * 8 + e] = hi;
            pk[4096 + t * 8 + e] = (__bf16)(val - (float)hi);
        }
    }
    if (t < 384) {
        int kt = t / 192, nt = (t / 64) % 3, lane = t & 63;
#pragma unroll
        for (int e = 0; e < 8; ++e) {
            int k = kt * 32 + ((lane >> 4) * 8) + e;
            float val = w3[nt * 1024 + k * 16 + (lane & 15)];
            __bf16 hi = (__bf16)val;
            pk[8192 + t * 8 + e] = hi;
            pk[11264 + t * 8 + e] = (__bf16)(val - (float)hi);
        }
    }
}

// ---------- layer 2 + y projection via split-bf16 MFMA (G=8 only) ----------
// Block = 8 vertices = 4 waves; wave owns a 16-row M-tile (2 vertices x 8 g).
// Staging in 3 single-pass phases (4 els/thread, vec4 loads).
__global__ __launch_bounds__(256) void k_fused2y_mfma(const float* __restrict__ x0,  // h1 [V][128] f32
                                                      const __bf16* __restrict__ x1, // x1b [V][128] bf16
                                                      const int* __restrict__ col,
                                                      const float* __restrict__ ew,
                                                      const __bf16* __restrict__ pk,
                                                      const float* __restrict__ b2,  // [64]
                                                      float* __restrict__ y02,       // [V][128] f32
                                                      __bf16* __restrict__ y1o,      // [V][128] bf16
                                                      __bf16* __restrict__ y2o) {    // [V][128] bf16
    __shared__ __attribute__((aligned(16))) __bf16 s_hi[4][16 * 72];
    __shared__ __attribute__((aligned(16))) __bf16 s_lo[4][16 * 72];
    __shared__ int   sc[8][8];
    __shared__ float sw[8][8];
    const int t = threadIdx.x;
    const int v0 = blockIdx.x * 8;
    if (t < 64) {
        int vl = t >> 3, e = t & 7;
        sc[vl][e] = col[(v0 + vl) * DEG + e];
        sw[vl][e] = ew[(v0 + vl) * DEG + e];
    }
    __syncthreads();
    // zero K-pad (kcol 48..63), pairs
    for (int u = t; u < 512; u += 256) {
        int tile = u >> 7, row = (u >> 3) & 15, i = (u & 7) * 2;
        bf16x2 z; z[0] = (__bf16)0.f; z[1] = (__bf16)0.f;
        *(bf16x2*)&s_hi[tile][row * 72 + 48 + i] = z;
        *(bf16x2*)&s_lo[tile][row * 72 + 48 + i] = z;
    }
    // staging: 3 phases, 4 els/thread each (1024 els = 8 vl x 128)
    const int su = t * 4;
    const int svl = su >> 7, sel = su & 127;          // sel multiple of 4
    const int stile = svl >> 1;
    const int srow = (svl & 1) * 8 + (sel >> 4);
    const int skbase = srow * 72 + (sel & 15);
    const size_t srowg = (size_t)(v0 + svl) * 128;
    {   // phase kch0: x0 fp32 -> hi/lo
        float4 val = *(const float4*)&x0[srowg + sel];
        const float* vp = (const float*)&val;
        bf16x4 hi4, lo4;
#pragma unroll
        for (int j = 0; j < 4; ++j) {
            __bf16 h = (__bf16)vp[j];
            hi4[j] = h;
            lo4[j] = (__bf16)(vp[j] - (float)h);
        }
        *(bf16x4*)&s_hi[stile][skbase] = hi4;
        *(bf16x4*)&s_lo[stile][skbase] = lo4;
    }
    {   // phase kch1: x1 bf16 copy (lo = 0)
        bf16x4 hi4 = *(const bf16x4*)&x1[srowg + sel];
        bf16x4 lo4;
#pragma unroll
        for (int j = 0; j < 4; ++j) lo4[j] = (__bf16)0.f;
        *(bf16x4*)&s_hi[stile][skbase + 16] = hi4;
        *(bf16x4*)&s_lo[stile][skbase + 16] = lo4;
    }
    {   // phase kch2: gather x2 = 2 L x1 - x0
        float a[4] = {0.f, 0.f, 0.f, 0.f};
#pragma unroll
        for (int e = 0; e < DEG; ++e) {
            float wv = sw[svl][e];
            bf16x4 p = *(const bf16x4*)&x1[(size_t)sc[svl][e] * 128 + sel];
#pragma unroll
            for (int j = 0; j < 4; ++j) a[j] = fmaf(wv, (float)p[j], a[j]);
        }
        float4 val = *(const float4*)&x0[srowg + sel];
        const float* vp = (const float*)&val;
        bf16x4 hi4, lo4;
#pragma unroll
        for (int j = 0; j < 4; ++j) {
            float vx = 2.f * a[j] - vp[j];
            __bf16 h = (__bf16)vx;
            hi4[j] = h;
            lo4[j] = (__bf16)(vx - (float)h);
        }
        *(bf16x4*)&s_hi[stile][skbase + 32] = hi4;
        *(bf16x4*)&s_lo[stile][skbase + 32] = lo4;
    }
    __syncthreads();
    const int wv = t >> 6, lane = t & 63;
    const int lrow = lane & 15, lkg = lane >> 4;
    // ---- phase A: h2 = relu(x.W2 + b2) ----
    f32x4 acc[4] = {{0.f,0.f,0.f,0.f},{0.f,0.f,0.f,0.f},{0.f,0.f,0.f,0.f},{0.f,0.f,0.f,0.f}};
#pragma unroll
    for (int kt = 0; kt < 2; ++kt) {
        bf16x8 Ah = *(const bf16x8*)&s_hi[wv][lrow * 72 + kt * 32 + lkg * 8];
        bf16x8 Al = *(const bf16x8*)&s_lo[wv][lrow * 72 + kt * 32 + lkg * 8];
#pragma unroll
        for (int nt = 0; nt < 4; ++nt) {
            bf16x8 Wh = *(const bf16x8*)&pk[((kt * 4 + nt) * 64 + lane) * 8];
            bf16x8 Wl = *(const bf16x8*)&pk[4096 + ((kt * 4 + nt) * 64 + lane) * 8];
            acc[nt] = __builtin_amdgcn_mfma_f32_16x16x32_bf16(Ah, Wh, acc[nt], 0, 0, 0);
            acc[nt] = __builtin_amdgcn_mfma_f32_16x16x32_bf16(Al, Wh, acc[nt], 0, 0, 0);
            acc[nt] = __builtin_amdgcn_mfma_f32_16x16x32_bf16(Ah, Wl, acc[nt], 0, 0, 0);
        }
    }
    // bias + relu -> overwrite OWN tile with h2 as bf16 hi/lo, A-frag layout.
    __builtin_amdgcn_sched_barrier(0);
#pragma unroll
    for (int nt = 0; nt < 4; ++nt) {
        float bias = b2[nt * 16 + lrow];
#pragma unroll
        for (int r = 0; r < 4; ++r) {
            int row = lkg * 4 + r;
            float h = fmaxf(acc[nt][r] + bias, 0.f);
            __bf16 hh = (__bf16)h;
            s_hi[wv][row * 72 + nt * 16 + lrow] = hh;
            s_lo[wv][row * 72 + nt * 16 + lrow] = (__bf16)(h - (float)hh);
        }
    }
    // wave-private tile: intra-wave lgkmcnt ordering suffices, no barrier
    // ---- phase B: y = h2 . W3 ----
    f32x4 accy[3] = {{0.f,0.f,0.f,0.f},{0.f,0.f,0.f,0.f},{0.f,0.f,0.f,0.f}};
#pragma unroll
    for (int kt = 0; kt < 2; ++kt) {
        bf16x8 Ah = *(const bf16x8*)&s_hi[wv][lrow * 72 + kt * 32 + lkg * 8];
        bf16x8 Al = *(const bf16x8*)&s_lo[wv][lrow * 72 + kt * 32 + lkg * 8];
#pragma unroll
        for (int nt = 0; nt < 3; ++nt) {
            bf16x8 Wh = *(const bf16x8*)&pk[8192 + ((kt * 3 + nt) * 64 + lane) * 8];
            bf16x8 Wl = *(const bf16x8*)&pk[11264 + ((kt * 3 + nt) * 64 + lane) * 8];
            accy[nt] = __builtin_amdgcn_mfma_f32_16x16x32_bf16(Ah, Wh, accy[nt], 0, 0, 0);
            accy[nt] = __builtin_amdgcn_mfma_f32_16x16x32_bf16(Al, Wh, accy[nt], 0, 0, 0);
            accy[nt] = __builtin_amdgcn_mfma_f32_16x16x32_bf16(Ah, Wl, accy[nt], 0, 0, 0);
        }
    }
    // store: y02 = y0 - y2 (fp32); y1, y2 bf16
    const int vbase = v0 + wv * 2;
#pragma unroll
    for (int r = 0; r < 4; ++r) {
        int row = lkg * 4 + r;
        int v = vbase + (row >> 3), g = row & 7;
        size_t off = (size_t)v * 128 + g * 16 + lrow;
        y02[off] = accy[0][r] - accy[2][r];
        y1o[off] = (__bf16)accy[1][r];
        y2o[off] = (__bf16)accy[2][r];
    }
}

// ---------- final (G=8): h3 = relu(y02 + L u + b3); out = h3 . w4 + b4 ----------
__global__ __launch_bounds__(256) void k_final_gb(const float* __restrict__ y02, // [V][128] f32
                                                  const __bf16* __restrict__ u,  // [V][128] bf16
                                                  const int* __restrict__ col,
                                                  const float* __restrict__ ew,
                                                  const float* __restrict__ b3,  // [16]
                                                  const float* __restrict__ w4,  // [16]
                                                  const float* __restrict__ b4,  // [1]
                                                  float* __restrict__ out, int b0) {
    int idx = blockIdx.x * 256 + threadIdx.x;   // over V*8
    int v = idx >> 3, g = idx & 7;
    const int e0 = v * DEG;
    float acc[16];
#pragma unroll
    for (int j = 0; j < 16; ++j) acc[j] = 0.f;
#pragma unroll
    for (int e = 0; e < DEG; ++e) {
        float wv = ew[e0 + e];
        const __bf16* src = u + (size_t)col[e0 + e] * 128 + g * 16;
        bf16x8 u0 = *(const bf16x8*)src;
        bf16x8 u1 = *(const bf16x8*)(src + 8);
#pragma unroll
        for (int j = 0; j < 8; ++j) {
            acc[j] = fmaf(wv, (float)u0[j], acc[j]);
            acc[8 + j] = fmaf(wv, (float)u1[j], acc[8 + j]);
        }
    }
    const float4* yp = (const float4*)&y02[(size_t)v * 128 + g * 16];
    float r = b4[0];
#pragma unroll
    for (int q = 0; q < 4; ++q) {
        float4 yv = yp[q];
        const float* py = (const float*)&yv;
#pragma unroll
        for (int j = 0; j < 4; ++j) {
            float h = py[j] + acc[q * 4 + j] + b3[q * 4 + j];
            h = fmaxf(h, 0.f);
            r = fmaf(h, w4[q * 4 + j], r);
        }
    }
    out[(b0 + g) * V_N + v] = r;
}

// ---------- legacy fp32 layer-2+y (G<8 fallback) ----------
template <int G>
__global__ __launch_bounds__(256) void k_fused2y(const float* __restrict__ x0,
                                                 const float* __restrict__ x1,
                                                 const int* __restrict__ col,
                                                 const float* __restrict__ ew,
                                                 const float* __restrict__ W2,
                                                 const float* __restrict__ b2,
                                                 const float* __restrict__ W3,
                                                 float* __restrict__ y) {
    constexpr int R = 16 * G;
    __shared__ float s[4][3 * R];
    __shared__ float sh2[4][G][64];
    __shared__ float sW2[3072];
    __shared__ float sW3[3072];
    __shared__ float sB[64];
    __shared__ int   sc[4][DEG];
    __shared__ float sw[4][DEG];
    const int t = threadIdx.x;
    const int v0 = blockIdx.x * 4;
    for (int j = t; j < 3072; j += 256) { sW2[j] = W2[j]; sW3[j] = W3[j]; }
    if (t < 64) sB[t] = b2[t];
    if (t < 32) {
        int vl = t >> 3, e = t & 7;
        sc[vl][e] = col[(v0 + vl) * DEG + e];
        sw[vl][e] = ew[(v0 + vl) * DEG + e];
    }
    __syncthreads();
    for (int u = t; u < 4 * R; u += 256) {
        int vl = u / R, el = u - vl * R;
        size_t row = (size_t)(v0 + vl) * R;
        float a0 = x0[row + el];
        float a1 = x1[row + el];
        s[vl][0 * R + el] = a0;
        s[vl][1 * R + el] = a1;
        float acc = 0.f;
#pragma unroll
        for (int e = 0; e < DEG; ++e)
            acc = fmaf(sw[vl][e], x1[(size_t)sc[vl][e] * R + el], acc);
        s[vl][2 * R + el] = 2.f * acc - a0;
    }
    __syncthreads();
    const int vl = t >> 6, o = t & 63;
    float wc[48];
#pragma unroll
    for (int k = 0; k < 3; ++k)
#pragma unroll
        for (int i = 0; i < 16; ++i)
            wc[k * 16 + i] = sW2[k * 1024 + i * 64 + o];
    float bias = sB[o];
#pragma unroll
    for (int g = 0; g < G; ++g) {
        float r = bias;
#pragma unroll
        for (int k = 0; k < 3; ++k) {
            const float4* ap = (const float4*)&s[vl][k * R + g * 16];
#pragma unroll
            for (int iq = 0; iq < 4; ++iq) {
                float4 a = ap[iq];
                r = fmaf(a.x, wc[k * 16 + iq * 4 + 0], r);
                r = fmaf(a.y, wc[k * 16 + iq * 4 + 1], r);
                r = fmaf(a.z, wc[k * 16 + iq * 4 + 2], r);
                r = fmaf(a.w, wc[k * 16 + iq * 4 + 3], r);
            }
        }
        sh2[vl][g][o] = fmaxf(r, 0.f);
    }
    __syncthreads();
    if (o < 48) {
        const int k3 = o >> 4, o3 = o & 15;
        float wy[64];
#pragma unroll
        for (int i = 0; i < 64; ++i)
            wy[i] = sW3[k3 * 1024 + i * 16 + o3];
        size_t yrow = (size_t)(v0 + vl) * (48 * G) + (size_t)k3 * (16 * G) + o3;
#pragma unroll
        for (int g = 0; g < G; ++g) {
            float r = 0.f;
            const float4* hp = (const float4*)&sh2[vl][g][0];
#pragma unroll
            for (int iq = 0; iq < 16; ++iq) {
                float4 h = hp[iq];
                r = fmaf(h.x, wy[iq * 4 + 0], r);
                r = fmaf(h.y, wy[iq * 4 + 1], r);
                r = fmaf(h.z, wy[iq * 4 + 2], r);
                r = fmaf(h.w, wy[iq * 4 + 3], r);
            }
            y[yrow + (size_t)g * 16] = r;
        }
    }
}

// ---------- legacy final (G<8 fallback) ----------
template <int G>
__global__ __launch_bounds__(256) void k_final_g(const float* __restrict__ y,
                                                 const float* __restrict__ z,
                                                 const int* __restrict__ col,
                                                 const float* __restrict__ ew,
                                                 const float* __restrict__ b3,
                                                 const float* __restrict__ w4,
                                                 const float* __restrict__ b4,
                                                 float* __restrict__ out, int b0) {
    int idx = blockIdx.x * 256 + threadIdx.x;   // over V*G
    int v = idx / G, g = idx - v * G;
    const size_t yr = (size_t)v * (48 * G) + g * 16;
    const size_t zr = (size_t)v * (32 * G) + g * 16;
    const int e0 = v * DEG;
    float4 acc[4];
#pragma unroll
    for (int q = 0; q < 4; ++q) acc[q] = make_float4(0.f, 0.f, 0.f, 0.f);
#pragma unroll
    for (int e = 0; e < DEG; ++e) {
        float wv = ew[e0 + e];
        const float* src = z + (size_t)col[e0 + e] * (32 * G) + 16 * G + g * 16;
#pragma unroll
        for (int q = 0; q < 4; ++q) {
            float4 u = *(const float4*)(src + q * 4);
            acc[q].x = fmaf(wv, u.x, acc[q].x);
            acc[q].y = fmaf(wv, u.y, acc[q].y);
            acc[q].z = fmaf(wv, u.z, acc[q].z);
            acc[q].w = fmaf(wv, u.w, acc[q].w);
        }
    }
    float r = b4[0];
#pragma unroll
    for (int q = 0; q < 4; ++q) {
        float4 y0v = *(const float4*)(y + yr + q * 4);
        float4 y2v = *(const float4*)(y + yr + (size_t)32 * G + q * 4);
        float4 z1v = *(const float4*)(z + zr + q * 4);
        const float* a = (const float*)&acc[q];
        const float* p0 = (const float*)&y0v;
        const float* p2 = (const float*)&y2v;
        const float* p1 = (const float*)&z1v;
#pragma unroll
        for (int j = 0; j < 4; ++j) {
            float h = p0[j] - p2[j] + p1[j] + 2.f * a[j] + b3[q * 4 + j];
            h = fmaxf(h, 0.f);
            r = fmaf(h, w4[q * 4 + j], r);
        }
    }
    out[(b0 + g) * V_N + v] = r;
}

// ---------- pipeline driver ----------
template <int G>
static void run_pipeline(const float* x, const int* ecol, const float* ew,
                         const float* w1, const float* b1, const float* w2, const float* b2,
                         const float* w3, const float* b3, const float* w4, const float* b4,
                         float* out, float* ws, hipStream_t stream) {
    const size_t V = V_N;
    dim3 blk(256);
    if constexpr (G == 8) {
        // layout (floats): xT 8V | x1 8V | h1 128V | h1b 64V(bf16) | x1b 64V(bf16) |
        //                  y02 128V | y1 64V(bf16) | y2 64V(bf16) | pk  -> 528V+pk <= 656V
        float*  xT  = ws;
        float*  x1  = xT + 8 * V;
        float*  h1  = x1 + 8 * V;
        __bf16* h1b = (__bf16*)(h1 + 128 * V);
        __bf16* x1b = (__bf16*)(h1 + 192 * V);
        float*  y02 = h1 + 256 * V;
        __bf16* y1b = (__bf16*)(y02 + 128 * V);
        __bf16* y2b = y1b + 128 * V;          // bf16 elements
        __bf16* ub  = x1b;                    // reuse x1b after fused2y
        __bf16* pk  = (__bf16*)(h1 + 512 * V); // dedicated spare (no aliasing)
        k_prepack<<<1, 512, 0, stream>>>(w2, w3, pk);   // once: weights pass-invariant
        for (int b0 = 0; b0 < B_N; b0 += 8) {
            k_transpose_g<8><<<(V * 8) / 256, blk, 0, stream>>>(x, xT, b0);
            k_spmm_g<8><<<(V * 8) / 256, blk, 0, stream>>>(xT, ecol, ew, x1);
            k_fused1_gb<<<(V * 8) / 256, blk, 0, stream>>>(xT, x1, ecol, ew, w1, b1, h1, h1b);
            k_spmm_f2b<<<(V * 16) / 256, blk, 0, stream>>>(h1b, ecol, ew, x1b);
            k_fused2y_mfma<<<V / 8, blk, 0, stream>>>(h1, x1b, ecol, ew, pk, b2, y02, y1b, y2b);
            k_spmm_u<<<(V * 16) / 256, blk, 0, stream>>>(y1b, y2b, ecol, ew, ub);
            k_final_gb<<<(V * 8) / 256, blk, 0, stream>>>(y02, ub, ecol, ew, b3, w4, b4, out, b0);
        }
    } else {
        const size_t GV = (size_t)G * V;
        float* xT   = ws;
        float* x1   = xT + GV;
        float* h1   = x1 + GV;
        float* x1b  = h1 + 16 * GV;
        float* y012 = x1b + 16 * GV;
        float* z12  = h1;
        for (int b0 = 0; b0 < B_N; b0 += G) {
            k_transpose_g<G><<<(V * G) / 256, blk, 0, stream>>>(x, xT, b0);
            k_spmm_g<G><<<(V * G) / 256, blk, 0, stream>>>(xT, ecol, ew, x1);
            k_fused1_g<G><<<(V * G) / 256, blk, 0, stream>>>(xT, x1, ecol, ew, w1, b1, h1);
            k_spmm_v<4 * G><<<(V * 4 * G) / 256, blk, 0, stream>>>(h1, ecol, ew, x1b);
            k_fused2y<G><<<V / 4, blk, 0, stream>>>(h1, x1b, ecol, ew, w2, b2, w3, y012);
            k_spmm_vs<8 * G><<<(V * 8 * G) / 256, blk, 0, stream>>>(
                y012 + 16 * G, 48 * G, ecol, ew, z12, 32 * G);
            k_final_g<G><<<(V * G) / 256, blk, 0, stream>>>(y012, z12, ecol, ew, b3, w4, b4, out, b0);
        }
    }
}

extern "C" void kernel_launch(void* const* d_in, const int* in_sizes, int n_in,
                              void* d_out, int out_size, void* d_ws, size_t ws_size,
                              hipStream_t stream) {
    const float* x = (const float*)d_in[0];
    // d_in[1] = edge_row = repeat(arange(V), 8) -> implicit, unused
    const int* ecol = (const int*)d_in[2];
    const float* ew = (const float*)d_in[3];
    const float* w1 = (const float*)d_in[4];
    const float* b1 = (const float*)d_in[5];
    const float* w2 = (const float*)d_in[6];
    const float* b2 = (const float*)d_in[7];
    const float* w3 = (const float*)d_in[8];
    const float* b3 = (const float*)d_in[9];
    const float* w4 = (const float*)d_in[10];
    const float* b4 = (const float*)d_in[11];
    float* out = (float*)d_out;
    float* ws = (float*)d_ws;

    auto need = [](int G) { return (size_t)82 * G * V_N * 4; };
    if (ws_size >= need(8))
        run_pipeline<8>(x, ecol, ew, w1, b1, w2, b2, w3, b3, w4, b4, out, ws, stream);
    else if (ws_size >= need(4))
        run_pipeline<4>(x, ecol, ew, w1, b1, w2, b2, w3, b3, w4, b4, out, ws, stream);
    else if (ws_size >= need(2))
        run_pipeline<2>(x, ecol, ew, w1, b1, w2, b2, w3, b3, w4, b4, out, ws, stream);
    else
        run_pipeline<1>(x, ecol, ew, w1, b1, w2, b2, w3, b3, w4, b4, out, ws, stream);
}

// Round 15
// 207.246 us; speedup vs baseline: 5.7792x; 1.1258x over previous
//
#include <hip/hip_runtime.h>

#define V_N 49152
#define B_N 16
#define DEG 8

typedef __bf16 bf16x8 __attribute__((ext_vector_type(8)));
typedef __bf16 bf16x4 __attribute__((ext_vector_type(4)));
typedef __bf16 bf16x2 __attribute__((ext_vector_type(2)));
typedef float f32x4 __attribute__((ext_vector_type(4)));

// ChebNet, vertex-major, batch-grouped. Both 8-batch groups processed in ONE
// launch set when workspace allows (rows laid out [NB][V]; gathers use
// grp*V + col[v]). Layer-3 commuting trick + linearity fold:
//   h3 = relu(y0 - y2 + L(y1 + 2 L y2) + b3),  yk = relu(h2).W3_k
// All gather sources bf16; h1 dual-stored (f32 direct / bf16 gathered);
// y02 = y0-y2 stored bf16 (additive pre-ReLU term).

// ---------- transpose: x[B,V] slice -> xT[(grp*V+v)*8+g] ----------
__global__ __launch_bounds__(256) void k_transpose(const float* __restrict__ x,
                                                   float* __restrict__ xT, int b0) {
    int idx = blockIdx.x * 256 + threadIdx.x;   // (bg, v), v inner: coalesced read
    int v = idx % V_N, bg = idx / V_N;          // bg in [0, NB*8)
    xT[((size_t)(bg >> 3) * V_N + v) * 8 + (bg & 7)] = x[(size_t)(b0 + bg) * V_N + v];
}

// ---------- x1 = L xT, width 8 ----------
__global__ __launch_bounds__(256) void k_spmm_g8(const float* __restrict__ xin,
                                                 const int* __restrict__ col,
                                                 const float* __restrict__ ew,
                                                 float* __restrict__ xout) {
    int idx = blockIdx.x * 256 + threadIdx.x;   // over NR*8
    int vv = idx >> 3, b = idx & 7;
    int grp = vv >= V_N;
    int v = vv - (grp ? V_N : 0);
    int goff = grp ? V_N : 0;
    const int e0 = v * DEG;
    float acc = 0.f;
#pragma unroll
    for (int e = 0; e < DEG; ++e)
        acc = fmaf(ew[e0 + e], xin[(size_t)(goff + col[e0 + e]) * 8 + b], acc);
    xout[idx] = acc;
}

// ---------- layer 1 fused: dual-store h1 (f32 + bf16) ----------
__global__ __launch_bounds__(256) void k_fused1_gb(const float* __restrict__ x0,
                                                   const float* __restrict__ x1,
                                                   const int* __restrict__ col,
                                                   const float* __restrict__ ew,
                                                   const float* __restrict__ W,   // [3][1][16]
                                                   const float* __restrict__ bias,// [16]
                                                   float* __restrict__ out,       // h1 [NR][128] f32
                                                   __bf16* __restrict__ outb) {   // h1b [NR][128] bf16
    int idx = blockIdx.x * 256 + threadIdx.x;   // (vv, g)
    int vv = idx >> 3, g = idx & 7;
    int grp = vv >= V_N;
    int v = vv - (grp ? V_N : 0);
    int goff = grp ? V_N : 0;
    float a0 = x0[idx], a1 = x1[idx];
    const int e0 = v * DEG;
    float acc = 0.f;
#pragma unroll
    for (int e = 0; e < DEG; ++e)
        acc = fmaf(ew[e0 + e], x1[(size_t)(goff + col[e0 + e]) * 8 + g], acc);
    float a2 = 2.f * acc - a0;
    float4* dst = (float4*)&out[(size_t)idx * 16];
    bf16x4* dstb = (bf16x4*)&outb[(size_t)idx * 16];
#pragma unroll
    for (int oq = 0; oq < 4; ++oq) {
        float4 r;
        float* rp = (float*)&r;
        bf16x4 rb;
#pragma unroll
        for (int j = 0; j < 4; ++j) {
            int o = oq * 4 + j;
            float h = fmaxf(fmaf(a0, W[o], fmaf(a1, W[16 + o], fmaf(a2, W[32 + o], bias[o]))), 0.f);
            rp[j] = h;
            rb[j] = (__bf16)h;
        }
        dst[oq] = r;
        dstb[oq] = rb;
    }
}

// ---------- x1b = L h1b, bf16, width 128, 16B/lane ----------
__global__ __launch_bounds__(256) void k_spmm_f2b(const __bf16* __restrict__ xin,
                                                  const int* __restrict__ col,
                                                  const float* __restrict__ ew,
                                                  __bf16* __restrict__ xout) {
    int idx = blockIdx.x * 256 + threadIdx.x;   // over NR*16
    int vv = idx >> 4;
    int c = (idx & 15) * 8;
    int grp = vv >= V_N;
    int v = vv - (grp ? V_N : 0);
    int goff = grp ? V_N : 0;
    const int e0 = v * DEG;
    float acc[8];
#pragma unroll
    for (int j = 0; j < 8; ++j) acc[j] = 0.f;
#pragma unroll
    for (int e = 0; e < DEG; ++e) {
        float wv = ew[e0 + e];
        bf16x8 p = *(const bf16x8*)&xin[(size_t)(goff + col[e0 + e]) * 128 + c];
#pragma unroll
        for (int j = 0; j < 8; ++j) acc[j] = fmaf(wv, (float)p[j], acc[j]);
    }
    bf16x8 o;
#pragma unroll
    for (int j = 0; j < 8; ++j) o[j] = (__bf16)acc[j];
    *(bf16x8*)&xout[(size_t)vv * 128 + c] = o;
}

// ---------- u = y1 + 2 * (L y2), bf16, width 128, 16B/lane ----------
__global__ __launch_bounds__(256) void k_spmm_u(const __bf16* __restrict__ y1,
                                                const __bf16* __restrict__ y2,
                                                const int* __restrict__ col,
                                                const float* __restrict__ ew,
                                                __bf16* __restrict__ u) {
    int idx = blockIdx.x * 256 + threadIdx.x;   // over NR*16
    int vv = idx >> 4;
    int c = (idx & 15) * 8;
    int grp = vv >= V_N;
    int v = vv - (grp ? V_N : 0);
    int goff = grp ? V_N : 0;
    const int e0 = v * DEG;
    float acc[8];
#pragma unroll
    for (int j = 0; j < 8; ++j) acc[j] = 0.f;
#pragma unroll
    for (int e = 0; e < DEG; ++e) {
        float wv = ew[e0 + e];
        bf16x8 p = *(const bf16x8*)&y2[(size_t)(goff + col[e0 + e]) * 128 + c];
#pragma unroll
        for (int j = 0; j < 8; ++j) acc[j] = fmaf(wv, (float)p[j], acc[j]);
    }
    bf16x8 a = *(const bf16x8*)&y1[(size_t)vv * 128 + c];
    bf16x8 o;
#pragma unroll
    for (int j = 0; j < 8; ++j) o[j] = (__bf16)fmaf(2.f, acc[j], (float)a[j]);
    *(bf16x8*)&u[(size_t)vv * 128 + c] = o;
}

// ---------- weight prepack into MFMA B-fragment layout (hi/lo split) ----------
// pk: [0,4096)=W2hi  [4096,8192)=W2lo  [8192,11264)=W3hi  [11264,14336)=W3lo
__global__ __launch_bounds__(512) void k_prepack(const float* __restrict__ w2,
                                                 const float* __restrict__ w3,
                                                 __bf16* __restrict__ pk) {
    int t = threadIdx.x;
    {
        int kt = t >> 8, nt = (t >> 6) & 3, lane = t & 63;
#pragma unroll
        for (int e = 0; e < 8; ++e) {
            int k = kt * 32 + ((lane >> 4) * 8) + e;
            float val = (k < 48) ? w2[(k >> 4) * 1024 + (k & 15) * 64 + nt * 16 + (lane & 15)] : 0.f;
            __bf16 hi = (__bf16)val;
            pk[t * 8 + e] = hi;
            pk[4096 + t * 8 + e] = (__bf16)(val - (float)hi);
        }
    }
    if (t < 384) {
        int kt = t / 192, nt = (t / 64) % 3, lane = t & 63;
#pragma unroll
        for (int e = 0; e < 8; ++e) {
            int k = kt * 32 + ((lane >> 4) * 8) + e;
            float val = w3[nt * 1024 + k * 16 + (lane & 15)];
            __bf16 hi = (__bf16)val;
            pk[8192 + t * 8 + e] = hi;
            pk[11264 + t * 8 + e] = (__bf16)(val - (float)hi);
        }
    }
}

// ---------- layer 2 + y projection via split-bf16 MFMA ----------
// Block = 8 rows (one group) = 4 waves; wave owns 16-row M-tile (2 rows x 8 g).
__global__ __launch_bounds__(256) void k_fused2y_mfma(const float* __restrict__ x0,  // h1 [NR][128] f32
                                                      const __bf16* __restrict__ x1, // x1b [NR][128] bf16
                                                      const int* __restrict__ col,
                                                      const float* __restrict__ ew,
                                                      const __bf16* __restrict__ pk,
                                                      const float* __restrict__ b2,  // [64]
                                                      __bf16* __restrict__ y02o,     // [NR][128] bf16
                                                      __bf16* __restrict__ y1o,      // [NR][128] bf16
                                                      __bf16* __restrict__ y2o) {    // [NR][128] bf16
    __shared__ __attribute__((aligned(16))) __bf16 s_hi[4][16 * 72];
    __shared__ __attribute__((aligned(16))) __bf16 s_lo[4][16 * 72];
    __shared__ int   sc[8][8];
    __shared__ float sw[8][8];
    const int t = threadIdx.x;
    const int v0 = blockIdx.x * 8;                 // global row base (one group)
    const int grp = v0 >= V_N;
    const int vloc = v0 - (grp ? V_N : 0);
    const int goff = grp ? V_N : 0;
    if (t < 64) {
        int vl = t >> 3, e = t & 7;
        sc[vl][e] = goff + col[(vloc + vl) * DEG + e];   // pre-offset gather row
        sw[vl][e] = ew[(vloc + vl) * DEG + e];
    }
    __syncthreads();
    // zero K-pad (kcol 48..63)
    for (int u = t; u < 512; u += 256) {
        int tile = u >> 7, row = (u >> 3) & 15, i = (u & 7) * 2;
        bf16x2 z; z[0] = (__bf16)0.f; z[1] = (__bf16)0.f;
        *(bf16x2*)&s_hi[tile][row * 72 + 48 + i] = z;
        *(bf16x2*)&s_lo[tile][row * 72 + 48 + i] = z;
    }
    // staging: 3 phases, 4 els/thread (1024 els = 8 rows x 128)
    const int su = t * 4;
    const int svl = su >> 7, sel = su & 127;
    const int stile = svl >> 1;
    const int srow = (svl & 1) * 8 + (sel >> 4);
    const int skbase = srow * 72 + (sel & 15);
    const size_t srowg = (size_t)(v0 + svl) * 128;
    {   // kch0: x0 fp32 -> hi/lo
        float4 val = *(const float4*)&x0[srowg + sel];
        const float* vp = (const float*)&val;
        bf16x4 hi4, lo4;
#pragma unroll
        for (int j = 0; j < 4; ++j) {
            __bf16 h = (__bf16)vp[j];
            hi4[j] = h;
            lo4[j] = (__bf16)(vp[j] - (float)h);
        }
        *(bf16x4*)&s_hi[stile][skbase] = hi4;
        *(bf16x4*)&s_lo[stile][skbase] = lo4;
    }
    {   // kch1: x1 bf16 copy (lo = 0)
        bf16x4 hi4 = *(const bf16x4*)&x1[srowg + sel];
        bf16x4 lo4;
#pragma unroll
        for (int j = 0; j < 4; ++j) lo4[j] = (__bf16)0.f;
        *(bf16x4*)&s_hi[stile][skbase + 16] = hi4;
        *(bf16x4*)&s_lo[stile][skbase + 16] = lo4;
    }
    {   // kch2: gather x2 = 2 L x1 - x0
        float a[4] = {0.f, 0.f, 0.f, 0.f};
#pragma unroll
        for (int e = 0; e < DEG; ++e) {
            float wv = sw[svl][e];
            bf16x4 p = *(const bf16x4*)&x1[(size_t)sc[svl][e] * 128 + sel];
#pragma unroll
            for (int j = 0; j < 4; ++j) a[j] = fmaf(wv, (float)p[j], a[j]);
        }
        float4 val = *(const float4*)&x0[srowg + sel];
        const float* vp = (const float*)&val;
        bf16x4 hi4, lo4;
#pragma unroll
        for (int j = 0; j < 4; ++j) {
            float vx = 2.f * a[j] - vp[j];
            __bf16 h = (__bf16)vx;
            hi4[j] = h;
            lo4[j] = (__bf16)(vx - (float)h);
        }
        *(bf16x4*)&s_hi[stile][skbase + 32] = hi4;
        *(bf16x4*)&s_lo[stile][skbase + 32] = lo4;
    }
    __syncthreads();
    const int wv = t >> 6, lane = t & 63;
    const int lrow = lane & 15, lkg = lane >> 4;
    // ---- phase A: h2 = relu(x.W2 + b2) ----
    f32x4 acc[4] = {{0.f,0.f,0.f,0.f},{0.f,0.f,0.f,0.f},{0.f,0.f,0.f,0.f},{0.f,0.f,0.f,0.f}};
#pragma unroll
    for (int kt = 0; kt < 2; ++kt) {
        bf16x8 Ah = *(const bf16x8*)&s_hi[wv][lrow * 72 + kt * 32 + lkg * 8];
        bf16x8 Al = *(const bf16x8*)&s_lo[wv][lrow * 72 + kt * 32 + lkg * 8];
#pragma unroll
        for (int nt = 0; nt < 4; ++nt) {
            bf16x8 Wh = *(const bf16x8*)&pk[((kt * 4 + nt) * 64 + lane) * 8];
            bf16x8 Wl = *(const bf16x8*)&pk[4096 + ((kt * 4 + nt) * 64 + lane) * 8];
            acc[nt] = __builtin_amdgcn_mfma_f32_16x16x32_bf16(Ah, Wh, acc[nt], 0, 0, 0);
            acc[nt] = __builtin_amdgcn_mfma_f32_16x16x32_bf16(Al, Wh, acc[nt], 0, 0, 0);
            acc[nt] = __builtin_amdgcn_mfma_f32_16x16x32_bf16(Ah, Wl, acc[nt], 0, 0, 0);
        }
    }
    // bias + relu -> overwrite OWN wave-private tile with h2 (bf16 hi/lo, A-frag layout)
    __builtin_amdgcn_sched_barrier(0);
#pragma unroll
    for (int nt = 0; nt < 4; ++nt) {
        float bias = b2[nt * 16 + lrow];
#pragma unroll
        for (int r = 0; r < 4; ++r) {
            int row = lkg * 4 + r;
            float h = fmaxf(acc[nt][r] + bias, 0.f);
            __bf16 hh = (__bf16)h;
            s_hi[wv][row * 72 + nt * 16 + lrow] = hh;
            s_lo[wv][row * 72 + nt * 16 + lrow] = (__bf16)(h - (float)hh);
        }
    }
    // wave-private tile: intra-wave lgkmcnt ordering suffices, no barrier
    // ---- phase B: y = h2 . W3 ----
    f32x4 accy[3] = {{0.f,0.f,0.f,0.f},{0.f,0.f,0.f,0.f},{0.f,0.f,0.f,0.f}};
#pragma unroll
    for (int kt = 0; kt < 2; ++kt) {
        bf16x8 Ah = *(const bf16x8*)&s_hi[wv][lrow * 72 + kt * 32 + lkg * 8];
        bf16x8 Al = *(const bf16x8*)&s_lo[wv][lrow * 72 + kt * 32 + lkg * 8];
#pragma unroll
        for (int nt = 0; nt < 3; ++nt) {
            bf16x8 Wh = *(const bf16x8*)&pk[8192 + ((kt * 3 + nt) * 64 + lane) * 8];
            bf16x8 Wl = *(const bf16x8*)&pk[11264 + ((kt * 3 + nt) * 64 + lane) * 8];
            accy[nt] = __builtin_amdgcn_mfma_f32_16x16x32_bf16(Ah, Wh, accy[nt], 0, 0, 0);
            accy[nt] = __builtin_amdgcn_mfma_f32_16x16x32_bf16(Al, Wh, accy[nt], 0, 0, 0);
            accy[nt] = __builtin_amdgcn_mfma_f32_16x16x32_bf16(Ah, Wl, accy[nt], 0, 0, 0);
        }
    }
    // store: y02 = y0 - y2 (bf16); y1, y2 bf16
    const int vbase = v0 + wv * 2;
#pragma unroll
    for (int r = 0; r < 4; ++r) {
        int row = lkg * 4 + r;
        int v = vbase + (row >> 3), g = row & 7;
        size_t off = (size_t)v * 128 + g * 16 + lrow;
        y02o[off] = (__bf16)(accy[0][r] - accy[2][r]);
        y1o[off] = (__bf16)accy[1][r];
        y2o[off] = (__bf16)accy[2][r];
    }
}

// ---------- final: h3 = relu(y02 + L u + b3); out = h3 . w4 + b4 ----------
__global__ __launch_bounds__(256) void k_final_gb(const __bf16* __restrict__ y02, // [NR][128] bf16
                                                  const __bf16* __restrict__ u,   // [NR][128] bf16
                                                  const int* __restrict__ col,
                                                  const float* __restrict__ ew,
                                                  const float* __restrict__ b3,   // [16]
                                                  const float* __restrict__ w4,   // [16]
                                                  const float* __restrict__ b4,   // [1]
                                                  float* __restrict__ out, int b0) {
    int idx = blockIdx.x * 256 + threadIdx.x;   // over NR*8
    int vv = idx >> 3, g = idx & 7;
    int grp = vv >= V_N;
    int v = vv - (grp ? V_N : 0);
    int goff = grp ? V_N : 0;
    const int e0 = v * DEG;
    float acc[16];
#pragma unroll
    for (int j = 0; j < 16; ++j) acc[j] = 0.f;
#pragma unroll
    for (int e = 0; e < DEG; ++e) {
        float wv = ew[e0 + e];
        const __bf16* src = u + (size_t)(goff + col[e0 + e]) * 128 + g * 16;
        bf16x8 u0 = *(const bf16x8*)src;
        bf16x8 u1 = *(const bf16x8*)(src + 8);
#pragma unroll
        for (int j = 0; j < 8; ++j) {
            acc[j] = fmaf(wv, (float)u0[j], acc[j]);
            acc[8 + j] = fmaf(wv, (float)u1[j], acc[8 + j]);
        }
    }
    const __bf16* yp = y02 + (size_t)vv * 128 + g * 16;
    bf16x8 y0v = *(const bf16x8*)yp;
    bf16x8 y1v = *(const bf16x8*)(yp + 8);
    float r = b4[0];
#pragma unroll
    for (int j = 0; j < 8; ++j) {
        float h = fmaxf((float)y0v[j] + acc[j] + b3[j], 0.f);
        r = fmaf(h, w4[j], r);
        float h2 = fmaxf((float)y1v[j] + acc[8 + j] + b3[8 + j], 0.f);
        r = fmaf(h2, w4[8 + j], r);
    }
    out[(size_t)(b0 + grp * 8 + g) * V_N + v] = r;
}

// ---------- driver ----------
extern "C" void kernel_launch(void* const* d_in, const int* in_sizes, int n_in,
                              void* d_out, int out_size, void* d_ws, size_t ws_size,
                              hipStream_t stream) {
    const float* x = (const float*)d_in[0];
    // d_in[1] = edge_row = repeat(arange(V), 8) -> implicit, unused
    const int* ecol = (const int*)d_in[2];
    const float* ew = (const float*)d_in[3];
    const float* w1 = (const float*)d_in[4];
    const float* b1 = (const float*)d_in[5];
    const float* w2 = (const float*)d_in[6];
    const float* b2 = (const float*)d_in[7];
    const float* w3 = (const float*)d_in[8];
    const float* b3 = (const float*)d_in[9];
    const float* w4 = (const float*)d_in[10];
    const float* b4 = (const float*)d_in[11];
    float* out = (float*)d_out;
    float* ws = (float*)d_ws;

    const size_t V = V_N;
    // merged (NB=2) needs 400*2V + 8192 floats = ~157.3MB; NB=1 needs ~78.7MB.
    // ws >= 129MB is established (G=8 ladder ran rounds 2-13).
    const size_t need2 = (size_t)(800 * V + 8192) * 4;
    const int NB = (ws_size >= need2) ? 2 : 1;
    const size_t VR = (size_t)NB * V;          // rows per launch set

    // layout (floats): xT 8VR | x1 8VR | h1 128VR(f32) | h1b 64VR | x1b 64VR |
    //                  y02b 64VR | y2b 64VR | pk 7168   (y1b aliases h1b; u aliases x1b)
    float*  xT   = ws;
    float*  x1   = xT + 8 * VR;
    float*  h1   = x1 + 8 * VR;
    __bf16* h1b  = (__bf16*)(h1 + 128 * VR);
    __bf16* x1b  = (__bf16*)(h1 + 192 * VR);
    __bf16* y02b = (__bf16*)(h1 + 256 * VR);
    __bf16* y2b  = (__bf16*)(h1 + 320 * VR);
    __bf16* y1b  = h1b;                        // h1b dead after k_spmm_f2b
    __bf16* ub   = x1b;                        // x1b dead after k_fused2y_mfma
    __bf16* pk   = (__bf16*)(h1 + 384 * VR);

    dim3 blk(256);
    k_prepack<<<1, 512, 0, stream>>>(w2, w3, pk);   // weights: once per call
    for (int b0 = 0; b0 < B_N; b0 += NB * 8) {
        k_transpose<<<(VR * 8) / 256, blk, 0, stream>>>(x, xT, b0);
        k_spmm_g8<<<(VR * 8) / 256, blk, 0, stream>>>(xT, ecol, ew, x1);
        k_fused1_gb<<<(VR * 8) / 256, blk, 0, stream>>>(xT, x1, ecol, ew, w1, b1, h1, h1b);
        k_spmm_f2b<<<(VR * 16) / 256, blk, 0, stream>>>(h1b, ecol, ew, x1b);
        k_fused2y_mfma<<<VR / 8, blk, 0, stream>>>(h1, x1b, ecol, ew, pk, b2, y02b, y1b, y2b);
        k_spmm_u<<<(VR * 16) / 256, blk, 0, stream>>>(y1b, y2b, ecol, ew, ub);
        k_final_gb<<<(VR * 8) / 256, blk, 0, stream>>>(y02b, ub, ecol, ew, b3, w4, b4, out, b0);
    }
}

// Round 17
// 190.182 us; speedup vs baseline: 6.2977x; 1.0897x over previous
//
#include <hip/hip_runtime.h>

#define V_N 49152
#define B_N 16
#define DEG 8

typedef __bf16 bf16x8 __attribute__((ext_vector_type(8)));
typedef __bf16 bf16x4 __attribute__((ext_vector_type(4)));
typedef __bf16 bf16x2 __attribute__((ext_vector_type(2)));
typedef float f32x4 __attribute__((ext_vector_type(4)));

// ChebNet, vertex-major, both 8-batch groups in one launch set (rows [NB][V]).
// Layer-3 commuting trick + linearity fold:
//   h3 = relu(y0 - y2 + L(y1 + 2 L y2) + b3),  yk = relu(h2).W3_k
// ALL intermediates bf16 (h1 single-stored bf16; y02 = y0-y2 bf16).
// NOTE: each [VR][128] bf16 buffer = 64*VR floats (round-16 bug was 32*VR).

// ---------- transpose: x[B,V] slice -> xT[(grp*V+v)*8+g] ----------
__global__ __launch_bounds__(256) void k_transpose(const float* __restrict__ x,
                                                   float* __restrict__ xT, int b0) {
    int idx = blockIdx.x * 256 + threadIdx.x;   // (bg, v), v inner: coalesced read
    int v = idx % V_N, bg = idx / V_N;          // bg in [0, NB*8)
    xT[((size_t)(bg >> 3) * V_N + v) * 8 + (bg & 7)] = x[(size_t)(b0 + bg) * V_N + v];
}

// ---------- x1 = L xT, width 8 ----------
__global__ __launch_bounds__(256) void k_spmm_g8(const float* __restrict__ xin,
                                                 const int* __restrict__ col,
                                                 const float* __restrict__ ew,
                                                 float* __restrict__ xout) {
    int idx = blockIdx.x * 256 + threadIdx.x;   // over NR*8
    int vv = idx >> 3, b = idx & 7;
    int grp = vv >= V_N;
    int v = vv - (grp ? V_N : 0);
    int goff = grp ? V_N : 0;
    const int e0 = v * DEG;
    float acc = 0.f;
#pragma unroll
    for (int e = 0; e < DEG; ++e)
        acc = fmaf(ew[e0 + e], xin[(size_t)(goff + col[e0 + e]) * 8 + b], acc);
    xout[idx] = acc;
}

// ---------- layer 1 fused: h1 (bf16 only) ----------
__global__ __launch_bounds__(256) void k_fused1_b(const float* __restrict__ x0,
                                                  const float* __restrict__ x1,
                                                  const int* __restrict__ col,
                                                  const float* __restrict__ ew,
                                                  const float* __restrict__ W,   // [3][1][16]
                                                  const float* __restrict__ bias,// [16]
                                                  __bf16* __restrict__ outb) {   // h1b [NR][128] bf16
    int idx = blockIdx.x * 256 + threadIdx.x;   // (vv, g)
    int vv = idx >> 3, g = idx & 7;
    int grp = vv >= V_N;
    int v = vv - (grp ? V_N : 0);
    int goff = grp ? V_N : 0;
    float a0 = x0[idx], a1 = x1[idx];
    const int e0 = v * DEG;
    float acc = 0.f;
#pragma unroll
    for (int e = 0; e < DEG; ++e)
        acc = fmaf(ew[e0 + e], x1[(size_t)(goff + col[e0 + e]) * 8 + g], acc);
    float a2 = 2.f * acc - a0;
    bf16x8* dstb = (bf16x8*)&outb[(size_t)idx * 16];
#pragma unroll
    for (int oq = 0; oq < 2; ++oq) {
        bf16x8 rb;
#pragma unroll
        for (int j = 0; j < 8; ++j) {
            int o = oq * 8 + j;
            float h = fmaxf(fmaf(a0, W[o], fmaf(a1, W[16 + o], fmaf(a2, W[32 + o], bias[o]))), 0.f);
            rb[j] = (__bf16)h;
        }
        dstb[oq] = rb;
    }
}

// ---------- x1b = L h1b, bf16, width 128, 16B/lane ----------
__global__ __launch_bounds__(256) void k_spmm_f2b(const __bf16* __restrict__ xin,
                                                  const int* __restrict__ col,
                                                  const float* __restrict__ ew,
                                                  __bf16* __restrict__ xout) {
    int idx = blockIdx.x * 256 + threadIdx.x;   // over NR*16
    int vv = idx >> 4;
    int c = (idx & 15) * 8;
    int grp = vv >= V_N;
    int v = vv - (grp ? V_N : 0);
    int goff = grp ? V_N : 0;
    const int e0 = v * DEG;
    float acc[8];
#pragma unroll
    for (int j = 0; j < 8; ++j) acc[j] = 0.f;
#pragma unroll
    for (int e = 0; e < DEG; ++e) {
        float wv = ew[e0 + e];
        bf16x8 p = *(const bf16x8*)&xin[(size_t)(goff + col[e0 + e]) * 128 + c];
#pragma unroll
        for (int j = 0; j < 8; ++j) acc[j] = fmaf(wv, (float)p[j], acc[j]);
    }
    bf16x8 o;
#pragma unroll
    for (int j = 0; j < 8; ++j) o[j] = (__bf16)acc[j];
    *(bf16x8*)&xout[(size_t)vv * 128 + c] = o;
}

// ---------- u = y1 + 2 * (L y2), bf16, width 128, 16B/lane ----------
__global__ __launch_bounds__(256) void k_spmm_u(const __bf16* __restrict__ y1,
                                                const __bf16* __restrict__ y2,
                                                const int* __restrict__ col,
                                                const float* __restrict__ ew,
                                                __bf16* __restrict__ u) {
    int idx = blockIdx.x * 256 + threadIdx.x;   // over NR*16
    int vv = idx >> 4;
    int c = (idx & 15) * 8;
    int grp = vv >= V_N;
    int v = vv - (grp ? V_N : 0);
    int goff = grp ? V_N : 0;
    const int e0 = v * DEG;
    float acc[8];
#pragma unroll
    for (int j = 0; j < 8; ++j) acc[j] = 0.f;
#pragma unroll
    for (int e = 0; e < DEG; ++e) {
        float wv = ew[e0 + e];
        bf16x8 p = *(const bf16x8*)&y2[(size_t)(goff + col[e0 + e]) * 128 + c];
#pragma unroll
        for (int j = 0; j < 8; ++j) acc[j] = fmaf(wv, (float)p[j], acc[j]);
    }
    bf16x8 a = *(const bf16x8*)&y1[(size_t)vv * 128 + c];
    bf16x8 o;
#pragma unroll
    for (int j = 0; j < 8; ++j) o[j] = (__bf16)fmaf(2.f, acc[j], (float)a[j]);
    *(bf16x8*)&u[(size_t)vv * 128 + c] = o;
}

// ---------- weight prepack into MFMA B-fragment layout (hi/lo split) ----------
// pk: [0,4096)=W2hi  [4096,8192)=W2lo  [8192,11264)=W3hi  [11264,14336)=W3lo
__global__ __launch_bounds__(512) void k_prepack(const float* __restrict__ w2,
                                                 const float* __restrict__ w3,
                                                 __bf16* __restrict__ pk) {
    int t = threadIdx.x;
    {
        int kt = t >> 8, nt = (t >> 6) & 3, lane = t & 63;
#pragma unroll
        for (int e = 0; e < 8; ++e) {
            int k = kt * 32 + ((lane >> 4) * 8) + e;
            float val = (k < 48) ? w2[(k >> 4) * 1024 + (k & 15) * 64 + nt * 16 + (lane & 15)] : 0.f;
            __bf16 hi = (__bf16)val;
            pk[t * 8 + e] = hi;
            pk[4096 + t * 8 + e] = (__bf16)(val - (float)hi);
        }
    }
    if (t < 384) {
        int kt = t / 192, nt = (t / 64) % 3, lane = t & 63;
#pragma unroll
        for (int e = 0; e < 8; ++e) {
            int k = kt * 32 + ((lane >> 4) * 8) + e;
            float val = w3[nt * 1024 + k * 16 + (lane & 15)];
            __bf16 hi = (__bf16)val;
            pk[8192 + t * 8 + e] = hi;
            pk[11264 + t * 8 + e] = (__bf16)(val - (float)hi);
        }
    }
}

// ---------- layer 2 + y projection via split-bf16 MFMA ----------
// Block = 8 rows (one group) = 4 waves; wave owns 16-row M-tile (2 rows x 8 g).
// x0 = h1b (bf16); reads at own rows only, so y1o may alias h1b safely.
__global__ __launch_bounds__(256) void k_fused2y_mfma(const __bf16* __restrict__ x0, // h1b [NR][128] bf16
                                                      const __bf16* __restrict__ x1, // x1b [NR][128] bf16
                                                      const int* __restrict__ col,
                                                      const float* __restrict__ ew,
                                                      const __bf16* __restrict__ pk,
                                                      const float* __restrict__ b2,  // [64]
                                                      __bf16* __restrict__ y02o,     // [NR][128] bf16
                                                      __bf16* __restrict__ y1o,      // [NR][128] bf16
                                                      __bf16* __restrict__ y2o) {    // [NR][128] bf16
    __shared__ __attribute__((aligned(16))) __bf16 s_hi[4][16 * 72];
    __shared__ __attribute__((aligned(16))) __bf16 s_lo[4][16 * 72];
    __shared__ int   sc[8][8];
    __shared__ float sw[8][8];
    const int t = threadIdx.x;
    const int v0 = blockIdx.x * 8;                 // global row base (one group)
    const int grp = v0 >= V_N;
    const int vloc = v0 - (grp ? V_N : 0);
    const int goff = grp ? V_N : 0;
    if (t < 64) {
        int vl = t >> 3, e = t & 7;
        sc[vl][e] = goff + col[(vloc + vl) * DEG + e];   // pre-offset gather row
        sw[vl][e] = ew[(vloc + vl) * DEG + e];
    }
    __syncthreads();
    // zero K-pad (kcol 48..63)
    for (int u = t; u < 512; u += 256) {
        int tile = u >> 7, row = (u >> 3) & 15, i = (u & 7) * 2;
        bf16x2 z; z[0] = (__bf16)0.f; z[1] = (__bf16)0.f;
        *(bf16x2*)&s_hi[tile][row * 72 + 48 + i] = z;
        *(bf16x2*)&s_lo[tile][row * 72 + 48 + i] = z;
    }
    // staging: 3 phases, 4 els/thread (1024 els = 8 rows x 128)
    const int su = t * 4;
    const int svl = su >> 7, sel = su & 127;
    const int stile = svl >> 1;
    const int srow = (svl & 1) * 8 + (sel >> 4);
    const int skbase = srow * 72 + (sel & 15);
    const size_t srowg = (size_t)(v0 + svl) * 128;
    bf16x4 zero4;
#pragma unroll
    for (int j = 0; j < 4; ++j) zero4[j] = (__bf16)0.f;
    bf16x4 x0b = *(const bf16x4*)&x0[srowg + sel];
    {   // kch0: x0 bf16 (lo = 0)
        *(bf16x4*)&s_hi[stile][skbase] = x0b;
        *(bf16x4*)&s_lo[stile][skbase] = zero4;
    }
    {   // kch1: x1 bf16 copy (lo = 0)
        bf16x4 hi4 = *(const bf16x4*)&x1[srowg + sel];
        *(bf16x4*)&s_hi[stile][skbase + 16] = hi4;
        *(bf16x4*)&s_lo[stile][skbase + 16] = zero4;
    }
    {   // kch2: gather x2 = 2 L x1 - x0 (f32 accum, hi/lo split)
        float a[4] = {0.f, 0.f, 0.f, 0.f};
#pragma unroll
        for (int e = 0; e < DEG; ++e) {
            float wv = sw[svl][e];
            bf16x4 p = *(const bf16x4*)&x1[(size_t)sc[svl][e] * 128 + sel];
#pragma unroll
            for (int j = 0; j < 4; ++j) a[j] = fmaf(wv, (float)p[j], a[j]);
        }
        bf16x4 hi4, lo4;
#pragma unroll
        for (int j = 0; j < 4; ++j) {
            float vx = 2.f * a[j] - (float)x0b[j];
            __bf16 h = (__bf16)vx;
            hi4[j] = h;
            lo4[j] = (__bf16)(vx - (float)h);
        }
        *(bf16x4*)&s_hi[stile][skbase + 32] = hi4;
        *(bf16x4*)&s_lo[stile][skbase + 32] = lo4;
    }
    __syncthreads();
    const int wv = t >> 6, lane = t & 63;
    const int lrow = lane & 15, lkg = lane >> 4;
    // ---- phase A: h2 = relu(x.W2 + b2) ----
    f32x4 acc[4] = {{0.f,0.f,0.f,0.f},{0.f,0.f,0.f,0.f},{0.f,0.f,0.f,0.f},{0.f,0.f,0.f,0.f}};
#pragma unroll
    for (int kt = 0; kt < 2; ++kt) {
        bf16x8 Ah = *(const bf16x8*)&s_hi[wv][lrow * 72 + kt * 32 + lkg * 8];
        bf16x8 Al = *(const bf16x8*)&s_lo[wv][lrow * 72 + kt * 32 + lkg * 8];
#pragma unroll
        for (int nt = 0; nt < 4; ++nt) {
            bf16x8 Wh = *(const bf16x8*)&pk[((kt * 4 + nt) * 64 + lane) * 8];
            bf16x8 Wl = *(const bf16x8*)&pk[4096 + ((kt * 4 + nt) * 64 + lane) * 8];
            acc[nt] = __builtin_amdgcn_mfma_f32_16x16x32_bf16(Ah, Wh, acc[nt], 0, 0, 0);
            acc[nt] = __builtin_amdgcn_mfma_f32_16x16x32_bf16(Al, Wh, acc[nt], 0, 0, 0);
            acc[nt] = __builtin_amdgcn_mfma_f32_16x16x32_bf16(Ah, Wl, acc[nt], 0, 0, 0);
        }
    }
    // bias + relu -> overwrite OWN wave-private tile with h2 (bf16 hi/lo, A-frag layout)
    __builtin_amdgcn_sched_barrier(0);
#pragma unroll
    for (int nt = 0; nt < 4; ++nt) {
        float bias = b2[nt * 16 + lrow];
#pragma unroll
        for (int r = 0; r < 4; ++r) {
            int row = lkg * 4 + r;
            float h = fmaxf(acc[nt][r] + bias, 0.f);
            __bf16 hh = (__bf16)h;
            s_hi[wv][row * 72 + nt * 16 + lrow] = hh;
            s_lo[wv][row * 72 + nt * 16 + lrow] = (__bf16)(h - (float)hh);
        }
    }
    // wave-private tile: intra-wave lgkmcnt ordering suffices, no barrier
    // ---- phase B: y = h2 . W3 ----
    f32x4 accy[3] = {{0.f,0.f,0.f,0.f},{0.f,0.f,0.f,0.f},{0.f,0.f,0.f,0.f}};
#pragma unroll
    for (int kt = 0; kt < 2; ++kt) {
        bf16x8 Ah = *(const bf16x8*)&s_hi[wv][lrow * 72 + kt * 32 + lkg * 8];
        bf16x8 Al = *(const bf16x8*)&s_lo[wv][lrow * 72 + kt * 32 + lkg * 8];
#pragma unroll
        for (int nt = 0; nt < 3; ++nt) {
            bf16x8 Wh = *(const bf16x8*)&pk[8192 + ((kt * 3 + nt) * 64 + lane) * 8];
            bf16x8 Wl = *(const bf16x8*)&pk[11264 + ((kt * 3 + nt) * 64 + lane) * 8];
            accy[nt] = __builtin_amdgcn_mfma_f32_16x16x32_bf16(Ah, Wh, accy[nt], 0, 0, 0);
            accy[nt] = __builtin_amdgcn_mfma_f32_16x16x32_bf16(Al, Wh, accy[nt], 0, 0, 0);
            accy[nt] = __builtin_amdgcn_mfma_f32_16x16x32_bf16(Ah, Wl, accy[nt], 0, 0, 0);
        }
    }
    // store: y02 = y0 - y2 (bf16); y1, y2 bf16
    const int vbase = v0 + wv * 2;
#pragma unroll
    for (int r = 0; r < 4; ++r) {
        int row = lkg * 4 + r;
        int v = vbase + (row >> 3), g = row & 7;
        size_t off = (size_t)v * 128 + g * 16 + lrow;
        y02o[off] = (__bf16)(accy[0][r] - accy[2][r]);
        y1o[off] = (__bf16)accy[1][r];
        y2o[off] = (__bf16)accy[2][r];
    }
}

// ---------- final: h3 = relu(y02 + L u + b3); out = h3 . w4 + b4 ----------
__global__ __launch_bounds__(256) void k_final_gb(const __bf16* __restrict__ y02, // [NR][128] bf16
                                                  const __bf16* __restrict__ u,   // [NR][128] bf16
                                                  const int* __restrict__ col,
                                                  const float* __restrict__ ew,
                                                  const float* __restrict__ b3,   // [16]
                                                  const float* __restrict__ w4,   // [16]
                                                  const float* __restrict__ b4,   // [1]
                                                  float* __restrict__ out, int b0) {
    int idx = blockIdx.x * 256 + threadIdx.x;   // over NR*8
    int vv = idx >> 3, g = idx & 7;
    int grp = vv >= V_N;
    int v = vv - (grp ? V_N : 0);
    int goff = grp ? V_N : 0;
    const int e0 = v * DEG;
    float acc[16];
#pragma unroll
    for (int j = 0; j < 16; ++j) acc[j] = 0.f;
#pragma unroll
    for (int e = 0; e < DEG; ++e) {
        float wv = ew[e0 + e];
        const __bf16* src = u + (size_t)(goff + col[e0 + e]) * 128 + g * 16;
        bf16x8 u0 = *(const bf16x8*)src;
        bf16x8 u1 = *(const bf16x8*)(src + 8);
#pragma unroll
        for (int j = 0; j < 8; ++j) {
            acc[j] = fmaf(wv, (float)u0[j], acc[j]);
            acc[8 + j] = fmaf(wv, (float)u1[j], acc[8 + j]);
        }
    }
    const __bf16* yp = y02 + (size_t)vv * 128 + g * 16;
    bf16x8 y0v = *(const bf16x8*)yp;
    bf16x8 y1v = *(const bf16x8*)(yp + 8);
    float r = b4[0];
#pragma unroll
    for (int j = 0; j < 8; ++j) {
        float h = fmaxf((float)y0v[j] + acc[j] + b3[j], 0.f);
        r = fmaf(h, w4[j], r);
        float h2 = fmaxf((float)y1v[j] + acc[8 + j] + b3[8 + j], 0.f);
        r = fmaf(h2, w4[8 + j], r);
    }
    out[(size_t)(b0 + grp * 8 + g) * V_N + v] = r;
}

// ---------- driver ----------
extern "C" void kernel_launch(void* const* d_in, const int* in_sizes, int n_in,
                              void* d_out, int out_size, void* d_ws, size_t ws_size,
                              hipStream_t stream) {
    const float* x = (const float*)d_in[0];
    // d_in[1] = edge_row = repeat(arange(V), 8) -> implicit, unused
    const int* ecol = (const int*)d_in[2];
    const float* ew = (const float*)d_in[3];
    const float* w1 = (const float*)d_in[4];
    const float* b1 = (const float*)d_in[5];
    const float* w2 = (const float*)d_in[6];
    const float* b2 = (const float*)d_in[7];
    const float* w3 = (const float*)d_in[8];
    const float* b3 = (const float*)d_in[9];
    const float* w4 = (const float*)d_in[10];
    const float* b4 = (const float*)d_in[11];
    float* out = (float*)d_out;
    float* ws = (float*)d_ws;

    const size_t V = V_N;
    // Each [VR][128] bf16 buffer = 64*VR FLOATS. NB=2 total = 272*2V + 8192
    // floats ~= 107MB; ws >= 129MB known -> NB=2. NB=1 fallback ~53.5MB.
    const size_t need2 = (size_t)(544 * V + 8192) * 4;
    const int NB = (ws_size >= need2) ? 2 : 1;
    const size_t VR = (size_t)NB * V;          // rows per launch set

    // layout (floats): xT 8VR | x1 8VR | h1b 64VR | x1b 64VR | y02b 64VR |
    //                  y2b 64VR | pk 7168
    // (y1b aliases h1b: fused2y reads h1b only at own rows pre-barrier; u aliases x1b)
    float*  xT   = ws;
    float*  x1   = xT + 8 * VR;
    __bf16* h1b  = (__bf16*)(x1 + 8 * VR);
    __bf16* x1b  = (__bf16*)(x1 + 72 * VR);
    __bf16* y02b = (__bf16*)(x1 + 136 * VR);
    __bf16* y2b  = (__bf16*)(x1 + 200 * VR);
    __bf16* y1b  = h1b;
    __bf16* ub   = x1b;
    __bf16* pk   = (__bf16*)(x1 + 264 * VR);

    dim3 blk(256);
    k_prepack<<<1, 512, 0, stream>>>(w2, w3, pk);   // weights: once per call
    for (int b0 = 0; b0 < B_N; b0 += NB * 8) {
        k_transpose<<<(VR * 8) / 256, blk, 0, stream>>>(x, xT, b0);
        k_spmm_g8<<<(VR * 8) / 256, blk, 0, stream>>>(xT, ecol, ew, x1);
        k_fused1_b<<<(VR * 8) / 256, blk, 0, stream>>>(xT, x1, ecol, ew, w1, b1, h1b);
        k_spmm_f2b<<<(VR * 16) / 256, blk, 0, stream>>>(h1b, ecol, ew, x1b);
        k_fused2y_mfma<<<VR / 8, blk, 0, stream>>>(h1b, x1b, ecol, ew, pk, b2, y02b, y1b, y2b);
        k_spmm_u<<<(VR * 16) / 256, blk, 0, stream>>>(y1b, y2b, ecol, ew, ub);
        k_final_gb<<<(VR * 8) / 256, blk, 0, stream>>>(y02b, ub, ecol, ew, b3, w4, b4, out, b0);
    }
}